// Round 4
// baseline (182.997 us; speedup 1.0000x reference)
//
#include <hip/hip_runtime.h>
#include <hip/hip_bf16.h>

typedef __hip_bfloat16 bf16;
typedef __attribute__((ext_vector_type(8))) short short8;
typedef __attribute__((ext_vector_type(4))) float f32x4;

#define SBAR() asm volatile("s_barrier" ::: "memory")
#define VMCNT2() asm volatile("s_waitcnt vmcnt(2)" ::: "memory")
#define VMCNT0() asm volatile("s_waitcnt vmcnt(0)" ::: "memory")

__device__ __forceinline__ void gload_lds16(const bf16* g, bf16* l) {
  __builtin_amdgcn_global_load_lds(
      (const __attribute__((address_space(1))) unsigned int*)g,
      (__attribute__((address_space(3))) unsigned int*)l, 16, 0, 0);
}

// Stage one 128x64 half-tile (row-major, ld=1024) into a linear 16KB LDS slot.
// Global source col is XOR-swizzled so swizzled LDS reads are conflict-free
// (rule 21: linear dest + inverse-swizzled source + swizzled read).
__device__ __forceinline__ void stage_half(const bf16* gbase, bf16* slot, int tid) {
  const int r = tid >> 3;                    // 0..63
  const int c = ((tid & 7) ^ (r & 7)) << 3;  // swizzled 16B chunk
  gload_lds16(gbase + (long)r * 1024 + c, slot + tid * 8);
  gload_lds16(gbase + (long)(r + 64) * 1024 + c, slot + 4096 + tid * 8);
}

// Swizzled fragment read: logical (row, 16B-chunk c16) of a [128][64] half-slot.
__device__ __forceinline__ short8 lds_frag(const bf16* slot, int row, int c16) {
  return *(const short8*)(slot + row * 64 + ((c16 ^ (row & 7)) << 3));
}

// 128x256 tile, BK=64, 8 waves (2M x 4N, 64x64 each), 2-phase-per-K-step
// counted-vmcnt schedule (T2+T3+T4+T5). K fixed at 1024 (NT=16).
// MODE 0: fused QKV projection — bn 0-3 -> Cq (bf16), 4-7 -> Ck (bf16),
//         8-11 -> Cv transposed (V^T[b][d][s], bf16).
// MODE 1: fp32 store to Cq (final O projection), N=1024 via bn 0-3.
template <int MODE>
__global__ __launch_bounds__(512, 2) void gemm128x256(
    const bf16* __restrict__ A, const bf16* __restrict__ Bq,
    const bf16* __restrict__ Bk, const bf16* __restrict__ Bv,
    void* __restrict__ Cq, void* __restrict__ Ck, void* __restrict__ Cv) {
  __shared__ bf16 smem[49152];  // 96 KiB: sA 2 slots + sB 4 slots (16KB each)
  const int bm = blockIdx.x, bn = blockIdx.y;
  const int tid = threadIdx.x;
  const int lane = tid & 63;
  const int wid = tid >> 6;
  const int wr = wid >> 2;    // 0..1  (M: 64-row half)
  const int wc = wid & 3;     // 0..3  (N: 64-col strip)
  const int lr = lane & 15;
  const int c16 = lane >> 4;  // 0..3
  const int g = (MODE == 0) ? (bn >> 2) : 0;
  const int bcol = (bn & 3) * 256;
  const bf16* Bsel = (MODE == 0) ? (g == 0 ? Bq : (g == 1 ? Bk : Bv)) : Bq;
  const int arow = bm * 128;
  const bf16* Ag = A + (long)arow * 1024;
  const bf16* Bg = Bsel + (long)bcol * 1024;
  bf16* sA = smem;            // 2 parity slots
  bf16* sB = smem + 16384;    // 4 slots: parity*2 + half

  // prologue: A(0), B(0)h0, B(0)h1, A(1)
  stage_half(Ag, sA, tid);
  stage_half(Bg, sB, tid);
  stage_half(Bg + 128 * 1024, sB + 8192, tid);
  stage_half(Ag + 64, sA + 8192, tid);
  VMCNT2();  // tile 0 landed; A(1) may stay in flight
  SBAR();

  f32x4 acc[4][4] = {};
  const int NT = 16;
  for (int t = 0; t < NT; ++t) {
    const int rp = t & 1;
    const int sp = rp ^ 1;
    const bf16* As = sA + rp * 8192;
    const bf16* Bs = sB + (rp * 2 + (wc >> 1)) * 8192;
    const int brb = (wc & 1) * 64;
    short8 aq[4][2], b01[2][2], b23[2][2];

    // ---- phase 0: read A-frags + B n0-1; stage B(t+1)h0; MFMA (m0-3 x n0-1)
#pragma unroll
    for (int m = 0; m < 4; ++m)
#pragma unroll
      for (int ks = 0; ks < 2; ++ks)
        aq[m][ks] = lds_frag(As, wr * 64 + m * 16 + lr, c16 + ks * 4);
#pragma unroll
    for (int n = 0; n < 2; ++n)
#pragma unroll
      for (int ks = 0; ks < 2; ++ks)
        b01[n][ks] = lds_frag(Bs, brb + n * 16 + lr, c16 + ks * 4);
    if (t + 1 < NT) stage_half(Bg + (t + 1) * 64, sB + sp * 2 * 8192, tid);
    SBAR();
    __builtin_amdgcn_s_setprio(1);
#pragma unroll
    for (int m = 0; m < 4; ++m)
#pragma unroll
      for (int n = 0; n < 2; ++n)
#pragma unroll
        for (int ks = 0; ks < 2; ++ks)
          acc[m][n] = __builtin_amdgcn_mfma_f32_16x16x32_bf16(
              aq[m][ks], b01[n][ks], acc[m][n], 0, 0, 0);
    __builtin_amdgcn_s_setprio(0);
    SBAR();

    // ---- phase 1: read B n2-3; stage B(t+1)h1 + A(t+2); counted vmcnt;
    //      MFMA (m0-3 x n2-3)
#pragma unroll
    for (int n = 0; n < 2; ++n)
#pragma unroll
      for (int ks = 0; ks < 2; ++ks)
        b23[n][ks] = lds_frag(Bs, brb + (n + 2) * 16 + lr, c16 + ks * 4);
    if (t + 1 < NT)
      stage_half(Bg + 128 * 1024 + (t + 1) * 64, sB + (sp * 2 + 1) * 8192, tid);
    if (t + 2 < NT) {
      stage_half(Ag + (t + 2) * 64, sA + rp * 8192, tid);
      VMCNT2();  // drain A(t+1)+B(t+1); leave A(t+2) in flight
    } else if (t + 1 < NT) {
      VMCNT0();  // tail: everything landed before last iter
    }
    SBAR();
    __builtin_amdgcn_s_setprio(1);
#pragma unroll
    for (int m = 0; m < 4; ++m)
#pragma unroll
      for (int n = 0; n < 2; ++n)
#pragma unroll
        for (int ks = 0; ks < 2; ++ks)
          acc[m][n + 2] = __builtin_amdgcn_mfma_f32_16x16x32_bf16(
              aq[m][ks], b23[n][ks], acc[m][n + 2], 0, 0, 0);
    __builtin_amdgcn_s_setprio(0);
    SBAR();
  }

  // ---- epilogue. C/D layout (m89): col = lane&15, row = (lane>>4)*4 + r
  const int r0 = (lane >> 4) * 4;
  if (MODE == 1) {
    float* C = (float*)Cq;
#pragma unroll
    for (int m = 0; m < 4; ++m)
#pragma unroll
      for (int n = 0; n < 4; ++n)
#pragma unroll
        for (int r = 0; r < 4; ++r)
          C[(long)(arow + wr * 64 + m * 16 + r0 + r) * 1024 + bcol + wc * 64 + n * 16 + lr] =
              acc[m][n][r];
  } else if (g < 2) {
    bf16* C = (bf16*)(g == 0 ? Cq : Ck);
#pragma unroll
    for (int m = 0; m < 4; ++m)
#pragma unroll
      for (int n = 0; n < 4; ++n)
#pragma unroll
        for (int r = 0; r < 4; ++r)
          C[(long)(arow + wr * 64 + m * 16 + r0 + r) * 1024 + bcol + wc * 64 + n * 16 + lr] =
              __float2bfloat16(acc[m][n][r]);
  } else {
    // V: transpose through swizzled LDS, store V^T[b][d][s] coalesced.
    char* T = (char*)smem;  // [256 d][128 s] bf16 = 64KB; all loads drained
#pragma unroll
    for (int m = 0; m < 4; ++m)
#pragma unroll
      for (int n = 0; n < 4; ++n)
#pragma unroll
        for (int r = 0; r < 4; ++r) {
          const int srow = wr * 64 + m * 16 + r0 + r;  // s-local 0..127
          const int dcol = wc * 64 + n * 16 + lr;      // d-local 0..255
          *(bf16*)(T + dcol * 256 + ((srow * 2) ^ ((dcol & 7) << 4))) =
              __float2bfloat16(acc[m][n][r]);
        }
    __syncthreads();
    const int d = tid >> 1;
    const int batch = arow >> 10;
    const int s0 = arow & 1023;
    const int d0 = (bn & 3) * 256;
    bf16* C = (bf16*)Cv;
    const long rowbase = ((long)batch * 1024 + d0 + d) * 1024 + s0;
#pragma unroll
    for (int i = 0; i < 8; ++i) {
      const int s = (tid & 1) * 64 + i * 8;
      const float4 v = *(const float4*)(T + d * 256 + ((s * 2) ^ ((d & 7) << 4)));
      *(float4*)&C[rowbase + s] = v;
    }
  }
}

// ---------------- 128x128 m97-structure GEMM for the per-batch attention GEMMs
#define BM 128
#define BK 64

// MODE 2 = scores: skip blocks with bn > bm; MODE 3 = PV: causal K-limit
template <int MODE>
__global__ __launch_bounds__(256, 2) void gemm_bt(
    const bf16* __restrict__ Aall, const bf16* __restrict__ Ball,
    bf16* __restrict__ Call, int N, int K, long sAB) {
  const int bm = blockIdx.x, bn = blockIdx.y, bz = blockIdx.z;
  if (MODE == 2 && bn > bm) return;
  const bf16* A = Aall + sAB * bz;
  const bf16* B = Ball + sAB * bz;
  bf16* C = Call + sAB * bz;
  const int kEnd = (MODE == 3) ? (((bm + 1) * BM < K) ? (bm + 1) * BM : K) : K;

  __shared__ bf16 smem[BM * BK * 2];
  bf16* As = smem;
  bf16* Bs = smem + BM * BK;
  const int t = threadIdx.x;
  const int lane = t & 63;
  const int wid = t >> 6;
  const int wr = (wid >> 1) * 64;
  const int wc = (wid & 1) * 64;
  const int lr = lane & 15;
  const int lk = (lane >> 4) * 8;
  f32x4 acc[4][4] = {};
  const int arow = bm * BM;
  const int brow = bn * BM;

  for (int k0 = 0; k0 < kEnd; k0 += BK) {
#pragma unroll
    for (int p = 0; p < 4; ++p) {
      const int row = p * 32 + (t >> 3);
      const int col = (t & 7) * 8;
      gload_lds16(A + (long)(arow + row) * K + k0 + col, &As[row * BK + col]);
      gload_lds16(B + (long)(brow + row) * K + k0 + col, &Bs[row * BK + col]);
    }
    __syncthreads();
#pragma unroll
    for (int kk = 0; kk < BK; kk += 32) {
      short8 a[4], b[4];
#pragma unroll
      for (int m = 0; m < 4; ++m)
        a[m] = *(const short8*)&As[(wr + m * 16 + lr) * BK + kk + lk];
#pragma unroll
      for (int n = 0; n < 4; ++n)
        b[n] = *(const short8*)&Bs[(wc + n * 16 + lr) * BK + kk + lk];
#pragma unroll
      for (int m = 0; m < 4; ++m)
#pragma unroll
        for (int n = 0; n < 4; ++n)
          acc[m][n] =
              __builtin_amdgcn_mfma_f32_16x16x32_bf16(a[m], b[n], acc[m][n], 0, 0, 0);
    }
    __syncthreads();
  }
#pragma unroll
  for (int m = 0; m < 4; ++m)
#pragma unroll
    for (int n = 0; n < 4; ++n)
#pragma unroll
      for (int r = 0; r < 4; ++r) {
        const int row = arow + wr + m * 16 + (lane >> 4) * 4 + r;
        const int col = brow + wc + n * 16 + lr;
        C[(long)row * N + col] = __float2bfloat16(acc[m][n][r]);
      }
}

// fp32 -> bf16 bulk convert, all 5 inputs in one launch.
__global__ __launch_bounds__(256) void f2b_all(
    const float* __restrict__ x, const float* __restrict__ wq,
    const float* __restrict__ wk, const float* __restrict__ wv,
    const float* __restrict__ wo, bf16* __restrict__ xb, bf16* __restrict__ wqb,
    bf16* __restrict__ wkb, bf16* __restrict__ wvb, bf16* __restrict__ wob) {
  const int bid = blockIdx.x;
  const float* src;
  bf16* dst;
  long base;
  if (bid < 4096) {
    src = x; dst = xb; base = (long)bid * 2048;
  } else {
    const int w = (bid - 4096) >> 9;
    base = (long)((bid - 4096) & 511) * 2048;
    src = (w == 0) ? wq : (w == 1) ? wk : (w == 2) ? wv : wo;
    dst = (w == 0) ? wqb : (w == 1) ? wkb : (w == 2) ? wvb : wob;
  }
  const long i = base + threadIdx.x * 8;
  const float4 a = *(const float4*)&src[i];
  const float4 b = *(const float4*)&src[i + 4];
  const float va[8] = {a.x, a.y, a.z, a.w, b.x, b.y, b.z, b.w};
  union { bf16 h; short s; } u;
  short8 o;
#pragma unroll
  for (int j = 0; j < 8; ++j) { u.h = __float2bfloat16(va[j]); o[j] = u.s; }
  *(short8*)&dst[i] = o;
}

// In-place causal softmax over bf16 score rows (applies 1/32 scale).
__global__ __launch_bounds__(256) void softmax_causal(bf16* __restrict__ P, int S) {
  const int q = blockIdx.x;
  const int b = blockIdx.y;
  bf16* row = P + ((long)b * S + q) * S;
  const int t = threadIdx.x;
  const int n = q + 1;
  __shared__ float red[8];
  float v[4];
  float mx = -1e30f;
#pragma unroll
  for (int i = 0; i < 4; ++i) {
    const int k = t + i * 256;
    v[i] = (k < n) ? __bfloat162float(row[k]) * 0.03125f : -1e30f;
    mx = fmaxf(mx, v[i]);
  }
#pragma unroll
  for (int o = 32; o > 0; o >>= 1) mx = fmaxf(mx, __shfl_xor(mx, o, 64));
  if ((t & 63) == 0) red[t >> 6] = mx;
  __syncthreads();
  mx = fmaxf(fmaxf(red[0], red[1]), fmaxf(red[2], red[3]));
  float e[4];
  float s = 0.f;
#pragma unroll
  for (int i = 0; i < 4; ++i) {
    const int k = t + i * 256;
    e[i] = (k < n) ? __expf(v[i] - mx) : 0.f;
    s += e[i];
  }
#pragma unroll
  for (int o = 32; o > 0; o >>= 1) s += __shfl_xor(s, o, 64);
  if ((t & 63) == 0) red[4 + (t >> 6)] = s;
  __syncthreads();
  s = (red[4] + red[5]) + (red[6] + red[7]);
  const float inv = 1.f / s;
#pragma unroll
  for (int i = 0; i < 4; ++i) {
    const int k = t + i * 256;
    row[k] = __float2bfloat16(e[i] * inv);
  }
}

extern "C" void kernel_launch(void* const* d_in, const int* in_sizes, int n_in,
                              void* d_out, int out_size, void* d_ws, size_t ws_size,
                              hipStream_t stream) {
  (void)in_sizes; (void)n_in; (void)out_size; (void)ws_size;
  const float* x  = (const float*)d_in[0];
  const float* wq = (const float*)d_in[1];
  const float* wk = (const float*)d_in[2];
  const float* wv = (const float*)d_in[3];
  const float* wo = (const float*)d_in[4];
  float* out = (float*)d_out;
  bf16* ws = (bf16*)d_ws;

  const long SB = 8192L * 1024;
  const long SW = 1024L * 1024;
  const long SS = 1024L * 1024;

  bf16* xb  = ws;
  bf16* wqb = ws + SB;
  bf16* wkb = ws + SB + SW;
  bf16* wvb = ws + SB + 2 * SW;
  bf16* wob = ws + SB + 3 * SW;
  bf16* Q   = ws + SB + 4 * SW;   // [8][s][d]; reused as attn-out
  bf16* Kb  = Q + SB;             // [8][s][d]
  bf16* VT  = Q + 2 * SB;         // [8][d][s]
  bf16* P   = Q + 3 * SB;         // scores / P in place

  f2b_all<<<dim3(6144), dim3(256), 0, stream>>>(x, wq, wk, wv, wo, xb, wqb, wkb, wvb, wob);
  // fused Q/K/V projections (V stored transposed): 768 blocks = 3 exact rounds
  gemm128x256<0><<<dim3(64, 12), dim3(512), 0, stream>>>(xb, wqb, wkb, wvb, Q, Kb, VT);
  // scores = Q K^T, lower-triangle blocks only
  gemm_bt<2><<<dim3(8, 8, 8), dim3(256), 0, stream>>>(Q, Kb, P, 1024, 1024, SS);
  softmax_causal<<<dim3(1024, 8), dim3(256), 0, stream>>>(P, 1024);
  // attn_out = P @ V (B operand = V^T, causal K-limit); into Q's buffer
  gemm_bt<3><<<dim3(8, 8, 8), dim3(256), 0, stream>>>(P, VT, Q, 1024, 1024, SS);
  // output projection -> fp32 d_out: 256 blocks = 1 exact round
  gemm128x256<1><<<dim3(64, 4), dim3(512), 0, stream>>>(Q, wob, nullptr, nullptr, out, nullptr, nullptr);
}

// Round 5
// 169.757 us; speedup vs baseline: 1.0780x; 1.0780x over previous
//
#include <hip/hip_runtime.h>
#include <hip/hip_bf16.h>

typedef __hip_bfloat16 bf16;
typedef __attribute__((ext_vector_type(8))) short short8;
typedef __attribute__((ext_vector_type(4))) float f32x4;

#define SBAR() asm volatile("s_barrier" ::: "memory")
#define VMCNT4() asm volatile("s_waitcnt vmcnt(4)" ::: "memory")
#define VMCNT2() asm volatile("s_waitcnt vmcnt(2)" ::: "memory")
#define VMCNT0() asm volatile("s_waitcnt vmcnt(0)" ::: "memory")

__device__ __forceinline__ void gload_lds16(const bf16* g, bf16* l) {
  __builtin_amdgcn_global_load_lds(
      (const __attribute__((address_space(1))) unsigned int*)g,
      (__attribute__((address_space(3))) unsigned int*)l, 16, 0, 0);
}

// Stage one 128x64 half-tile (row-major, ld=1024) into a linear 16KB LDS slot.
// Global source col is XOR-swizzled so swizzled LDS reads are conflict-free.
__device__ __forceinline__ void stage_half(const bf16* gbase, bf16* slot, int tid) {
  const int r = tid >> 3;                    // 0..63
  const int c = ((tid & 7) ^ (r & 7)) << 3;  // swizzled 16B chunk
  gload_lds16(gbase + (long)r * 1024 + c, slot + tid * 8);
  gload_lds16(gbase + (long)(r + 64) * 1024 + c, slot + 4096 + tid * 8);
}

// Swizzled fragment read: logical (row, 16B-chunk c16) of a [128][64] half-slot.
__device__ __forceinline__ short8 lds_frag(const bf16* slot, int row, int c16) {
  return *(const short8*)(slot + row * 64 + ((c16 ^ (row & 7)) << 3));
}

// ---------------- 256x256-tile 4-phase kernel, fused Q+K projections.
// grid (32, 8): bn 0-3 -> Q (Bq weights, Cq out), bn 4-7 -> K. 1 exact round.
__global__ __launch_bounds__(512, 2) void gemm_qk(
    const bf16* __restrict__ A, const bf16* __restrict__ Bq,
    const bf16* __restrict__ Bk, bf16* __restrict__ Cq, bf16* __restrict__ Ck) {
  __shared__ bf16 smem[65536];  // 128 KiB: A 4 half-slots + B 4 half-slots
  const int bm = blockIdx.x, bn = blockIdx.y;
  const int tid = threadIdx.x;
  const int lane = tid & 63;
  const int wid = tid >> 6;
  const int wr = wid >> 2;   // 0..1 (M)
  const int wc = wid & 3;    // 0..3 (N)
  const int lr = lane & 15;
  const int c16 = lane >> 4;
  const int g = bn >> 2;
  const int bcol = (bn & 3) * 256;
  const bf16* Bsel = (g == 0) ? Bq : Bk;
  const int arow = bm * 256;
  const bf16* Ag = A + (long)arow * 1024;
  const bf16* Bg = Bsel + (long)bcol * 1024;
  bf16* sA = smem;
  bf16* sB = smem + 32768;

  stage_half(Ag, sA, tid);
  stage_half(Ag + 128 * 1024, sA + 8192, tid);
  stage_half(Bg, sB, tid);
  stage_half(Bg + 128 * 1024, sB + 8192, tid);
  stage_half(Ag + 64, sA + 16384, tid);
  stage_half(Ag + 128 * 1024 + 64, sA + 24576, tid);
  VMCNT4();
  SBAR();

  f32x4 acc[8][4] = {};
  const int NT = 16;
  for (int t = 0; t < NT; ++t) {
    const int rp = t & 1;
    const bf16* As = sA + (rp * 2 + wr) * 8192;
    const bf16* Bs = sB + (rp * 2 + (wc >> 1)) * 8192;
    const int brb = (wc & 1) * 64;
    const int sp2 = (rp ^ 1) * 2;
    short8 aq0[4][2], aq1[4][2], bq0[2][2], bq1[2][2];

#pragma unroll
    for (int m = 0; m < 4; ++m)
#pragma unroll
      for (int ks = 0; ks < 2; ++ks)
        aq0[m][ks] = lds_frag(As, m * 16 + lr, c16 + ks * 4);
#pragma unroll
    for (int n = 0; n < 2; ++n)
#pragma unroll
      for (int ks = 0; ks < 2; ++ks)
        bq0[n][ks] = lds_frag(Bs, brb + n * 16 + lr, c16 + ks * 4);
    if (t + 1 < NT) stage_half(Bg + (t + 1) * 64, sB + sp2 * 8192, tid);
    SBAR();
    __builtin_amdgcn_s_setprio(1);
#pragma unroll
    for (int m = 0; m < 4; ++m)
#pragma unroll
      for (int n = 0; n < 2; ++n)
#pragma unroll
        for (int ks = 0; ks < 2; ++ks)
          acc[m][n] = __builtin_amdgcn_mfma_f32_16x16x32_bf16(
              aq0[m][ks], bq0[n][ks], acc[m][n], 0, 0, 0);
    __builtin_amdgcn_s_setprio(0);
    SBAR();

#pragma unroll
    for (int n = 0; n < 2; ++n)
#pragma unroll
      for (int ks = 0; ks < 2; ++ks)
        bq1[n][ks] = lds_frag(Bs, brb + (n + 2) * 16 + lr, c16 + ks * 4);
    if (t + 1 < NT) stage_half(Bg + 128 * 1024 + (t + 1) * 64, sB + (sp2 + 1) * 8192, tid);
    SBAR();
    __builtin_amdgcn_s_setprio(1);
#pragma unroll
    for (int m = 0; m < 4; ++m)
#pragma unroll
      for (int n = 0; n < 2; ++n)
#pragma unroll
        for (int ks = 0; ks < 2; ++ks)
          acc[m][n + 2] = __builtin_amdgcn_mfma_f32_16x16x32_bf16(
              aq0[m][ks], bq1[n][ks], acc[m][n + 2], 0, 0, 0);
    __builtin_amdgcn_s_setprio(0);
    SBAR();

#pragma unroll
    for (int m = 0; m < 4; ++m)
#pragma unroll
      for (int ks = 0; ks < 2; ++ks)
        aq1[m][ks] = lds_frag(As, (m + 4) * 16 + lr, c16 + ks * 4);
    SBAR();
    __builtin_amdgcn_s_setprio(1);
#pragma unroll
    for (int m = 0; m < 4; ++m)
#pragma unroll
      for (int n = 0; n < 2; ++n)
#pragma unroll
        for (int ks = 0; ks < 2; ++ks)
          acc[m + 4][n + 2] = __builtin_amdgcn_mfma_f32_16x16x32_bf16(
              aq1[m][ks], bq1[n][ks], acc[m + 4][n + 2], 0, 0, 0);
    __builtin_amdgcn_s_setprio(0);
    SBAR();

    if (t + 2 < NT) {
      stage_half(Ag + (t + 2) * 64, sA + rp * 2 * 8192, tid);
      stage_half(Ag + 128 * 1024 + (t + 2) * 64, sA + (rp * 2 + 1) * 8192, tid);
      VMCNT4();
    } else if (t + 1 < NT) {
      VMCNT0();
    }
    SBAR();
    __builtin_amdgcn_s_setprio(1);
#pragma unroll
    for (int m = 0; m < 4; ++m)
#pragma unroll
      for (int n = 0; n < 2; ++n)
#pragma unroll
        for (int ks = 0; ks < 2; ++ks)
          acc[m + 4][n] = __builtin_amdgcn_mfma_f32_16x16x32_bf16(
              aq1[m][ks], bq0[n][ks], acc[m + 4][n], 0, 0, 0);
    __builtin_amdgcn_s_setprio(0);
    SBAR();
  }

  const int r0 = (lane >> 4) * 4;
  bf16* C = (g == 0) ? Cq : Ck;
#pragma unroll
  for (int m = 0; m < 8; ++m)
#pragma unroll
    for (int n = 0; n < 4; ++n)
#pragma unroll
      for (int r = 0; r < 4; ++r)
        C[(long)(arow + wr * 128 + m * 16 + r0 + r) * 1024 + bcol + wc * 64 + n * 16 + lr] =
            __float2bfloat16(acc[m][n][r]);
}

// ---------------- 128x256-tile 2-phase kernel, O-projection (fp32 out).
// grid (64, 4) = 256 blocks = 1 exact round. Measured ~27 us in round 4.
__global__ __launch_bounds__(512, 2) void gemm_oproj(
    const bf16* __restrict__ A, const bf16* __restrict__ B, float* __restrict__ C) {
  __shared__ bf16 smem[49152];  // 96 KiB
  const int bm = blockIdx.x, bn = blockIdx.y;
  const int tid = threadIdx.x;
  const int lane = tid & 63;
  const int wid = tid >> 6;
  const int wr = wid >> 2;
  const int wc = wid & 3;
  const int lr = lane & 15;
  const int c16 = lane >> 4;
  const int bcol = bn * 256;
  const int arow = bm * 128;
  const bf16* Ag = A + (long)arow * 1024;
  const bf16* Bg = B + (long)bcol * 1024;
  bf16* sA = smem;
  bf16* sB = smem + 16384;

  stage_half(Ag, sA, tid);
  stage_half(Bg, sB, tid);
  stage_half(Bg + 128 * 1024, sB + 8192, tid);
  stage_half(Ag + 64, sA + 8192, tid);
  VMCNT2();
  SBAR();

  f32x4 acc[4][4] = {};
  const int NT = 16;
  for (int t = 0; t < NT; ++t) {
    const int rp = t & 1;
    const int sp = rp ^ 1;
    const bf16* As = sA + rp * 8192;
    const bf16* Bs = sB + (rp * 2 + (wc >> 1)) * 8192;
    const int brb = (wc & 1) * 64;
    short8 aq[4][2], b01[2][2], b23[2][2];

#pragma unroll
    for (int m = 0; m < 4; ++m)
#pragma unroll
      for (int ks = 0; ks < 2; ++ks)
        aq[m][ks] = lds_frag(As, wr * 64 + m * 16 + lr, c16 + ks * 4);
#pragma unroll
    for (int n = 0; n < 2; ++n)
#pragma unroll
      for (int ks = 0; ks < 2; ++ks)
        b01[n][ks] = lds_frag(Bs, brb + n * 16 + lr, c16 + ks * 4);
    if (t + 1 < NT) stage_half(Bg + (t + 1) * 64, sB + sp * 2 * 8192, tid);
    SBAR();
    __builtin_amdgcn_s_setprio(1);
#pragma unroll
    for (int m = 0; m < 4; ++m)
#pragma unroll
      for (int n = 0; n < 2; ++n)
#pragma unroll
        for (int ks = 0; ks < 2; ++ks)
          acc[m][n] = __builtin_amdgcn_mfma_f32_16x16x32_bf16(
              aq[m][ks], b01[n][ks], acc[m][n], 0, 0, 0);
    __builtin_amdgcn_s_setprio(0);
    SBAR();

#pragma unroll
    for (int n = 0; n < 2; ++n)
#pragma unroll
      for (int ks = 0; ks < 2; ++ks)
        b23[n][ks] = lds_frag(Bs, brb + (n + 2) * 16 + lr, c16 + ks * 4);
    if (t + 1 < NT)
      stage_half(Bg + 128 * 1024 + (t + 1) * 64, sB + (sp * 2 + 1) * 8192, tid);
    if (t + 2 < NT) {
      stage_half(Ag + (t + 2) * 64, sA + rp * 8192, tid);
      VMCNT2();
    } else if (t + 1 < NT) {
      VMCNT0();
    }
    SBAR();
    __builtin_amdgcn_s_setprio(1);
#pragma unroll
    for (int m = 0; m < 4; ++m)
#pragma unroll
      for (int n = 0; n < 2; ++n)
#pragma unroll
        for (int ks = 0; ks < 2; ++ks)
          acc[m][n + 2] = __builtin_amdgcn_mfma_f32_16x16x32_bf16(
              aq[m][ks], b23[n][ks], acc[m][n + 2], 0, 0, 0);
    __builtin_amdgcn_s_setprio(0);
    SBAR();
  }

  const int r0 = (lane >> 4) * 4;
#pragma unroll
  for (int m = 0; m < 4; ++m)
#pragma unroll
    for (int n = 0; n < 4; ++n)
#pragma unroll
      for (int r = 0; r < 4; ++r)
        C[(long)(arow + wr * 64 + m * 16 + r0 + r) * 1024 + bcol + wc * 64 + n * 16 + lr] =
            acc[m][n][r];
}

// ---------------- merged V-projection + scores launch (128x128 m97 structure).
// grid 1024 x 256thr, 2 blocks/CU: ids 0..511 = V-proj (transpose epilogue into
// V^T[b][d][s]); ids 512..1023 = scores QK^T (lower-triangle blocks only).
__global__ __launch_bounds__(256, 2) void vscore(
    const bf16* __restrict__ xb, const bf16* __restrict__ wvb,
    bf16* __restrict__ VT, const bf16* __restrict__ Q,
    const bf16* __restrict__ Kb, bf16* __restrict__ P) {
  const int id = blockIdx.x;
  const bf16 *A, *B;
  int arow, brow, kEnd;
  bool isV;
  long pbase = 0;
  if (id < 512) {
    isV = true;
    arow = (id & 63) * 128;       // 64 M-tiles over 8192 rows
    brow = (id >> 6) * 128;       // 8 N-tiles over 1024 cols
    A = xb; B = wvb; kEnd = 1024;
  } else {
    isV = false;
    const int sid = id - 512;
    const int bz = sid >> 6;
    const int bm = (sid >> 3) & 7, bn = sid & 7;
    if (bn > bm) return;
    const long SS = 1024L * 1024;
    A = Q + SS * bz; B = Kb + SS * bz; pbase = SS * bz;
    arow = bm * 128; brow = bn * 128; kEnd = 1024;
  }

  __shared__ bf16 smem[128 * 64 * 2];  // 32 KiB; reused for transpose epilogue
  bf16* As = smem;
  bf16* Bs = smem + 128 * 64;
  const int t = threadIdx.x;
  const int lane = t & 63;
  const int wid = t >> 6;
  const int wr = (wid >> 1) * 64;
  const int wc = (wid & 1) * 64;
  const int lr = lane & 15;
  const int lk = (lane >> 4) * 8;
  f32x4 acc[4][4] = {};

  for (int k0 = 0; k0 < kEnd; k0 += 64) {
#pragma unroll
    for (int p = 0; p < 4; ++p) {
      const int row = p * 32 + (t >> 3);
      const int col = (t & 7) * 8;
      gload_lds16(A + (long)(arow + row) * 1024 + k0 + col, &As[row * 64 + col]);
      gload_lds16(B + (long)(brow + row) * 1024 + k0 + col, &Bs[row * 64 + col]);
    }
    __syncthreads();
#pragma unroll
    for (int kk = 0; kk < 64; kk += 32) {
      short8 a[4], b[4];
#pragma unroll
      for (int m = 0; m < 4; ++m)
        a[m] = *(const short8*)&As[(wr + m * 16 + lr) * 64 + kk + lk];
#pragma unroll
      for (int n = 0; n < 4; ++n)
        b[n] = *(const short8*)&Bs[(wc + n * 16 + lr) * 64 + kk + lk];
#pragma unroll
      for (int m = 0; m < 4; ++m)
#pragma unroll
        for (int n = 0; n < 4; ++n)
          acc[m][n] =
              __builtin_amdgcn_mfma_f32_16x16x32_bf16(a[m], b[n], acc[m][n], 0, 0, 0);
    }
    __syncthreads();
  }

  if (!isV) {
    bf16* C = P + pbase;
#pragma unroll
    for (int m = 0; m < 4; ++m)
#pragma unroll
      for (int n = 0; n < 4; ++n)
#pragma unroll
        for (int r = 0; r < 4; ++r) {
          const int row = arow + wr + m * 16 + (lane >> 4) * 4 + r;
          const int col = brow + wc + n * 16 + lr;
          C[(long)row * 1024 + col] = __float2bfloat16(acc[m][n][r]);
        }
  } else {
    // transpose through LDS, coalesced 16B stores of V^T[b][d][s]
    __syncthreads();
    bf16* T = smem;  // [128 d][128 s]
#pragma unroll
    for (int m = 0; m < 4; ++m)
#pragma unroll
      for (int n = 0; n < 4; ++n)
#pragma unroll
        for (int r = 0; r < 4; ++r) {
          const int srow = wr + m * 16 + (lane >> 4) * 4 + r;  // s-local
          const int dcol = wc + n * 16 + lr;                   // d-local
          T[dcol * 128 + srow] = __float2bfloat16(acc[m][n][r]);
        }
    __syncthreads();
    const int batch = arow >> 10;
    const int s0 = arow & 1023;
    const int dl = t >> 1;
#pragma unroll
    for (int i = 0; i < 8; ++i) {
      const int sb = (t & 1) * 64 + i * 8;
      *(float4*)&VT[((long)batch * 1024 + brow + dl) * 1024 + s0 + sb] =
          *(const float4*)&T[dl * 128 + sb];
    }
  }
}

// ---------------- PV GEMM (causal K-limit), 128x128 m97 structure.
__global__ __launch_bounds__(256, 2) void gemm_pv(
    const bf16* __restrict__ Pall, const bf16* __restrict__ VTall,
    bf16* __restrict__ Call) {
  const int bm = blockIdx.x, bn = blockIdx.y, bz = blockIdx.z;
  const long SS = 1024L * 1024;
  const bf16* A = Pall + SS * bz;
  const bf16* B = VTall + SS * bz;
  bf16* C = Call + SS * bz;
  const int kEnd = ((bm + 1) * 128 < 1024) ? (bm + 1) * 128 : 1024;

  __shared__ bf16 smem[128 * 64 * 2];
  bf16* As = smem;
  bf16* Bs = smem + 128 * 64;
  const int t = threadIdx.x;
  const int lane = t & 63;
  const int wid = t >> 6;
  const int wr = (wid >> 1) * 64;
  const int wc = (wid & 1) * 64;
  const int lr = lane & 15;
  const int lk = (lane >> 4) * 8;
  f32x4 acc[4][4] = {};
  const int arow = bm * 128;
  const int brow = bn * 128;

  for (int k0 = 0; k0 < kEnd; k0 += 64) {
#pragma unroll
    for (int p = 0; p < 4; ++p) {
      const int row = p * 32 + (t >> 3);
      const int col = (t & 7) * 8;
      gload_lds16(A + (long)(arow + row) * 1024 + k0 + col, &As[row * 64 + col]);
      gload_lds16(B + (long)(brow + row) * 1024 + k0 + col, &Bs[row * 64 + col]);
    }
    __syncthreads();
#pragma unroll
    for (int kk = 0; kk < 64; kk += 32) {
      short8 a[4], b[4];
#pragma unroll
      for (int m = 0; m < 4; ++m)
        a[m] = *(const short8*)&As[(wr + m * 16 + lr) * 64 + kk + lk];
#pragma unroll
      for (int n = 0; n < 4; ++n)
        b[n] = *(const short8*)&Bs[(wc + n * 16 + lr) * 64 + kk + lk];
#pragma unroll
      for (int m = 0; m < 4; ++m)
#pragma unroll
        for (int n = 0; n < 4; ++n)
          acc[m][n] =
              __builtin_amdgcn_mfma_f32_16x16x32_bf16(a[m], b[n], acc[m][n], 0, 0, 0);
    }
    __syncthreads();
  }
#pragma unroll
  for (int m = 0; m < 4; ++m)
#pragma unroll
    for (int n = 0; n < 4; ++n)
#pragma unroll
      for (int r = 0; r < 4; ++r) {
        const int row = arow + wr + m * 16 + (lane >> 4) * 4 + r;
        const int col = brow + wc + n * 16 + lr;
        C[(long)row * 1024 + col] = __float2bfloat16(acc[m][n][r]);
      }
}

// fp32 -> bf16 bulk convert, all 5 inputs in one launch.
__global__ __launch_bounds__(256) void f2b_all(
    const float* __restrict__ x, const float* __restrict__ wq,
    const float* __restrict__ wk, const float* __restrict__ wv,
    const float* __restrict__ wo, bf16* __restrict__ xb, bf16* __restrict__ wqb,
    bf16* __restrict__ wkb, bf16* __restrict__ wvb, bf16* __restrict__ wob) {
  const int bid = blockIdx.x;
  const float* src;
  bf16* dst;
  long base;
  if (bid < 4096) {
    src = x; dst = xb; base = (long)bid * 2048;
  } else {
    const int w = (bid - 4096) >> 9;
    base = (long)((bid - 4096) & 511) * 2048;
    src = (w == 0) ? wq : (w == 1) ? wk : (w == 2) ? wv : wo;
    dst = (w == 0) ? wqb : (w == 1) ? wkb : (w == 2) ? wvb : wob;
  }
  const long i = base + threadIdx.x * 8;
  const float4 a = *(const float4*)&src[i];
  const float4 b = *(const float4*)&src[i + 4];
  const float va[8] = {a.x, a.y, a.z, a.w, b.x, b.y, b.z, b.w};
  union { bf16 h; short s; } u;
  short8 o;
#pragma unroll
  for (int j = 0; j < 8; ++j) { u.h = __float2bfloat16(va[j]); o[j] = u.s; }
  *(short8*)&dst[i] = o;
}

// In-place causal softmax over bf16 score rows (applies 1/32 scale).
__global__ __launch_bounds__(256) void softmax_causal(bf16* __restrict__ P, int S) {
  const int q = blockIdx.x;
  const int b = blockIdx.y;
  bf16* row = P + ((long)b * S + q) * S;
  const int t = threadIdx.x;
  const int n = q + 1;
  __shared__ float red[8];
  float v[4];
  float mx = -1e30f;
#pragma unroll
  for (int i = 0; i < 4; ++i) {
    const int k = t + i * 256;
    v[i] = (k < n) ? __bfloat162float(row[k]) * 0.03125f : -1e30f;
    mx = fmaxf(mx, v[i]);
  }
#pragma unroll
  for (int o = 32; o > 0; o >>= 1) mx = fmaxf(mx, __shfl_xor(mx, o, 64));
  if ((t & 63) == 0) red[t >> 6] = mx;
  __syncthreads();
  mx = fmaxf(fmaxf(red[0], red[1]), fmaxf(red[2], red[3]));
  float e[4];
  float s = 0.f;
#pragma unroll
  for (int i = 0; i < 4; ++i) {
    const int k = t + i * 256;
    e[i] = (k < n) ? __expf(v[i] - mx) : 0.f;
    s += e[i];
  }
#pragma unroll
  for (int o = 32; o > 0; o >>= 1) s += __shfl_xor(s, o, 64);
  if ((t & 63) == 0) red[4 + (t >> 6)] = s;
  __syncthreads();
  s = (red[4] + red[5]) + (red[6] + red[7]);
  const float inv = 1.f / s;
#pragma unroll
  for (int i = 0; i < 4; ++i) {
    const int k = t + i * 256;
    row[k] = __float2bfloat16(e[i] * inv);
  }
}

extern "C" void kernel_launch(void* const* d_in, const int* in_sizes, int n_in,
                              void* d_out, int out_size, void* d_ws, size_t ws_size,
                              hipStream_t stream) {
  (void)in_sizes; (void)n_in; (void)out_size; (void)ws_size;
  const float* x  = (const float*)d_in[0];
  const float* wq = (const float*)d_in[1];
  const float* wk = (const float*)d_in[2];
  const float* wv = (const float*)d_in[3];
  const float* wo = (const float*)d_in[4];
  float* out = (float*)d_out;
  bf16* ws = (bf16*)d_ws;

  const long SB = 8192L * 1024;
  const long SW = 1024L * 1024;

  bf16* xb  = ws;
  bf16* wqb = ws + SB;
  bf16* wkb = ws + SB + SW;
  bf16* wvb = ws + SB + 2 * SW;
  bf16* wob = ws + SB + 3 * SW;
  bf16* Q   = ws + SB + 4 * SW;   // [8][s][d]; reused as attn-out
  bf16* Kb  = Q + SB;             // [8][s][d]
  bf16* VT  = Q + 2 * SB;         // [8][d][s]
  bf16* P   = Q + 3 * SB;         // scores / P in place

  f2b_all<<<dim3(6144), dim3(256), 0, stream>>>(x, wq, wk, wv, wo, xb, wqb, wkb, wvb, wob);
  // Q+K projections: 256 blocks = 1 exact round of 256^2 tiles
  gemm_qk<<<dim3(32, 8), dim3(512), 0, stream>>>(xb, wqb, wkb, Q, Kb);
  // V projection (512 blocks) + scores QK^T (512 blocks, triangular) merged
  vscore<<<dim3(1024), dim3(256), 0, stream>>>(xb, wvb, VT, Q, Kb, P);
  softmax_causal<<<dim3(1024, 8), dim3(256), 0, stream>>>(P, 1024);
  // attn_out = P @ V (B operand = V^T, causal K-limit); into Q's buffer
  gemm_pv<<<dim3(8, 8, 8), dim3(256), 0, stream>>>(P, VT, Q);
  // output projection -> fp32 d_out: 256 blocks = 1 exact round
  gemm_oproj<<<dim3(64, 4), dim3(512), 0, stream>>>(Q, wob, out);
}

// Round 6
// 156.630 us; speedup vs baseline: 1.1683x; 1.0838x over previous
//
#include <hip/hip_runtime.h>
#include <hip/hip_bf16.h>

typedef __hip_bfloat16 bf16;
typedef __attribute__((ext_vector_type(8))) short short8;
typedef __attribute__((ext_vector_type(4))) float f32x4;

#define SBAR() asm volatile("s_barrier" ::: "memory")
#define VMCNT4() asm volatile("s_waitcnt vmcnt(4)" ::: "memory")
#define VMCNT2() asm volatile("s_waitcnt vmcnt(2)" ::: "memory")
#define VMCNT0() asm volatile("s_waitcnt vmcnt(0)" ::: "memory")

__device__ __forceinline__ void gload_lds16(const bf16* g, bf16* l) {
  __builtin_amdgcn_global_load_lds(
      (const __attribute__((address_space(1))) unsigned int*)g,
      (__attribute__((address_space(3))) unsigned int*)l, 16, 0, 0);
}

// Stage one 128x64 half-tile (row-major, ld=1024) into a linear 16KB LDS slot.
// Global source col is XOR-swizzled so swizzled LDS reads are conflict-free.
__device__ __forceinline__ void stage_half(const bf16* gbase, bf16* slot, int tid) {
  const int r = tid >> 3;                    // 0..63
  const int c = ((tid & 7) ^ (r & 7)) << 3;  // swizzled 16B chunk
  gload_lds16(gbase + (long)r * 1024 + c, slot + tid * 8);
  gload_lds16(gbase + (long)(r + 64) * 1024 + c, slot + 4096 + tid * 8);
}

// Swizzled fragment read: logical (row, 16B-chunk c16) of a [128][64] half-slot.
__device__ __forceinline__ short8 lds_frag(const bf16* slot, int row, int c16) {
  return *(const short8*)(slot + row * 64 + ((c16 ^ (row & 7)) << 3));
}

// ======== 256x256-tile 4-phase main loop (T2+T3+T4+T5), shared by QK & vscore.
// Runs the 16-K-step pipeline given staged global bases; acc is 8x4 f32x4.
#define LOOP256(Ag, Bg, sA, sB, acc)                                              \
  {                                                                               \
    stage_half(Ag, sA, tid);                                                      \
    stage_half(Ag + 128 * 1024, sA + 8192, tid);                                  \
    stage_half(Bg, sB, tid);                                                      \
    stage_half(Bg + 128 * 1024, sB + 8192, tid);                                  \
    stage_half(Ag + 64, sA + 16384, tid);                                         \
    stage_half(Ag + 128 * 1024 + 64, sA + 24576, tid);                            \
    VMCNT4();                                                                     \
    SBAR();                                                                       \
    const int NT = 16;                                                            \
    for (int t = 0; t < NT; ++t) {                                                \
      const int rp = t & 1;                                                       \
      const bf16* As = sA + (rp * 2 + wr) * 8192;                                 \
      const bf16* Bs = sB + (rp * 2 + (wc >> 1)) * 8192;                          \
      const int brb = (wc & 1) * 64;                                              \
      const int sp2 = (rp ^ 1) * 2;                                               \
      short8 aq0[4][2], aq1[4][2], bq0[2][2], bq1[2][2];                          \
      _Pragma("unroll") for (int m = 0; m < 4; ++m)                               \
          _Pragma("unroll") for (int ks = 0; ks < 2; ++ks)                        \
              aq0[m][ks] = lds_frag(As, m * 16 + lr, c16 + ks * 4);               \
      _Pragma("unroll") for (int n = 0; n < 2; ++n)                               \
          _Pragma("unroll") for (int ks = 0; ks < 2; ++ks)                        \
              bq0[n][ks] = lds_frag(Bs, brb + n * 16 + lr, c16 + ks * 4);         \
      if (t + 1 < NT) stage_half(Bg + (t + 1) * 64, sB + sp2 * 8192, tid);        \
      SBAR();                                                                     \
      __builtin_amdgcn_s_setprio(1);                                              \
      _Pragma("unroll") for (int m = 0; m < 4; ++m)                               \
          _Pragma("unroll") for (int n = 0; n < 2; ++n)                           \
              _Pragma("unroll") for (int ks = 0; ks < 2; ++ks)                    \
                  acc[m][n] = __builtin_amdgcn_mfma_f32_16x16x32_bf16(            \
                      aq0[m][ks], bq0[n][ks], acc[m][n], 0, 0, 0);                \
      __builtin_amdgcn_s_setprio(0);                                              \
      SBAR();                                                                     \
      _Pragma("unroll") for (int n = 0; n < 2; ++n)                               \
          _Pragma("unroll") for (int ks = 0; ks < 2; ++ks)                        \
              bq1[n][ks] = lds_frag(Bs, brb + (n + 2) * 16 + lr, c16 + ks * 4);   \
      if (t + 1 < NT)                                                             \
        stage_half(Bg + 128 * 1024 + (t + 1) * 64, sB + (sp2 + 1) * 8192, tid);   \
      SBAR();                                                                     \
      __builtin_amdgcn_s_setprio(1);                                              \
      _Pragma("unroll") for (int m = 0; m < 4; ++m)                               \
          _Pragma("unroll") for (int n = 0; n < 2; ++n)                           \
              _Pragma("unroll") for (int ks = 0; ks < 2; ++ks)                    \
                  acc[m][n + 2] = __builtin_amdgcn_mfma_f32_16x16x32_bf16(        \
                      aq0[m][ks], bq1[n][ks], acc[m][n + 2], 0, 0, 0);            \
      __builtin_amdgcn_s_setprio(0);                                              \
      SBAR();                                                                     \
      _Pragma("unroll") for (int m = 0; m < 4; ++m)                               \
          _Pragma("unroll") for (int ks = 0; ks < 2; ++ks)                        \
              aq1[m][ks] = lds_frag(As, (m + 4) * 16 + lr, c16 + ks * 4);         \
      SBAR();                                                                     \
      __builtin_amdgcn_s_setprio(1);                                              \
      _Pragma("unroll") for (int m = 0; m < 4; ++m)                               \
          _Pragma("unroll") for (int n = 0; n < 2; ++n)                           \
              _Pragma("unroll") for (int ks = 0; ks < 2; ++ks)                    \
                  acc[m + 4][n + 2] = __builtin_amdgcn_mfma_f32_16x16x32_bf16(    \
                      aq1[m][ks], bq1[n][ks], acc[m + 4][n + 2], 0, 0, 0);        \
      __builtin_amdgcn_s_setprio(0);                                              \
      SBAR();                                                                     \
      if (t + 2 < NT) {                                                           \
        stage_half(Ag + (t + 2) * 64, sA + rp * 2 * 8192, tid);                   \
        stage_half(Ag + 128 * 1024 + (t + 2) * 64, sA + (rp * 2 + 1) * 8192, tid);\
        VMCNT4();                                                                 \
      } else if (t + 1 < NT) {                                                    \
        VMCNT0();                                                                 \
      }                                                                           \
      SBAR();                                                                     \
      __builtin_amdgcn_s_setprio(1);                                              \
      _Pragma("unroll") for (int m = 0; m < 4; ++m)                               \
          _Pragma("unroll") for (int n = 0; n < 2; ++n)                           \
              _Pragma("unroll") for (int ks = 0; ks < 2; ++ks)                    \
                  acc[m + 4][n] = __builtin_amdgcn_mfma_f32_16x16x32_bf16(        \
                      aq1[m][ks], bq0[n][ks], acc[m + 4][n], 0, 0, 0);            \
      __builtin_amdgcn_s_setprio(0);                                              \
      SBAR();                                                                     \
    }                                                                             \
  }

// ---------------- fused Q+K projections: grid (32, 8) = 256 blocks = 1 round.
__global__ __launch_bounds__(512, 2) void gemm_qk(
    const bf16* __restrict__ A, const bf16* __restrict__ Bq,
    const bf16* __restrict__ Bk, bf16* __restrict__ Cq, bf16* __restrict__ Ck) {
  __shared__ bf16 smem[65536];
  const int bm = blockIdx.x, bn = blockIdx.y;
  const int tid = threadIdx.x;
  const int lane = tid & 63;
  const int wid = tid >> 6;
  const int wr = wid >> 2;
  const int wc = wid & 3;
  const int lr = lane & 15;
  const int c16 = lane >> 4;
  const int g = bn >> 2;
  const int bcol = (bn & 3) * 256;
  const int arow = bm * 256;
  const bf16* Ag = A + (long)arow * 1024;
  const bf16* Bg = ((g == 0) ? Bq : Bk) + (long)bcol * 1024;
  bf16* sA = smem;
  bf16* sB = smem + 32768;

  f32x4 acc[8][4] = {};
  LOOP256(Ag, Bg, sA, sB, acc);

  const int r0 = (lane >> 4) * 4;
  bf16* C = (g == 0) ? Cq : Ck;
#pragma unroll
  for (int m = 0; m < 8; ++m)
#pragma unroll
    for (int n = 0; n < 4; ++n)
#pragma unroll
      for (int r = 0; r < 4; ++r)
        C[(long)(arow + wr * 128 + m * 16 + r0 + r) * 1024 + bcol + wc * 64 + n * 16 + lr] =
            __float2bfloat16(acc[m][n][r]);
}

// ---------------- merged V-projection + scores at 256^2 rate.
// grid (208): id 0..127 = V-proj (bm=id>>2, d-strip=id&3; V^T transpose epilogue);
//             id 128..207 = scores, 10 lower-triangle 256^2 tiles x 8 batches.
__global__ __launch_bounds__(512, 2) void vscore256(
    const bf16* __restrict__ xb, const bf16* __restrict__ wvb,
    bf16* __restrict__ VT, const bf16* __restrict__ Q,
    const bf16* __restrict__ Kb, bf16* __restrict__ P) {
  __shared__ bf16 smem[65536];
  const int id = blockIdx.x;
  const int tid = threadIdx.x;
  const int lane = tid & 63;
  const int wid = tid >> 6;
  const int wr = wid >> 2;
  const int wc = wid & 3;
  const int lr = lane & 15;
  const int c16 = lane >> 4;
  const long SS = 1024L * 1024;

  const bf16 *Ag, *Bg;
  int bmS = 0, bnS = 0, bzS = 0, bmV = 0, bnV = 0;
  const bool isV = (id < 128);
  if (isV) {
    bmV = id >> 2;             // 0..31 over 8192 rows
    bnV = id & 3;              // 0..3 over 1024 d
    Ag = xb + (long)bmV * 256 * 1024;
    Bg = wvb + (long)bnV * 256 * 1024;
  } else {
    const int sid = id - 128;
    bzS = sid / 10;
    const int r = sid - bzS * 10;          // lower-triangle tile index
    bmS = (r >= 1) + (r >= 3) + (r >= 6);  // {0,1,1,2,2,2,3,3,3,3}
    bnS = r - (bmS * (bmS + 1)) / 2;
    Ag = Q + SS * bzS + (long)bmS * 256 * 1024;
    Bg = Kb + SS * bzS + (long)bnS * 256 * 1024;
  }
  bf16* sA = smem;
  bf16* sB = smem + 32768;

  f32x4 acc[8][4] = {};
  LOOP256(Ag, Bg, sA, sB, acc);

  const int r0 = (lane >> 4) * 4;
  if (!isV) {
    bf16* C = P + SS * bzS;
    const int arow = bmS * 256, bcol = bnS * 256;
#pragma unroll
    for (int m = 0; m < 8; ++m)
#pragma unroll
      for (int n = 0; n < 4; ++n)
#pragma unroll
        for (int r = 0; r < 4; ++r)
          C[(long)(arow + wr * 128 + m * 16 + r0 + r) * 1024 + bcol + wc * 64 + n * 16 + lr] =
              __float2bfloat16(acc[m][n][r]);
  } else {
    // transpose 256x256 through swizzled LDS (exactly 128 KiB), store V^T.
    char* T = (char*)smem;  // main loop ends fully drained (VMCNT0 + SBAR)
#pragma unroll
    for (int m = 0; m < 8; ++m)
#pragma unroll
      for (int n = 0; n < 4; ++n)
#pragma unroll
        for (int r = 0; r < 4; ++r) {
          const int srow = wr * 128 + m * 16 + r0 + r;  // s-local 0..255
          const int dcol = wc * 64 + n * 16 + lr;       // d-local 0..255
          *(bf16*)(T + dcol * 512 + ((srow * 2) ^ ((dcol & 7) << 4))) =
              __float2bfloat16(acc[m][n][r]);
        }
    __syncthreads();
    const int d = tid >> 1;                // 0..255
    const int batch = bmV >> 2;
    const int s0 = (bmV & 3) * 256;
    const int d0 = bnV * 256;
    const long rowbase = ((long)batch * 1024 + d0 + d) * 1024 + s0;
#pragma unroll
    for (int i = 0; i < 16; ++i) {
      const int s = (tid & 1) * 128 + i * 8;
      const float4 v = *(const float4*)(T + d * 512 + ((s * 2) ^ ((d & 7) << 4)));
      *(float4*)&VT[rowbase + s] = v;
    }
  }
}

// ---------------- 128x256-tile 2-phase kernel: PV (MODE 0) and O-proj (MODE 1).
// MODE 0: grid (8,4,8), kEnd=(bm+1)*128, bf16 out. MODE 1: grid (64,4), fp32 out.
template <int MODE>
__global__ __launch_bounds__(512, 2) void gemm_pvo(
    const bf16* __restrict__ Aall, const bf16* __restrict__ Ball,
    void* __restrict__ Call) {
  __shared__ bf16 smem[49152];  // 96 KiB
  const int bm = blockIdx.x, bn = blockIdx.y, bz = blockIdx.z;
  const long SS = 1024L * 1024;
  const bf16* A = (MODE == 0) ? Aall + SS * bz : Aall;
  const bf16* B = (MODE == 0) ? Ball + SS * bz : Ball;
  const int tid = threadIdx.x;
  const int lane = tid & 63;
  const int wid = tid >> 6;
  const int wr = wid >> 2;
  const int wc = wid & 3;
  const int lr = lane & 15;
  const int c16 = lane >> 4;
  const int bcol = bn * 256;
  const int arow = bm * 128;
  const int NT = (MODE == 1) ? 16 : (bm + 1) * 2;  // K-steps of 64
  const bf16* Ag = A + (long)arow * 1024;
  const bf16* Bg = B + (long)bcol * 1024;
  bf16* sA = smem;
  bf16* sB = smem + 16384;

  stage_half(Ag, sA, tid);
  stage_half(Bg, sB, tid);
  stage_half(Bg + 128 * 1024, sB + 8192, tid);
  stage_half(Ag + 64, sA + 8192, tid);
  VMCNT2();
  SBAR();

  f32x4 acc[4][4] = {};
  for (int t = 0; t < NT; ++t) {
    const int rp = t & 1;
    const int sp = rp ^ 1;
    const bf16* As = sA + rp * 8192;
    const bf16* Bs = sB + (rp * 2 + (wc >> 1)) * 8192;
    const int brb = (wc & 1) * 64;
    short8 aq[4][2], b01[2][2], b23[2][2];

#pragma unroll
    for (int m = 0; m < 4; ++m)
#pragma unroll
      for (int ks = 0; ks < 2; ++ks)
        aq[m][ks] = lds_frag(As, wr * 64 + m * 16 + lr, c16 + ks * 4);
#pragma unroll
    for (int n = 0; n < 2; ++n)
#pragma unroll
      for (int ks = 0; ks < 2; ++ks)
        b01[n][ks] = lds_frag(Bs, brb + n * 16 + lr, c16 + ks * 4);
    if (t + 1 < NT) stage_half(Bg + (t + 1) * 64, sB + sp * 2 * 8192, tid);
    SBAR();
    __builtin_amdgcn_s_setprio(1);
#pragma unroll
    for (int m = 0; m < 4; ++m)
#pragma unroll
      for (int n = 0; n < 2; ++n)
#pragma unroll
        for (int ks = 0; ks < 2; ++ks)
          acc[m][n] = __builtin_amdgcn_mfma_f32_16x16x32_bf16(
              aq[m][ks], b01[n][ks], acc[m][n], 0, 0, 0);
    __builtin_amdgcn_s_setprio(0);
    SBAR();

#pragma unroll
    for (int n = 0; n < 2; ++n)
#pragma unroll
      for (int ks = 0; ks < 2; ++ks)
        b23[n][ks] = lds_frag(Bs, brb + (n + 2) * 16 + lr, c16 + ks * 4);
    if (t + 1 < NT)
      stage_half(Bg + 128 * 1024 + (t + 1) * 64, sB + (sp * 2 + 1) * 8192, tid);
    if (t + 2 < NT) {
      stage_half(Ag + (t + 2) * 64, sA + rp * 8192, tid);
      VMCNT2();
    } else if (t + 1 < NT) {
      VMCNT0();
    }
    SBAR();
    __builtin_amdgcn_s_setprio(1);
#pragma unroll
    for (int m = 0; m < 4; ++m)
#pragma unroll
      for (int n = 0; n < 2; ++n)
#pragma unroll
        for (int ks = 0; ks < 2; ++ks)
          acc[m][n + 2] = __builtin_amdgcn_mfma_f32_16x16x32_bf16(
              aq[m][ks], b23[n][ks], acc[m][n + 2], 0, 0, 0);
    __builtin_amdgcn_s_setprio(0);
    SBAR();
  }

  const int r0 = (lane >> 4) * 4;
  if (MODE == 1) {
    float* C = (float*)Call;
#pragma unroll
    for (int m = 0; m < 4; ++m)
#pragma unroll
      for (int n = 0; n < 4; ++n)
#pragma unroll
        for (int r = 0; r < 4; ++r)
          C[(long)(arow + wr * 64 + m * 16 + r0 + r) * 1024 + bcol + wc * 64 + n * 16 + lr] =
              acc[m][n][r];
  } else {
    bf16* C = (bf16*)Call + SS * bz;
#pragma unroll
    for (int m = 0; m < 4; ++m)
#pragma unroll
      for (int n = 0; n < 4; ++n)
#pragma unroll
        for (int r = 0; r < 4; ++r)
          C[(long)(arow + wr * 64 + m * 16 + r0 + r) * 1024 + bcol + wc * 64 + n * 16 + lr] =
              __float2bfloat16(acc[m][n][r]);
  }
}

// fp32 -> bf16 bulk convert, all 5 inputs in one launch.
__global__ __launch_bounds__(256) void f2b_all(
    const float* __restrict__ x, const float* __restrict__ wq,
    const float* __restrict__ wk, const float* __restrict__ wv,
    const float* __restrict__ wo, bf16* __restrict__ xb, bf16* __restrict__ wqb,
    bf16* __restrict__ wkb, bf16* __restrict__ wvb, bf16* __restrict__ wob) {
  const int bid = blockIdx.x;
  const float* src;
  bf16* dst;
  long base;
  if (bid < 4096) {
    src = x; dst = xb; base = (long)bid * 2048;
  } else {
    const int w = (bid - 4096) >> 9;
    base = (long)((bid - 4096) & 511) * 2048;
    src = (w == 0) ? wq : (w == 1) ? wk : (w == 2) ? wv : wo;
    dst = (w == 0) ? wqb : (w == 1) ? wkb : (w == 2) ? wvb : wob;
  }
  const long i = base + threadIdx.x * 8;
  const float4 a = *(const float4*)&src[i];
  const float4 b = *(const float4*)&src[i + 4];
  const float va[8] = {a.x, a.y, a.z, a.w, b.x, b.y, b.z, b.w};
  union { bf16 h; short s; } u;
  short8 o;
#pragma unroll
  for (int j = 0; j < 8; ++j) { u.h = __float2bfloat16(va[j]); o[j] = u.s; }
  *(short8*)&dst[i] = o;
}

// In-place causal softmax over bf16 score rows (applies 1/32 scale).
__global__ __launch_bounds__(256) void softmax_causal(bf16* __restrict__ P, int S) {
  const int q = blockIdx.x;
  const int b = blockIdx.y;
  bf16* row = P + ((long)b * S + q) * S;
  const int t = threadIdx.x;
  const int n = q + 1;
  __shared__ float red[8];
  float v[4];
  float mx = -1e30f;
#pragma unroll
  for (int i = 0; i < 4; ++i) {
    const int k = t + i * 256;
    v[i] = (k < n) ? __bfloat162float(row[k]) * 0.03125f : -1e30f;
    mx = fmaxf(mx, v[i]);
  }
#pragma unroll
  for (int o = 32; o > 0; o >>= 1) mx = fmaxf(mx, __shfl_xor(mx, o, 64));
  if ((t & 63) == 0) red[t >> 6] = mx;
  __syncthreads();
  mx = fmaxf(fmaxf(red[0], red[1]), fmaxf(red[2], red[3]));
  float e[4];
  float s = 0.f;
#pragma unroll
  for (int i = 0; i < 4; ++i) {
    const int k = t + i * 256;
    e[i] = (k < n) ? __expf(v[i] - mx) : 0.f;
    s += e[i];
  }
#pragma unroll
  for (int o = 32; o > 0; o >>= 1) s += __shfl_xor(s, o, 64);
  if ((t & 63) == 0) red[4 + (t >> 6)] = s;
  __syncthreads();
  s = (red[4] + red[5]) + (red[6] + red[7]);
  const float inv = 1.f / s;
#pragma unroll
  for (int i = 0; i < 4; ++i) {
    const int k = t + i * 256;
    row[k] = __float2bfloat16(e[i] * inv);
  }
}

extern "C" void kernel_launch(void* const* d_in, const int* in_sizes, int n_in,
                              void* d_out, int out_size, void* d_ws, size_t ws_size,
                              hipStream_t stream) {
  (void)in_sizes; (void)n_in; (void)out_size; (void)ws_size;
  const float* x  = (const float*)d_in[0];
  const float* wq = (const float*)d_in[1];
  const float* wk = (const float*)d_in[2];
  const float* wv = (const float*)d_in[3];
  const float* wo = (const float*)d_in[4];
  float* out = (float*)d_out;
  bf16* ws = (bf16*)d_ws;

  const long SB = 8192L * 1024;
  const long SW = 1024L * 1024;

  bf16* xb  = ws;
  bf16* wqb = ws + SB;
  bf16* wkb = ws + SB + SW;
  bf16* wvb = ws + SB + 2 * SW;
  bf16* wob = ws + SB + 3 * SW;
  bf16* Q   = ws + SB + 4 * SW;   // [8][s][d]; reused as attn-out
  bf16* Kb  = Q + SB;             // [8][s][d]
  bf16* VT  = Q + 2 * SB;         // [8][d][s]
  bf16* P   = Q + 3 * SB;         // scores / P in place

  f2b_all<<<dim3(6144), dim3(256), 0, stream>>>(x, wq, wk, wv, wo, xb, wqb, wkb, wvb, wob);
  // Q+K projections: 256 blocks = 1 exact round of 256^2 tiles
  gemm_qk<<<dim3(32, 8), dim3(512), 0, stream>>>(xb, wqb, wkb, Q, Kb);
  // V projection (128 blocks) + triangular scores (80 blocks), all 256^2 rate
  vscore256<<<dim3(208), dim3(512), 0, stream>>>(xb, wvb, VT, Q, Kb, P);
  softmax_causal<<<dim3(1024, 8), dim3(256), 0, stream>>>(P, 1024);
  // attn_out = P @ V (B = V^T, causal K-limit): 256 blocks = 1 exact round
  gemm_pvo<0><<<dim3(8, 4, 8), dim3(512), 0, stream>>>(P, VT, Q);
  // output projection -> fp32 d_out: 256 blocks = 1 exact round
  gemm_pvo<1><<<dim3(64, 4, 1), dim3(512), 0, stream>>>(Q, wob, out);
}

// Round 7
// 147.974 us; speedup vs baseline: 1.2367x; 1.0585x over previous
//
#include <hip/hip_runtime.h>
#include <hip/hip_bf16.h>

typedef __hip_bfloat16 bf16;
typedef __attribute__((ext_vector_type(8))) short short8;
typedef __attribute__((ext_vector_type(4))) float f32x4;

#define SBAR() asm volatile("s_barrier" ::: "memory")
#define VMCNT4() asm volatile("s_waitcnt vmcnt(4)" ::: "memory")
#define VMCNT2() asm volatile("s_waitcnt vmcnt(2)" ::: "memory")
#define VMCNT0() asm volatile("s_waitcnt vmcnt(0)" ::: "memory")

__device__ __forceinline__ void gload_lds16(const bf16* g, bf16* l) {
  __builtin_amdgcn_global_load_lds(
      (const __attribute__((address_space(1))) unsigned int*)g,
      (__attribute__((address_space(3))) unsigned int*)l, 16, 0, 0);
}

// Stage one 128x64 half-tile (row-major, ld=1024) into a linear 16KB LDS slot.
// Global source col is XOR-swizzled so swizzled LDS reads are conflict-free.
__device__ __forceinline__ void stage_half(const bf16* gbase, bf16* slot, int tid) {
  const int r = tid >> 3;                    // 0..63
  const int c = ((tid & 7) ^ (r & 7)) << 3;  // swizzled 16B chunk
  gload_lds16(gbase + (long)r * 1024 + c, slot + tid * 8);
  gload_lds16(gbase + (long)(r + 64) * 1024 + c, slot + 4096 + tid * 8);
}

// Swizzled fragment read: logical (row, 16B-chunk c16) of a [128][64] half-slot.
__device__ __forceinline__ short8 lds_frag(const bf16* slot, int row, int c16) {
  return *(const short8*)(slot + row * 64 + ((c16 ^ (row & 7)) << 3));
}

// ======== 256x256-tile 4-phase main loop (T2+T3+T4+T5), shared by QK & vscore.
#define LOOP256(Ag, Bg, sA, sB, acc)                                              \
  {                                                                               \
    stage_half(Ag, sA, tid);                                                      \
    stage_half(Ag + 128 * 1024, sA + 8192, tid);                                  \
    stage_half(Bg, sB, tid);                                                      \
    stage_half(Bg + 128 * 1024, sB + 8192, tid);                                  \
    stage_half(Ag + 64, sA + 16384, tid);                                         \
    stage_half(Ag + 128 * 1024 + 64, sA + 24576, tid);                            \
    VMCNT4();                                                                     \
    SBAR();                                                                       \
    const int NT = 16;                                                            \
    for (int t = 0; t < NT; ++t) {                                                \
      const int rp = t & 1;                                                       \
      const bf16* As = sA + (rp * 2 + wr) * 8192;                                 \
      const bf16* Bs = sB + (rp * 2 + (wc >> 1)) * 8192;                          \
      const int brb = (wc & 1) * 64;                                              \
      const int sp2 = (rp ^ 1) * 2;                                               \
      short8 aq0[4][2], aq1[4][2], bq0[2][2], bq1[2][2];                          \
      _Pragma("unroll") for (int m = 0; m < 4; ++m)                               \
          _Pragma("unroll") for (int ks = 0; ks < 2; ++ks)                        \
              aq0[m][ks] = lds_frag(As, m * 16 + lr, c16 + ks * 4);               \
      _Pragma("unroll") for (int n = 0; n < 2; ++n)                               \
          _Pragma("unroll") for (int ks = 0; ks < 2; ++ks)                        \
              bq0[n][ks] = lds_frag(Bs, brb + n * 16 + lr, c16 + ks * 4);         \
      if (t + 1 < NT) stage_half(Bg + (t + 1) * 64, sB + sp2 * 8192, tid);        \
      SBAR();                                                                     \
      __builtin_amdgcn_s_setprio(1);                                              \
      _Pragma("unroll") for (int m = 0; m < 4; ++m)                               \
          _Pragma("unroll") for (int n = 0; n < 2; ++n)                           \
              _Pragma("unroll") for (int ks = 0; ks < 2; ++ks)                    \
                  acc[m][n] = __builtin_amdgcn_mfma_f32_16x16x32_bf16(            \
                      aq0[m][ks], bq0[n][ks], acc[m][n], 0, 0, 0);                \
      __builtin_amdgcn_s_setprio(0);                                              \
      SBAR();                                                                     \
      _Pragma("unroll") for (int n = 0; n < 2; ++n)                               \
          _Pragma("unroll") for (int ks = 0; ks < 2; ++ks)                        \
              bq1[n][ks] = lds_frag(Bs, brb + (n + 2) * 16 + lr, c16 + ks * 4);   \
      if (t + 1 < NT)                                                             \
        stage_half(Bg + 128 * 1024 + (t + 1) * 64, sB + (sp2 + 1) * 8192, tid);   \
      SBAR();                                                                     \
      __builtin_amdgcn_s_setprio(1);                                              \
      _Pragma("unroll") for (int m = 0; m < 4; ++m)                               \
          _Pragma("unroll") for (int n = 0; n < 2; ++n)                           \
              _Pragma("unroll") for (int ks = 0; ks < 2; ++ks)                    \
                  acc[m][n + 2] = __builtin_amdgcn_mfma_f32_16x16x32_bf16(        \
                      aq0[m][ks], bq1[n][ks], acc[m][n + 2], 0, 0, 0);            \
      __builtin_amdgcn_s_setprio(0);                                              \
      SBAR();                                                                     \
      _Pragma("unroll") for (int m = 0; m < 4; ++m)                               \
          _Pragma("unroll") for (int ks = 0; ks < 2; ++ks)                        \
              aq1[m][ks] = lds_frag(As, (m + 4) * 16 + lr, c16 + ks * 4);         \
      SBAR();                                                                     \
      __builtin_amdgcn_s_setprio(1);                                              \
      _Pragma("unroll") for (int m = 0; m < 4; ++m)                               \
          _Pragma("unroll") for (int n = 0; n < 2; ++n)                           \
              _Pragma("unroll") for (int ks = 0; ks < 2; ++ks)                    \
                  acc[m + 4][n + 2] = __builtin_amdgcn_mfma_f32_16x16x32_bf16(    \
                      aq1[m][ks], bq1[n][ks], acc[m + 4][n + 2], 0, 0, 0);        \
      __builtin_amdgcn_s_setprio(0);                                              \
      SBAR();                                                                     \
      if (t + 2 < NT) {                                                           \
        stage_half(Ag + (t + 2) * 64, sA + rp * 2 * 8192, tid);                   \
        stage_half(Ag + 128 * 1024 + (t + 2) * 64, sA + (rp * 2 + 1) * 8192, tid);\
        VMCNT4();                                                                 \
      } else if (t + 1 < NT) {                                                    \
        VMCNT0();                                                                 \
      }                                                                           \
      SBAR();                                                                     \
      __builtin_amdgcn_s_setprio(1);                                              \
      _Pragma("unroll") for (int m = 0; m < 4; ++m)                               \
          _Pragma("unroll") for (int n = 0; n < 2; ++n)                           \
              _Pragma("unroll") for (int ks = 0; ks < 2; ++ks)                    \
                  acc[m + 4][n] = __builtin_amdgcn_mfma_f32_16x16x32_bf16(        \
                      aq1[m][ks], bq0[n][ks], acc[m + 4][n], 0, 0, 0);            \
      __builtin_amdgcn_s_setprio(0);                                              \
      SBAR();                                                                     \
    }                                                                             \
  }

// ---------------- fused Q+K projections: grid (32, 8) = 256 blocks = 1 round.
__global__ __launch_bounds__(512, 2) void gemm_qk(
    const bf16* __restrict__ A, const bf16* __restrict__ Bq,
    const bf16* __restrict__ Bk, bf16* __restrict__ Cq, bf16* __restrict__ Ck) {
  __shared__ bf16 smem[65536];
  const int bm = blockIdx.x, bn = blockIdx.y;
  const int tid = threadIdx.x;
  const int lane = tid & 63;
  const int wid = tid >> 6;
  const int wr = wid >> 2;
  const int wc = wid & 3;
  const int lr = lane & 15;
  const int c16 = lane >> 4;
  const int g = bn >> 2;
  const int bcol = (bn & 3) * 256;
  const int arow = bm * 256;
  const bf16* Ag = A + (long)arow * 1024;
  const bf16* Bg = ((g == 0) ? Bq : Bk) + (long)bcol * 1024;
  bf16* sA = smem;
  bf16* sB = smem + 32768;

  f32x4 acc[8][4] = {};
  LOOP256(Ag, Bg, sA, sB, acc);

  const int r0 = (lane >> 4) * 4;
  bf16* C = (g == 0) ? Cq : Ck;
#pragma unroll
  for (int m = 0; m < 8; ++m)
#pragma unroll
    for (int n = 0; n < 4; ++n)
#pragma unroll
      for (int r = 0; r < 4; ++r)
        C[(long)(arow + wr * 128 + m * 16 + r0 + r) * 1024 + bcol + wc * 64 + n * 16 + lr] =
            __float2bfloat16(acc[m][n][r]);
}

// ---------------- merged V'-projection + scores at 256^2 rate, plain epilogues.
// grid (208): id 0..127 = V'^T = W' @ x^T per batch (b=id>>4, tile id&15);
//             id 128..207 = scores, 10 lower-triangle 256^2 tiles x 8 batches.
__global__ __launch_bounds__(512, 2) void vscore256(
    const bf16* __restrict__ xb, const bf16* __restrict__ Wp,
    bf16* __restrict__ VT, const bf16* __restrict__ Q,
    const bf16* __restrict__ Kb, bf16* __restrict__ P) {
  __shared__ bf16 smem[65536];
  const int id = blockIdx.x;
  const int tid = threadIdx.x;
  const int lane = tid & 63;
  const int wid = tid >> 6;
  const int wr = wid >> 2;
  const int wc = wid & 3;
  const int lr = lane & 15;
  const int c16 = lane >> 4;
  const long SS = 1024L * 1024;

  const bf16 *Ag, *Bg;
  bf16* C;
  int arow, bcol;
  if (id < 128) {
    // V'^T[b][g][s] = sum_d W'[g][d] * x[b][s][d]  (BT, plain store)
    const int b = id >> 4;
    const int tile = id & 15;
    const int gs = tile >> 2, ss = tile & 3;
    arow = gs * 256;
    bcol = ss * 256;
    Ag = Wp + (long)arow * 1024;
    Bg = xb + (long)b * SS + (long)bcol * 1024;
    C = VT + (long)b * SS;
  } else {
    const int sid = id - 128;
    const int bz = sid / 10;
    const int r = sid - bz * 10;           // lower-triangle tile index
    const int bm = (r >= 1) + (r >= 3) + (r >= 6);
    const int bn = r - (bm * (bm + 1)) / 2;
    arow = bm * 256;
    bcol = bn * 256;
    Ag = Q + (long)bz * SS + (long)arow * 1024;
    Bg = Kb + (long)bz * SS + (long)bcol * 1024;
    C = P + (long)bz * SS;
  }
  bf16* sA = smem;
  bf16* sB = smem + 32768;

  f32x4 acc[8][4] = {};
  LOOP256(Ag, Bg, sA, sB, acc);

  const int r0 = (lane >> 4) * 4;
#pragma unroll
  for (int m = 0; m < 8; ++m)
#pragma unroll
    for (int n = 0; n < 4; ++n)
#pragma unroll
      for (int r = 0; r < 4; ++r)
        C[(long)(arow + wr * 128 + m * 16 + r0 + r) * 1024 + bcol + wc * 64 + n * 16 + lr] =
            __float2bfloat16(acc[m][n][r]);
}

// ---------------- W' = wo @ wv, as BT(wob[g][e], wvT[d][e]) -> W'[g][d] bf16.
// 128^2 m97 structure, grid (8,8) = 64 blocks. One-off 2.1 GFLOP.
__global__ __launch_bounds__(256, 2) void wprime(
    const bf16* __restrict__ A, const bf16* __restrict__ B, bf16* __restrict__ C) {
  const int bm = blockIdx.x, bn = blockIdx.y;
  __shared__ bf16 smem[128 * 64 * 2];
  bf16* As = smem;
  bf16* Bs = smem + 128 * 64;
  const int t = threadIdx.x;
  const int lane = t & 63;
  const int wid = t >> 6;
  const int wr = (wid >> 1) * 64;
  const int wc = (wid & 1) * 64;
  const int lr = lane & 15;
  const int lk = (lane >> 4) * 8;
  f32x4 acc[4][4] = {};
  const int arow = bm * 128;
  const int brow = bn * 128;

  for (int k0 = 0; k0 < 1024; k0 += 64) {
#pragma unroll
    for (int p = 0; p < 4; ++p) {
      const int row = p * 32 + (t >> 3);
      const int col = (t & 7) * 8;
      gload_lds16(A + (long)(arow + row) * 1024 + k0 + col, &As[row * 64 + col]);
      gload_lds16(B + (long)(brow + row) * 1024 + k0 + col, &Bs[row * 64 + col]);
    }
    __syncthreads();
#pragma unroll
    for (int kk = 0; kk < 64; kk += 32) {
      short8 a[4], b[4];
#pragma unroll
      for (int m = 0; m < 4; ++m)
        a[m] = *(const short8*)&As[(wr + m * 16 + lr) * 64 + kk + lk];
#pragma unroll
      for (int n = 0; n < 4; ++n)
        b[n] = *(const short8*)&Bs[(wc + n * 16 + lr) * 64 + kk + lk];
#pragma unroll
      for (int m = 0; m < 4; ++m)
#pragma unroll
        for (int n = 0; n < 4; ++n)
          acc[m][n] =
              __builtin_amdgcn_mfma_f32_16x16x32_bf16(a[m], b[n], acc[m][n], 0, 0, 0);
    }
    __syncthreads();
  }
#pragma unroll
  for (int m = 0; m < 4; ++m)
#pragma unroll
    for (int n = 0; n < 4; ++n)
#pragma unroll
      for (int r = 0; r < 4; ++r) {
        const int row = arow + wr + m * 16 + (lane >> 4) * 4 + r;
        const int col = brow + wc + n * 16 + lr;
        C[(long)row * 1024 + col] = __float2bfloat16(acc[m][n][r]);
      }
}

// ---------------- PV: out[b][q][g] = sum_s P[q][s] V'^T[g][s], fp32 -> d_out.
// 128x256 tile, 2-phase counted-vmcnt, causal K-limit. grid (8,4,8) = 256 blocks.
__global__ __launch_bounds__(512, 2) void gemm_pv32(
    const bf16* __restrict__ Pall, const bf16* __restrict__ VTall,
    float* __restrict__ Out) {
  __shared__ bf16 smem[49152];
  const int bm = blockIdx.x, bn = blockIdx.y, bz = blockIdx.z;
  const long SS = 1024L * 1024;
  const bf16* A = Pall + SS * bz;
  const bf16* B = VTall + SS * bz;
  const int tid = threadIdx.x;
  const int lane = tid & 63;
  const int wid = tid >> 6;
  const int wr = wid >> 2;
  const int wc = wid & 3;
  const int lr = lane & 15;
  const int c16 = lane >> 4;
  const int bcol = bn * 256;
  const int arow = bm * 128;
  const int NT = (bm + 1) * 2;  // causal: s < (bm+1)*128
  const bf16* Ag = A + (long)arow * 1024;
  const bf16* Bg = B + (long)bcol * 1024;
  bf16* sA = smem;
  bf16* sB = smem + 16384;

  stage_half(Ag, sA, tid);
  stage_half(Bg, sB, tid);
  stage_half(Bg + 128 * 1024, sB + 8192, tid);
  stage_half(Ag + 64, sA + 8192, tid);
  VMCNT2();
  SBAR();

  f32x4 acc[4][4] = {};
  for (int t = 0; t < NT; ++t) {
    const int rp = t & 1;
    const int sp = rp ^ 1;
    const bf16* As = sA + rp * 8192;
    const bf16* Bs = sB + (rp * 2 + (wc >> 1)) * 8192;
    const int brb = (wc & 1) * 64;
    short8 aq[4][2], b01[2][2], b23[2][2];

#pragma unroll
    for (int m = 0; m < 4; ++m)
#pragma unroll
      for (int ks = 0; ks < 2; ++ks)
        aq[m][ks] = lds_frag(As, wr * 64 + m * 16 + lr, c16 + ks * 4);
#pragma unroll
    for (int n = 0; n < 2; ++n)
#pragma unroll
      for (int ks = 0; ks < 2; ++ks)
        b01[n][ks] = lds_frag(Bs, brb + n * 16 + lr, c16 + ks * 4);
    if (t + 1 < NT) stage_half(Bg + (t + 1) * 64, sB + sp * 2 * 8192, tid);
    SBAR();
    __builtin_amdgcn_s_setprio(1);
#pragma unroll
    for (int m = 0; m < 4; ++m)
#pragma unroll
      for (int n = 0; n < 2; ++n)
#pragma unroll
        for (int ks = 0; ks < 2; ++ks)
          acc[m][n] = __builtin_amdgcn_mfma_f32_16x16x32_bf16(
              aq[m][ks], b01[n][ks], acc[m][n], 0, 0, 0);
    __builtin_amdgcn_s_setprio(0);
    SBAR();

#pragma unroll
    for (int n = 0; n < 2; ++n)
#pragma unroll
      for (int ks = 0; ks < 2; ++ks)
        b23[n][ks] = lds_frag(Bs, brb + (n + 2) * 16 + lr, c16 + ks * 4);
    if (t + 1 < NT)
      stage_half(Bg + 128 * 1024 + (t + 1) * 64, sB + (sp * 2 + 1) * 8192, tid);
    if (t + 2 < NT) {
      stage_half(Ag + (t + 2) * 64, sA + rp * 8192, tid);
      VMCNT2();
    } else if (t + 1 < NT) {
      VMCNT0();
    }
    SBAR();
    __builtin_amdgcn_s_setprio(1);
#pragma unroll
    for (int m = 0; m < 4; ++m)
#pragma unroll
      for (int n = 0; n < 2; ++n)
#pragma unroll
        for (int ks = 0; ks < 2; ++ks)
          acc[m][n + 2] = __builtin_amdgcn_mfma_f32_16x16x32_bf16(
              aq[m][ks], b23[n][ks], acc[m][n + 2], 0, 0, 0);
    __builtin_amdgcn_s_setprio(0);
    SBAR();
  }

  const int r0 = (lane >> 4) * 4;
  float* C = Out + SS * bz;
#pragma unroll
  for (int m = 0; m < 4; ++m)
#pragma unroll
    for (int n = 0; n < 4; ++n)
#pragma unroll
      for (int r = 0; r < 4; ++r)
        C[(long)(arow + wr * 64 + m * 16 + r0 + r) * 1024 + bcol + wc * 64 + n * 16 + lr] =
            acc[m][n][r];
}

// fp32 -> bf16 conversions: x, wq, wk, wo plain; wv transposed (64x64 LDS tiles).
__global__ __launch_bounds__(256) void f2b_all(
    const float* __restrict__ x, const float* __restrict__ wq,
    const float* __restrict__ wk, const float* __restrict__ wo,
    const float* __restrict__ wv, bf16* __restrict__ xb, bf16* __restrict__ wqb,
    bf16* __restrict__ wkb, bf16* __restrict__ wob, bf16* __restrict__ wvTb) {
  __shared__ float T[64][65];
  const int bid = blockIdx.x;
  const int t = threadIdx.x;
  union { bf16 h; short s; } u;

  if (bid >= 5632) {  // wv transpose-convert: wvT[d][e] = wv[e][d]
    const int tr = bid - 5632;         // 0..255
    const int er = tr >> 4, dc = tr & 15;
    const int r = t >> 2, c = (t & 3) * 16;
    const float* src = wv + (long)(er * 64 + r) * 1024 + dc * 64 + c;
#pragma unroll
    for (int j = 0; j < 4; ++j) {
      const float4 v = *(const float4*)(src + j * 4);
      T[r][c + j * 4 + 0] = v.x;
      T[r][c + j * 4 + 1] = v.y;
      T[r][c + j * 4 + 2] = v.z;
      T[r][c + j * 4 + 3] = v.w;
    }
    __syncthreads();
    const int d = t >> 2, ec = (t & 3) * 16;
    bf16* dst = wvTb + (long)(dc * 64 + d) * 1024 + er * 64 + ec;
#pragma unroll
    for (int half = 0; half < 2; ++half) {
      short8 o;
#pragma unroll
      for (int j = 0; j < 8; ++j) {
        u.h = __float2bfloat16(T[ec + half * 8 + j][d]);
        o[j] = u.s;
      }
      *(short8*)(dst + half * 8) = o;
    }
    return;
  }

  const float* src;
  bf16* dst;
  long base;
  if (bid < 4096) {
    src = x; dst = xb; base = (long)bid * 2048;
  } else {
    const int w = (bid - 4096) >> 9;
    base = (long)((bid - 4096) & 511) * 2048;
    src = (w == 0) ? wq : (w == 1) ? wk : wo;
    dst = (w == 0) ? wqb : (w == 1) ? wkb : wob;
  }
  const long i = base + t * 8;
  const float4 a = *(const float4*)&src[i];
  const float4 b = *(const float4*)&src[i + 4];
  const float va[8] = {a.x, a.y, a.z, a.w, b.x, b.y, b.z, b.w};
  short8 o;
#pragma unroll
  for (int j = 0; j < 8; ++j) { u.h = __float2bfloat16(va[j]); o[j] = u.s; }
  *(short8*)&dst[i] = o;
}

// In-place causal softmax over bf16 score rows (applies 1/32 scale).
__global__ __launch_bounds__(256) void softmax_causal(bf16* __restrict__ P, int S) {
  const int q = blockIdx.x;
  const int b = blockIdx.y;
  bf16* row = P + ((long)b * S + q) * S;
  const int t = threadIdx.x;
  const int n = q + 1;
  __shared__ float red[8];
  float v[4];
  float mx = -1e30f;
#pragma unroll
  for (int i = 0; i < 4; ++i) {
    const int k = t + i * 256;
    v[i] = (k < n) ? __bfloat162float(row[k]) * 0.03125f : -1e30f;
    mx = fmaxf(mx, v[i]);
  }
#pragma unroll
  for (int o = 32; o > 0; o >>= 1) mx = fmaxf(mx, __shfl_xor(mx, o, 64));
  if ((t & 63) == 0) red[t >> 6] = mx;
  __syncthreads();
  mx = fmaxf(fmaxf(red[0], red[1]), fmaxf(red[2], red[3]));
  float e[4];
  float s = 0.f;
#pragma unroll
  for (int i = 0; i < 4; ++i) {
    const int k = t + i * 256;
    e[i] = (k < n) ? __expf(v[i] - mx) : 0.f;
    s += e[i];
  }
#pragma unroll
  for (int o = 32; o > 0; o >>= 1) s += __shfl_xor(s, o, 64);
  if ((t & 63) == 0) red[4 + (t >> 6)] = s;
  __syncthreads();
  s = (red[4] + red[5]) + (red[6] + red[7]);
  const float inv = 1.f / s;
#pragma unroll
  for (int i = 0; i < 4; ++i) {
    const int k = t + i * 256;
    row[k] = __float2bfloat16(e[i] * inv);
  }
}

extern "C" void kernel_launch(void* const* d_in, const int* in_sizes, int n_in,
                              void* d_out, int out_size, void* d_ws, size_t ws_size,
                              hipStream_t stream) {
  (void)in_sizes; (void)n_in; (void)out_size; (void)ws_size;
  const float* x  = (const float*)d_in[0];
  const float* wq = (const float*)d_in[1];
  const float* wk = (const float*)d_in[2];
  const float* wv = (const float*)d_in[3];
  const float* wo = (const float*)d_in[4];
  float* out = (float*)d_out;
  bf16* ws = (bf16*)d_ws;

  const long SB = 8192L * 1024;
  const long SW = 1024L * 1024;

  bf16* xb   = ws;                    // [8][s][d]
  bf16* wqb  = ws + SB;
  bf16* wkb  = ws + SB + SW;
  bf16* wob  = ws + SB + 2 * SW;
  bf16* wvTb = ws + SB + 3 * SW;      // wv transposed [d][e]
  bf16* Wp   = ws + SB + 4 * SW;      // W' = wo @ wv  [g][d]
  bf16* Q    = ws + SB + 5 * SW;      // [8][s][d]
  bf16* Kb   = Q + SB;                // [8][s][d]
  bf16* VT   = Q + 2 * SB;            // V'^T [8][g][s]
  bf16* P    = Q + 3 * SB;            // scores / P in place
  // total ws: ~90 MB

  f2b_all<<<dim3(5888), dim3(256), 0, stream>>>(x, wq, wk, wo, wv,
                                                xb, wqb, wkb, wob, wvTb);
  // W' = wo @ wv (64 blocks, one-off)
  wprime<<<dim3(8, 8), dim3(256), 0, stream>>>(wob, wvTb, Wp);
  // Q+K projections: 256 blocks = 1 exact round of 256^2 tiles
  gemm_qk<<<dim3(32, 8), dim3(512), 0, stream>>>(xb, wqb, wkb, Q, Kb);
  // V'^T (128 blocks, plain store) + triangular scores (80 blocks)
  vscore256<<<dim3(208), dim3(512), 0, stream>>>(xb, Wp, VT, Q, Kb, P);
  softmax_causal<<<dim3(1024, 8), dim3(256), 0, stream>>>(P, 1024);
  // out = P @ V' (B = V'^T, causal K-limit), fp32 straight to d_out
  gemm_pv32<<<dim3(8, 4, 8), dim3(512), 0, stream>>>(P, VT, out);
}

// Round 8
// 140.461 us; speedup vs baseline: 1.3028x; 1.0535x over previous
//
#include <hip/hip_runtime.h>
#include <hip/hip_bf16.h>

typedef __hip_bfloat16 bf16;
typedef __attribute__((ext_vector_type(8))) short short8;
typedef __attribute__((ext_vector_type(4))) float f32x4;

#define SBAR() asm volatile("s_barrier" ::: "memory")
#define VMCNT4() asm volatile("s_waitcnt vmcnt(4)" ::: "memory")
#define VMCNT2() asm volatile("s_waitcnt vmcnt(2)" ::: "memory")
#define VMCNT0() asm volatile("s_waitcnt vmcnt(0)" ::: "memory")

__device__ __forceinline__ void gload_lds16(const bf16* g, bf16* l) {
  __builtin_amdgcn_global_load_lds(
      (const __attribute__((address_space(1))) unsigned int*)g,
      (__attribute__((address_space(3))) unsigned int*)l, 16, 0, 0);
}

// Stage one 128x64 half-tile (row-major, ld=1024) into a linear 16KB LDS slot.
// Global source col is XOR-swizzled so swizzled LDS reads are conflict-free.
__device__ __forceinline__ void stage_half(const bf16* gbase, bf16* slot, int tid) {
  const int r = tid >> 3;                    // 0..63
  const int c = ((tid & 7) ^ (r & 7)) << 3;  // swizzled 16B chunk
  gload_lds16(gbase + (long)r * 1024 + c, slot + tid * 8);
  gload_lds16(gbase + (long)(r + 64) * 1024 + c, slot + 4096 + tid * 8);
}

// Swizzled fragment read: logical (row, 16B-chunk c16) of a [128][64] half-slot.
__device__ __forceinline__ short8 lds_frag(const bf16* slot, int row, int c16) {
  return *(const short8*)(slot + row * 64 + ((c16 ^ (row & 7)) << 3));
}

// ======== 256x256-tile 4-phase main loop (T2+T3+T4+T5).
#define LOOP256(Ag, Bg, sA, sB, acc)                                              \
  {                                                                               \
    stage_half(Ag, sA, tid);                                                      \
    stage_half(Ag + 128 * 1024, sA + 8192, tid);                                  \
    stage_half(Bg, sB, tid);                                                      \
    stage_half(Bg + 128 * 1024, sB + 8192, tid);                                  \
    stage_half(Ag + 64, sA + 16384, tid);                                         \
    stage_half(Ag + 128 * 1024 + 64, sA + 24576, tid);                            \
    VMCNT4();                                                                     \
    SBAR();                                                                       \
    const int NT = 16;                                                            \
    for (int t = 0; t < NT; ++t) {                                                \
      const int rp = t & 1;                                                       \
      const bf16* As = sA + (rp * 2 + wr) * 8192;                                 \
      const bf16* Bs = sB + (rp * 2 + (wc >> 1)) * 8192;                          \
      const int brb = (wc & 1) * 64;                                              \
      const int sp2 = (rp ^ 1) * 2;                                               \
      short8 aq0[4][2], aq1[4][2], bq0[2][2], bq1[2][2];                          \
      _Pragma("unroll") for (int m = 0; m < 4; ++m)                               \
          _Pragma("unroll") for (int ks = 0; ks < 2; ++ks)                        \
              aq0[m][ks] = lds_frag(As, m * 16 + lr, c16 + ks * 4);               \
      _Pragma("unroll") for (int n = 0; n < 2; ++n)                               \
          _Pragma("unroll") for (int ks = 0; ks < 2; ++ks)                        \
              bq0[n][ks] = lds_frag(Bs, brb + n * 16 + lr, c16 + ks * 4);         \
      if (t + 1 < NT) stage_half(Bg + (t + 1) * 64, sB + sp2 * 8192, tid);        \
      SBAR();                                                                     \
      __builtin_amdgcn_s_setprio(1);                                              \
      _Pragma("unroll") for (int m = 0; m < 4; ++m)                               \
          _Pragma("unroll") for (int n = 0; n < 2; ++n)                           \
              _Pragma("unroll") for (int ks = 0; ks < 2; ++ks)                    \
                  acc[m][n] = __builtin_amdgcn_mfma_f32_16x16x32_bf16(            \
                      aq0[m][ks], bq0[n][ks], acc[m][n], 0, 0, 0);                \
      __builtin_amdgcn_s_setprio(0);                                              \
      SBAR();                                                                     \
      _Pragma("unroll") for (int n = 0; n < 2; ++n)                               \
          _Pragma("unroll") for (int ks = 0; ks < 2; ++ks)                        \
              bq1[n][ks] = lds_frag(Bs, brb + (n + 2) * 16 + lr, c16 + ks * 4);   \
      if (t + 1 < NT)                                                             \
        stage_half(Bg + 128 * 1024 + (t + 1) * 64, sB + (sp2 + 1) * 8192, tid);   \
      SBAR();                                                                     \
      __builtin_amdgcn_s_setprio(1);                                              \
      _Pragma("unroll") for (int m = 0; m < 4; ++m)                               \
          _Pragma("unroll") for (int n = 0; n < 2; ++n)                           \
              _Pragma("unroll") for (int ks = 0; ks < 2; ++ks)                    \
                  acc[m][n + 2] = __builtin_amdgcn_mfma_f32_16x16x32_bf16(        \
                      aq0[m][ks], bq1[n][ks], acc[m][n + 2], 0, 0, 0);            \
      __builtin_amdgcn_s_setprio(0);                                              \
      SBAR();                                                                     \
      _Pragma("unroll") for (int m = 0; m < 4; ++m)                               \
          _Pragma("unroll") for (int ks = 0; ks < 2; ++ks)                        \
              aq1[m][ks] = lds_frag(As, (m + 4) * 16 + lr, c16 + ks * 4);         \
      SBAR();                                                                     \
      __builtin_amdgcn_s_setprio(1);                                              \
      _Pragma("unroll") for (int m = 0; m < 4; ++m)                               \
          _Pragma("unroll") for (int n = 0; n < 2; ++n)                           \
              _Pragma("unroll") for (int ks = 0; ks < 2; ++ks)                    \
                  acc[m + 4][n + 2] = __builtin_amdgcn_mfma_f32_16x16x32_bf16(    \
                      aq1[m][ks], bq1[n][ks], acc[m + 4][n + 2], 0, 0, 0);        \
      __builtin_amdgcn_s_setprio(0);                                              \
      SBAR();                                                                     \
      if (t + 2 < NT) {                                                           \
        stage_half(Ag + (t + 2) * 64, sA + rp * 2 * 8192, tid);                   \
        stage_half(Ag + 128 * 1024 + (t + 2) * 64, sA + (rp * 2 + 1) * 8192, tid);\
        VMCNT4();                                                                 \
      } else if (t + 1 < NT) {                                                    \
        VMCNT0();                                                                 \
      }                                                                           \
      SBAR();                                                                     \
      __builtin_amdgcn_s_setprio(1);                                              \
      _Pragma("unroll") for (int m = 0; m < 4; ++m)                               \
          _Pragma("unroll") for (int n = 0; n < 2; ++n)                           \
              _Pragma("unroll") for (int ks = 0; ks < 2; ++ks)                    \
                  acc[m + 4][n] = __builtin_amdgcn_mfma_f32_16x16x32_bf16(        \
                      aq1[m][ks], bq0[n][ks], acc[m + 4][n], 0, 0, 0);            \
      __builtin_amdgcn_s_setprio(0);                                              \
      SBAR();                                                                     \
    }                                                                             \
  }

// ---------------- merged G-projection + V'-projection at 256^2 rate.
// id 0..127:  G = BT(xb, M')   [8192 x 1024], bm=id>>2, bn=id&3
// id 128..255: V'^T = BT(W', xb_b) per batch (b=(id-128)>>4, tile (id-128)&15)
__global__ __launch_bounds__(512, 2) void gemm_gv(
    const bf16* __restrict__ xb, const bf16* __restrict__ Mp,
    const bf16* __restrict__ Wp, bf16* __restrict__ G, bf16* __restrict__ VT) {
  __shared__ bf16 smem[65536];
  const int id = blockIdx.x;
  const int tid = threadIdx.x;
  const int lane = tid & 63;
  const int wid = tid >> 6;
  const int wr = wid >> 2;
  const int wc = wid & 3;
  const int lr = lane & 15;
  const int c16 = lane >> 4;
  const long SS = 1024L * 1024;

  const bf16 *Ag, *Bg;
  bf16* C;
  int arow, bcol;
  if (id < 128) {
    const int bm = id >> 2, bn = id & 3;
    arow = bm * 256;
    bcol = bn * 256;
    Ag = xb + (long)arow * 1024;
    Bg = Mp + (long)bcol * 1024;
    C = G;
  } else {
    const int v = id - 128;
    const int b = v >> 4;
    const int gs = (v & 15) >> 2, ss = v & 3;
    arow = gs * 256;
    bcol = ss * 256;
    Ag = Wp + (long)arow * 1024;
    Bg = xb + (long)b * SS + (long)bcol * 1024;
    C = VT + (long)b * SS;
  }
  bf16* sA = smem;
  bf16* sB = smem + 32768;

  f32x4 acc[8][4] = {};
  LOOP256(Ag, Bg, sA, sB, acc);

  const int r0 = (lane >> 4) * 4;
#pragma unroll
  for (int m = 0; m < 8; ++m)
#pragma unroll
    for (int n = 0; n < 4; ++n)
#pragma unroll
      for (int r = 0; r < 4; ++r)
        C[(long)(arow + wr * 128 + m * 16 + r0 + r) * 1024 + bcol + wc * 64 + n * 16 + lr] =
            __float2bfloat16(acc[m][n][r]);
}

// ---------------- small GEMMs M' and W', split-K x2, fp32 partials.
// grid 256: mat = id>>7 (0: M'=BT(wkT,wqT), 1: W'=BT(wo,wvT)),
//           chunk = (id>>6)&1 (K half), tile = id&63 (bm=tile>>3, bn=tile&7).
__global__ __launch_bounds__(256, 2) void small_w(
    const bf16* __restrict__ wkT, const bf16* __restrict__ wqT,
    const bf16* __restrict__ wo, const bf16* __restrict__ wvT,
    float* __restrict__ part) {
  const int id = blockIdx.x;
  const int mat = id >> 7;
  const int chunk = (id >> 6) & 1;
  const int tile = id & 63;
  const int bm = tile >> 3, bn = tile & 7;
  const bf16* A = (mat == 0) ? wkT : wo;
  const bf16* B = (mat == 0) ? wqT : wvT;
  float* C = part + (long)(mat * 2 + chunk) * (1024L * 1024);

  __shared__ bf16 smem[128 * 64 * 2];
  bf16* As = smem;
  bf16* Bs = smem + 128 * 64;
  const int t = threadIdx.x;
  const int lane = t & 63;
  const int wid = t >> 6;
  const int wr = (wid >> 1) * 64;
  const int wc = (wid & 1) * 64;
  const int lr = lane & 15;
  const int lk = (lane >> 4) * 8;
  f32x4 acc[4][4] = {};
  const int arow = bm * 128;
  const int brow = bn * 128;
  const int k0base = chunk * 512;

  for (int k0 = k0base; k0 < k0base + 512; k0 += 64) {
#pragma unroll
    for (int p = 0; p < 4; ++p) {
      const int row = p * 32 + (t >> 3);
      const int col = (t & 7) * 8;
      gload_lds16(A + (long)(arow + row) * 1024 + k0 + col, &As[row * 64 + col]);
      gload_lds16(B + (long)(brow + row) * 1024 + k0 + col, &Bs[row * 64 + col]);
    }
    __syncthreads();
#pragma unroll
    for (int kk = 0; kk < 64; kk += 32) {
      short8 a[4], b[4];
#pragma unroll
      for (int m = 0; m < 4; ++m)
        a[m] = *(const short8*)&As[(wr + m * 16 + lr) * 64 + kk + lk];
#pragma unroll
      for (int n = 0; n < 4; ++n)
        b[n] = *(const short8*)&Bs[(wc + n * 16 + lr) * 64 + kk + lk];
#pragma unroll
      for (int m = 0; m < 4; ++m)
#pragma unroll
        for (int n = 0; n < 4; ++n)
          acc[m][n] =
              __builtin_amdgcn_mfma_f32_16x16x32_bf16(a[m], b[n], acc[m][n], 0, 0, 0);
    }
    __syncthreads();
  }
#pragma unroll
  for (int m = 0; m < 4; ++m)
#pragma unroll
    for (int n = 0; n < 4; ++n)
#pragma unroll
      for (int r = 0; r < 4; ++r) {
        const int row = arow + wr + m * 16 + (lane >> 4) * 4 + r;
        const int col = brow + wc + n * 16 + lr;
        C[(long)row * 1024 + col] = acc[m][n][r];
      }
}

// ---------------- sum split-K partials, convert to bf16 M' / W'.
__global__ __launch_bounds__(256) void reduce_w(
    const float* __restrict__ part, bf16* __restrict__ Mp, bf16* __restrict__ Wp) {
  const long i = ((long)blockIdx.x * 256 + threadIdx.x) * 8;  // 0 .. 2M
  const long M1 = 1024L * 1024;
  const int mat = (i >= M1) ? 1 : 0;
  const long e = i - (long)mat * M1;
  const float* p0 = part + (long)(mat * 2) * M1 + e;
  const float* p1 = p0 + M1;
  bf16* dst = (mat ? Wp : Mp) + e;
  const float4 a0 = *(const float4*)p0;
  const float4 a1 = *(const float4*)(p0 + 4);
  const float4 b0 = *(const float4*)p1;
  const float4 b1 = *(const float4*)(p1 + 4);
  const float v[8] = {a0.x + b0.x, a0.y + b0.y, a0.z + b0.z, a0.w + b0.w,
                      a1.x + b1.x, a1.y + b1.y, a1.z + b1.z, a1.w + b1.w};
  union { bf16 h; short s; } u;
  short8 o;
#pragma unroll
  for (int j = 0; j < 8; ++j) { u.h = __float2bfloat16(v[j]); o[j] = u.s; }
  *(short8*)dst = o;
}

// ---------------- scores = BT(G_b, xb_b), causal 128x256 tiles, bf16 -> P.
// grid 160: bz = id/20, r = id%20 -> (bm 0..7, bn 0..bm/2). NT=16 (full d-sum).
__global__ __launch_bounds__(512, 2) void gemm_sc(
    const bf16* __restrict__ Gall, const bf16* __restrict__ xball,
    bf16* __restrict__ Pall) {
  __shared__ bf16 smem[49152];
  const int id = blockIdx.x;
  const int bz = id / 20;
  int rr = id - bz * 20, bm = 0;
  while (rr >= bm / 2 + 1) { rr -= bm / 2 + 1; ++bm; }
  const int bn = rr;
  const long SS = 1024L * 1024;
  const bf16* A = Gall + SS * bz;
  const bf16* B = xball + SS * bz;
  const int tid = threadIdx.x;
  const int lane = tid & 63;
  const int wid = tid >> 6;
  const int wr = wid >> 2;
  const int wc = wid & 3;
  const int lr = lane & 15;
  const int c16 = lane >> 4;
  const int bcol = bn * 256;
  const int arow = bm * 128;
  const int NT = 16;
  const bf16* Ag = A + (long)arow * 1024;
  const bf16* Bg = B + (long)bcol * 1024;
  bf16* sA = smem;
  bf16* sB = smem + 16384;

  stage_half(Ag, sA, tid);
  stage_half(Bg, sB, tid);
  stage_half(Bg + 128 * 1024, sB + 8192, tid);
  stage_half(Ag + 64, sA + 8192, tid);
  VMCNT2();
  SBAR();

  f32x4 acc[4][4] = {};
  for (int t = 0; t < NT; ++t) {
    const int rp = t & 1;
    const int sp = rp ^ 1;
    const bf16* As = sA + rp * 8192;
    const bf16* Bs = sB + (rp * 2 + (wc >> 1)) * 8192;
    const int brb = (wc & 1) * 64;
    short8 aq[4][2], b01[2][2], b23[2][2];
#pragma unroll
    for (int m = 0; m < 4; ++m)
#pragma unroll
      for (int ks = 0; ks < 2; ++ks)
        aq[m][ks] = lds_frag(As, wr * 64 + m * 16 + lr, c16 + ks * 4);
#pragma unroll
    for (int n = 0; n < 2; ++n)
#pragma unroll
      for (int ks = 0; ks < 2; ++ks)
        b01[n][ks] = lds_frag(Bs, brb + n * 16 + lr, c16 + ks * 4);
    if (t + 1 < NT) stage_half(Bg + (t + 1) * 64, sB + sp * 2 * 8192, tid);
    SBAR();
    __builtin_amdgcn_s_setprio(1);
#pragma unroll
    for (int m = 0; m < 4; ++m)
#pragma unroll
      for (int n = 0; n < 2; ++n)
#pragma unroll
        for (int ks = 0; ks < 2; ++ks)
          acc[m][n] = __builtin_amdgcn_mfma_f32_16x16x32_bf16(
              aq[m][ks], b01[n][ks], acc[m][n], 0, 0, 0);
    __builtin_amdgcn_s_setprio(0);
    SBAR();
#pragma unroll
    for (int n = 0; n < 2; ++n)
#pragma unroll
      for (int ks = 0; ks < 2; ++ks)
        b23[n][ks] = lds_frag(Bs, brb + (n + 2) * 16 + lr, c16 + ks * 4);
    if (t + 1 < NT)
      stage_half(Bg + 128 * 1024 + (t + 1) * 64, sB + (sp * 2 + 1) * 8192, tid);
    if (t + 2 < NT) {
      stage_half(Ag + (t + 2) * 64, sA + rp * 8192, tid);
      VMCNT2();
    } else if (t + 1 < NT) {
      VMCNT0();
    }
    SBAR();
    __builtin_amdgcn_s_setprio(1);
#pragma unroll
    for (int m = 0; m < 4; ++m)
#pragma unroll
      for (int n = 0; n < 2; ++n)
#pragma unroll
        for (int ks = 0; ks < 2; ++ks)
          acc[m][n + 2] = __builtin_amdgcn_mfma_f32_16x16x32_bf16(
              aq[m][ks], b23[n][ks], acc[m][n + 2], 0, 0, 0);
    __builtin_amdgcn_s_setprio(0);
    SBAR();
  }

  const int r0 = (lane >> 4) * 4;
  bf16* C = Pall + SS * bz;
#pragma unroll
  for (int m = 0; m < 4; ++m)
#pragma unroll
    for (int n = 0; n < 4; ++n)
#pragma unroll
      for (int r = 0; r < 4; ++r)
        C[(long)(arow + wr * 64 + m * 16 + r0 + r) * 1024 + bcol + wc * 64 + n * 16 + lr] =
            __float2bfloat16(acc[m][n][r]);
}

// ---------------- PV: out[b][q][g] = sum_s P[q][s] V'^T[g][s], fp32 -> d_out.
__global__ __launch_bounds__(512, 2) void gemm_pv32(
    const bf16* __restrict__ Pall, const bf16* __restrict__ VTall,
    float* __restrict__ Out) {
  __shared__ bf16 smem[49152];
  const int bm = blockIdx.x, bn = blockIdx.y, bz = blockIdx.z;
  const long SS = 1024L * 1024;
  const bf16* A = Pall + SS * bz;
  const bf16* B = VTall + SS * bz;
  const int tid = threadIdx.x;
  const int lane = tid & 63;
  const int wid = tid >> 6;
  const int wr = wid >> 2;
  const int wc = wid & 3;
  const int lr = lane & 15;
  const int c16 = lane >> 4;
  const int bcol = bn * 256;
  const int arow = bm * 128;
  const int NT = (bm + 1) * 2;  // causal: s < (bm+1)*128
  const bf16* Ag = A + (long)arow * 1024;
  const bf16* Bg = B + (long)bcol * 1024;
  bf16* sA = smem;
  bf16* sB = smem + 16384;

  stage_half(Ag, sA, tid);
  stage_half(Bg, sB, tid);
  stage_half(Bg + 128 * 1024, sB + 8192, tid);
  stage_half(Ag + 64, sA + 8192, tid);
  VMCNT2();
  SBAR();

  f32x4 acc[4][4] = {};
  for (int t = 0; t < NT; ++t) {
    const int rp = t & 1;
    const int sp = rp ^ 1;
    const bf16* As = sA + rp * 8192;
    const bf16* Bs = sB + (rp * 2 + (wc >> 1)) * 8192;
    const int brb = (wc & 1) * 64;
    short8 aq[4][2], b01[2][2], b23[2][2];
#pragma unroll
    for (int m = 0; m < 4; ++m)
#pragma unroll
      for (int ks = 0; ks < 2; ++ks)
        aq[m][ks] = lds_frag(As, wr * 64 + m * 16 + lr, c16 + ks * 4);
#pragma unroll
    for (int n = 0; n < 2; ++n)
#pragma unroll
      for (int ks = 0; ks < 2; ++ks)
        b01[n][ks] = lds_frag(Bs, brb + n * 16 + lr, c16 + ks * 4);
    if (t + 1 < NT) stage_half(Bg + (t + 1) * 64, sB + sp * 2 * 8192, tid);
    SBAR();
    __builtin_amdgcn_s_setprio(1);
#pragma unroll
    for (int m = 0; m < 4; ++m)
#pragma unroll
      for (int n = 0; n < 2; ++n)
#pragma unroll
        for (int ks = 0; ks < 2; ++ks)
          acc[m][n] = __builtin_amdgcn_mfma_f32_16x16x32_bf16(
              aq[m][ks], b01[n][ks], acc[m][n], 0, 0, 0);
    __builtin_amdgcn_s_setprio(0);
    SBAR();
#pragma unroll
    for (int n = 0; n < 2; ++n)
#pragma unroll
      for (int ks = 0; ks < 2; ++ks)
        b23[n][ks] = lds_frag(Bs, brb + (n + 2) * 16 + lr, c16 + ks * 4);
    if (t + 1 < NT)
      stage_half(Bg + 128 * 1024 + (t + 1) * 64, sB + (sp * 2 + 1) * 8192, tid);
    if (t + 2 < NT) {
      stage_half(Ag + (t + 2) * 64, sA + rp * 8192, tid);
      VMCNT2();
    } else if (t + 1 < NT) {
      VMCNT0();
    }
    SBAR();
    __builtin_amdgcn_s_setprio(1);
#pragma unroll
    for (int m = 0; m < 4; ++m)
#pragma unroll
      for (int n = 0; n < 2; ++n)
#pragma unroll
        for (int ks = 0; ks < 2; ++ks)
          acc[m][n + 2] = __builtin_amdgcn_mfma_f32_16x16x32_bf16(
              aq[m][ks], b23[n][ks], acc[m][n + 2], 0, 0, 0);
    __builtin_amdgcn_s_setprio(0);
    SBAR();
  }

  const int r0 = (lane >> 4) * 4;
  float* C = Out + SS * bz;
#pragma unroll
  for (int m = 0; m < 4; ++m)
#pragma unroll
    for (int n = 0; n < 4; ++n)
#pragma unroll
      for (int r = 0; r < 4; ++r)
        C[(long)(arow + wr * 64 + m * 16 + r0 + r) * 1024 + bcol + wc * 64 + n * 16 + lr] =
            acc[m][n][r];
}

// fp32 -> bf16: x, wo plain; wq, wk, wv transposed (64x64 LDS tiles).
__global__ __launch_bounds__(256) void f2b_all(
    const float* __restrict__ x, const float* __restrict__ wo,
    const float* __restrict__ wq, const float* __restrict__ wk,
    const float* __restrict__ wv, bf16* __restrict__ xb, bf16* __restrict__ wob,
    bf16* __restrict__ wqTb, bf16* __restrict__ wkTb, bf16* __restrict__ wvTb) {
  __shared__ float T[64][65];
  const int bid = blockIdx.x;
  const int t = threadIdx.x;
  union { bf16 h; short s; } u;

  if (bid >= 4608) {  // transpose-convert: wT[d][e] = w[e][d]
    const int tr = bid - 4608;         // 0..767
    const int mat = tr >> 8;           // 0 wq, 1 wk, 2 wv
    const int tile = tr & 255;
    const int er = tile >> 4, dc = tile & 15;
    const float* src = ((mat == 0) ? wq : (mat == 1) ? wk : wv);
    bf16* dstb = ((mat == 0) ? wqTb : (mat == 1) ? wkTb : wvTb);
    const int r = t >> 2, c = (t & 3) * 16;
    const float* s0 = src + (long)(er * 64 + r) * 1024 + dc * 64 + c;
#pragma unroll
    for (int j = 0; j < 4; ++j) {
      const float4 v = *(const float4*)(s0 + j * 4);
      T[r][c + j * 4 + 0] = v.x;
      T[r][c + j * 4 + 1] = v.y;
      T[r][c + j * 4 + 2] = v.z;
      T[r][c + j * 4 + 3] = v.w;
    }
    __syncthreads();
    const int d = t >> 2, ec = (t & 3) * 16;
    bf16* dst = dstb + (long)(dc * 64 + d) * 1024 + er * 64 + ec;
#pragma unroll
    for (int half = 0; half < 2; ++half) {
      short8 o;
#pragma unroll
      for (int j = 0; j < 8; ++j) {
        u.h = __float2bfloat16(T[ec + half * 8 + j][d]);
        o[j] = u.s;
      }
      *(short8*)(dst + half * 8) = o;
    }
    return;
  }

  const float* src;
  bf16* dst;
  long base;
  if (bid < 4096) {
    src = x; dst = xb; base = (long)bid * 2048;
  } else {
    src = wo; dst = wob; base = (long)(bid - 4096) * 2048;
  }
  const long i = base + t * 8;
  const float4 a = *(const float4*)&src[i];
  const float4 b = *(const float4*)&src[i + 4];
  const float va[8] = {a.x, a.y, a.z, a.w, b.x, b.y, b.z, b.w};
  short8 o;
#pragma unroll
  for (int j = 0; j < 8; ++j) { u.h = __float2bfloat16(va[j]); o[j] = u.s; }
  *(short8*)&dst[i] = o;
}

// In-place causal softmax over bf16 score rows (applies 1/32 scale).
__global__ __launch_bounds__(256) void softmax_causal(bf16* __restrict__ P, int S) {
  const int q = blockIdx.x;
  const int b = blockIdx.y;
  bf16* row = P + ((long)b * S + q) * S;
  const int t = threadIdx.x;
  const int n = q + 1;
  __shared__ float red[8];
  float v[4];
  float mx = -1e30f;
#pragma unroll
  for (int i = 0; i < 4; ++i) {
    const int k = t + i * 256;
    v[i] = (k < n) ? __bfloat162float(row[k]) * 0.03125f : -1e30f;
    mx = fmaxf(mx, v[i]);
  }
#pragma unroll
  for (int o = 32; o > 0; o >>= 1) mx = fmaxf(mx, __shfl_xor(mx, o, 64));
  if ((t & 63) == 0) red[t >> 6] = mx;
  __syncthreads();
  mx = fmaxf(fmaxf(red[0], red[1]), fmaxf(red[2], red[3]));
  float e[4];
  float s = 0.f;
#pragma unroll
  for (int i = 0; i < 4; ++i) {
    const int k = t + i * 256;
    e[i] = (k < n) ? __expf(v[i] - mx) : 0.f;
    s += e[i];
  }
#pragma unroll
  for (int o = 32; o > 0; o >>= 1) s += __shfl_xor(s, o, 64);
  if ((t & 63) == 0) red[4 + (t >> 6)] = s;
  __syncthreads();
  s = (red[4] + red[5]) + (red[6] + red[7]);
  const float inv = 1.f / s;
#pragma unroll
  for (int i = 0; i < 4; ++i) {
    const int k = t + i * 256;
    row[k] = __float2bfloat16(e[i] * inv);
  }
}

extern "C" void kernel_launch(void* const* d_in, const int* in_sizes, int n_in,
                              void* d_out, int out_size, void* d_ws, size_t ws_size,
                              hipStream_t stream) {
  (void)in_sizes; (void)n_in; (void)out_size; (void)ws_size;
  const float* x  = (const float*)d_in[0];
  const float* wq = (const float*)d_in[1];
  const float* wk = (const float*)d_in[2];
  const float* wv = (const float*)d_in[3];
  const float* wo = (const float*)d_in[4];
  float* out = (float*)d_out;
  bf16* ws = (bf16*)d_ws;

  const long SB = 8192L * 1024;
  const long SW = 1024L * 1024;

  bf16* xb   = ws;                    // [8][s][d]     16.8 MB
  bf16* wqTb = ws + SB;               // wq^T [d][e]
  bf16* wkTb = ws + SB + SW;          // wk^T [d][e]
  bf16* wvTb = ws + SB + 2 * SW;      // wv^T [d][e]
  bf16* wob  = ws + SB + 3 * SW;      // wo   [g][e]
  bf16* Mp   = ws + SB + 4 * SW;      // M'[d'][d] = sum_e wk[e,d'] wq[e,d]
  bf16* Wp   = ws + SB + 5 * SW;      // W'[g][d]  = sum_e wo[g,e] wv[e,d]
  bf16* G    = ws + SB + 6 * SW;      // [8192][1024]
  bf16* VT   = G + SB;                // V'^T [8][g][s]
  bf16* P    = VT + SB;               // scores / P in place
  float* part = (float*)P;            // split-K partials (16 MB, dead before P)
  // total ws: ~80 MB

  f2b_all<<<dim3(5376), dim3(256), 0, stream>>>(x, wo, wq, wk, wv,
                                                xb, wob, wqTb, wkTb, wvTb);
  // M' and W' (split-K x2, fp32 partials) then reduce+convert
  small_w<<<dim3(256), dim3(256), 0, stream>>>(wkTb, wqTb, wob, wvTb, part);
  reduce_w<<<dim3(1024), dim3(256), 0, stream>>>(part, Mp, Wp);
  // G = x M'  and  V'^T = W' x^T : 256 blocks = 1 exact 256^2 round
  gemm_gv<<<dim3(256), dim3(512), 0, stream>>>(xb, Mp, Wp, G, VT);
  // scores = G x^T, causal 128x256 tiles (20 per batch)
  gemm_sc<<<dim3(160), dim3(512), 0, stream>>>(G, xb, P);
  softmax_causal<<<dim3(1024, 8), dim3(256), 0, stream>>>(P, 1024);
  // out = P @ V' (causal K-limit), fp32 straight to d_out
  gemm_pv32<<<dim3(8, 4, 8), dim3(512), 0, stream>>>(P, VT, out);
}

// Round 9
// 132.265 us; speedup vs baseline: 1.3836x; 1.0620x over previous
//
#include <hip/hip_runtime.h>
#include <hip/hip_bf16.h>

typedef __hip_bfloat16 bf16;
typedef __attribute__((ext_vector_type(8))) short short8;
typedef __attribute__((ext_vector_type(4))) float f32x4;

#define SBAR() asm volatile("s_barrier" ::: "memory")
#define VMCNT4() asm volatile("s_waitcnt vmcnt(4)" ::: "memory")
#define VMCNT2() asm volatile("s_waitcnt vmcnt(2)" ::: "memory")
#define VMCNT0() asm volatile("s_waitcnt vmcnt(0)" ::: "memory")

__device__ __forceinline__ void gload_lds16(const bf16* g, bf16* l) {
  __builtin_amdgcn_global_load_lds(
      (const __attribute__((address_space(1))) unsigned int*)g,
      (__attribute__((address_space(3))) unsigned int*)l, 16, 0, 0);
}

// Stage one 128x64 half-tile (row-major, ld=1024) into a linear 16KB LDS slot.
// Global source col is XOR-swizzled so swizzled LDS reads are conflict-free.
__device__ __forceinline__ void stage_half(const bf16* gbase, bf16* slot, int tid) {
  const int r = tid >> 3;                    // 0..63
  const int c = ((tid & 7) ^ (r & 7)) << 3;  // swizzled 16B chunk
  gload_lds16(gbase + (long)r * 1024 + c, slot + tid * 8);
  gload_lds16(gbase + (long)(r + 64) * 1024 + c, slot + 4096 + tid * 8);
}

// Swizzled fragment read: logical (row, 16B-chunk c16) of a [128][64] half-slot.
__device__ __forceinline__ short8 lds_frag(const bf16* slot, int row, int c16) {
  return *(const short8*)(slot + row * 64 + ((c16 ^ (row & 7)) << 3));
}

// ======== 256x256-tile 4-phase main loop (T2+T3+T4+T5).
#define LOOP256(Ag, Bg, sA, sB, acc)                                              \
  {                                                                               \
    stage_half(Ag, sA, tid);                                                      \
    stage_half(Ag + 128 * 1024, sA + 8192, tid);                                  \
    stage_half(Bg, sB, tid);                                                      \
    stage_half(Bg + 128 * 1024, sB + 8192, tid);                                  \
    stage_half(Ag + 64, sA + 16384, tid);                                         \
    stage_half(Ag + 128 * 1024 + 64, sA + 24576, tid);                            \
    VMCNT4();                                                                     \
    SBAR();                                                                       \
    const int NT = 16;                                                            \
    for (int t = 0; t < NT; ++t) {                                                \
      const int rp = t & 1;                                                       \
      const bf16* As = sA + (rp * 2 + wr) * 8192;                                 \
      const bf16* Bs = sB + (rp * 2 + (wc >> 1)) * 8192;                          \
      const int brb = (wc & 1) * 64;                                              \
      const int sp2 = (rp ^ 1) * 2;                                               \
      short8 aq0[4][2], aq1[4][2], bq0[2][2], bq1[2][2];                          \
      _Pragma("unroll") for (int m = 0; m < 4; ++m)                               \
          _Pragma("unroll") for (int ks = 0; ks < 2; ++ks)                        \
              aq0[m][ks] = lds_frag(As, m * 16 + lr, c16 + ks * 4);               \
      _Pragma("unroll") for (int n = 0; n < 2; ++n)                               \
          _Pragma("unroll") for (int ks = 0; ks < 2; ++ks)                        \
              bq0[n][ks] = lds_frag(Bs, brb + n * 16 + lr, c16 + ks * 4);         \
      if (t + 1 < NT) stage_half(Bg + (t + 1) * 64, sB + sp2 * 8192, tid);        \
      SBAR();                                                                     \
      __builtin_amdgcn_s_setprio(1);                                              \
      _Pragma("unroll") for (int m = 0; m < 4; ++m)                               \
          _Pragma("unroll") for (int n = 0; n < 2; ++n)                           \
              _Pragma("unroll") for (int ks = 0; ks < 2; ++ks)                    \
                  acc[m][n] = __builtin_amdgcn_mfma_f32_16x16x32_bf16(            \
                      aq0[m][ks], bq0[n][ks], acc[m][n], 0, 0, 0);                \
      __builtin_amdgcn_s_setprio(0);                                              \
      SBAR();                                                                     \
      _Pragma("unroll") for (int n = 0; n < 2; ++n)                               \
          _Pragma("unroll") for (int ks = 0; ks < 2; ++ks)                        \
              bq1[n][ks] = lds_frag(Bs, brb + (n + 2) * 16 + lr, c16 + ks * 4);   \
      if (t + 1 < NT)                                                             \
        stage_half(Bg + 128 * 1024 + (t + 1) * 64, sB + (sp2 + 1) * 8192, tid);   \
      SBAR();                                                                     \
      __builtin_amdgcn_s_setprio(1);                                              \
      _Pragma("unroll") for (int m = 0; m < 4; ++m)                               \
          _Pragma("unroll") for (int n = 0; n < 2; ++n)                           \
              _Pragma("unroll") for (int ks = 0; ks < 2; ++ks)                    \
                  acc[m][n + 2] = __builtin_amdgcn_mfma_f32_16x16x32_bf16(        \
                      aq0[m][ks], bq1[n][ks], acc[m][n + 2], 0, 0, 0);            \
      __builtin_amdgcn_s_setprio(0);                                              \
      SBAR();                                                                     \
      _Pragma("unroll") for (int m = 0; m < 4; ++m)                               \
          _Pragma("unroll") for (int ks = 0; ks < 2; ++ks)                        \
              aq1[m][ks] = lds_frag(As, (m + 4) * 16 + lr, c16 + ks * 4);         \
      SBAR();                                                                     \
      __builtin_amdgcn_s_setprio(1);                                              \
      _Pragma("unroll") for (int m = 0; m < 4; ++m)                               \
          _Pragma("unroll") for (int n = 0; n < 2; ++n)                           \
              _Pragma("unroll") for (int ks = 0; ks < 2; ++ks)                    \
                  acc[m + 4][n + 2] = __builtin_amdgcn_mfma_f32_16x16x32_bf16(    \
                      aq1[m][ks], bq1[n][ks], acc[m + 4][n + 2], 0, 0, 0);        \
      __builtin_amdgcn_s_setprio(0);                                              \
      SBAR();                                                                     \
      if (t + 2 < NT) {                                                           \
        stage_half(Ag + (t + 2) * 64, sA + rp * 2 * 8192, tid);                   \
        stage_half(Ag + 128 * 1024 + (t + 2) * 64, sA + (rp * 2 + 1) * 8192, tid);\
        VMCNT4();                                                                 \
      } else if (t + 1 < NT) {                                                    \
        VMCNT0();                                                                 \
      }                                                                           \
      SBAR();                                                                     \
      __builtin_amdgcn_s_setprio(1);                                              \
      _Pragma("unroll") for (int m = 0; m < 4; ++m)                               \
          _Pragma("unroll") for (int n = 0; n < 2; ++n)                           \
              _Pragma("unroll") for (int ks = 0; ks < 2; ++ks)                    \
                  acc[m + 4][n] = __builtin_amdgcn_mfma_f32_16x16x32_bf16(        \
                      aq1[m][ks], bq0[n][ks], acc[m + 4][n], 0, 0, 0);            \
      __builtin_amdgcn_s_setprio(0);                                              \
      SBAR();                                                                     \
    }                                                                             \
  }

// ---------------- merged G-projection + V'-projection at 256^2 rate.
// id 0..127:  G = BT(xb, M')   [8192 x 1024], bm=id>>2, bn=id&3
// id 128..255: V'^T = BT(W', xb_b) per batch (b=(id-128)>>4, tile (id-128)&15)
__global__ __launch_bounds__(512, 2) void gemm_gv(
    const bf16* __restrict__ xb, const bf16* __restrict__ Mp,
    const bf16* __restrict__ Wp, bf16* __restrict__ G, bf16* __restrict__ VT) {
  __shared__ bf16 smem[65536];
  const int id = blockIdx.x;
  const int tid = threadIdx.x;
  const int lane = tid & 63;
  const int wid = tid >> 6;
  const int wr = wid >> 2;
  const int wc = wid & 3;
  const int lr = lane & 15;
  const int c16 = lane >> 4;
  const long SS = 1024L * 1024;

  const bf16 *Ag, *Bg;
  bf16* C;
  int arow, bcol;
  if (id < 128) {
    const int bm = id >> 2, bn = id & 3;
    arow = bm * 256;
    bcol = bn * 256;
    Ag = xb + (long)arow * 1024;
    Bg = Mp + (long)bcol * 1024;
    C = G;
  } else {
    const int v = id - 128;
    const int b = v >> 4;
    const int gs = (v & 15) >> 2, ss = v & 3;
    arow = gs * 256;
    bcol = ss * 256;
    Ag = Wp + (long)arow * 1024;
    Bg = xb + (long)b * SS + (long)bcol * 1024;
    C = VT + (long)b * SS;
  }
  bf16* sA = smem;
  bf16* sB = smem + 32768;

  f32x4 acc[8][4] = {};
  LOOP256(Ag, Bg, sA, sB, acc);

  const int r0 = (lane >> 4) * 4;
#pragma unroll
  for (int m = 0; m < 8; ++m)
#pragma unroll
    for (int n = 0; n < 4; ++n)
#pragma unroll
      for (int r = 0; r < 4; ++r)
        C[(long)(arow + wr * 128 + m * 16 + r0 + r) * 1024 + bcol + wc * 64 + n * 16 + lr] =
            __float2bfloat16(acc[m][n][r]);
}

// ---------------- prep2: small GEMMs (blocks 0-255, dispatched FIRST so they
// overlap) + x fp32->bf16 conversion (blocks 256-4351, HBM-bound filler).
// small_w: mat = id>>7 (0: M'=BT(wkT,wqT), 1: W'=BT(wo,wvT)),
//          chunk = (id>>6)&1 (K half), tile = id&63 (bm=tile>>3, bn=tile&7).
__global__ __launch_bounds__(256, 2) void prep2(
    const bf16* __restrict__ wkT, const bf16* __restrict__ wqT,
    const bf16* __restrict__ wo, const bf16* __restrict__ wvT,
    float* __restrict__ part, const float* __restrict__ x,
    bf16* __restrict__ xb) {
  __shared__ bf16 smem[128 * 64 * 2];
  const int bid = blockIdx.x;
  const int t = threadIdx.x;

  if (bid >= 256) {  // x conversion
    const long i = (long)(bid - 256) * 2048 + t * 8;
    const float4 a = *(const float4*)&x[i];
    const float4 b = *(const float4*)&x[i + 4];
    const float va[8] = {a.x, a.y, a.z, a.w, b.x, b.y, b.z, b.w};
    union { bf16 h; short s; } u;
    short8 o;
#pragma unroll
    for (int j = 0; j < 8; ++j) { u.h = __float2bfloat16(va[j]); o[j] = u.s; }
    *(short8*)&xb[i] = o;
    return;
  }

  const int id = bid;
  const int mat = id >> 7;
  const int chunk = (id >> 6) & 1;
  const int tile = id & 63;
  const int bm = tile >> 3, bn = tile & 7;
  const bf16* A = (mat == 0) ? wkT : wo;
  const bf16* B = (mat == 0) ? wqT : wvT;
  float* C = part + (long)(mat * 2 + chunk) * (1024L * 1024);

  bf16* As = smem;
  bf16* Bs = smem + 128 * 64;
  const int lane = t & 63;
  const int wid = t >> 6;
  const int wr = (wid >> 1) * 64;
  const int wc = (wid & 1) * 64;
  const int lr = lane & 15;
  const int lk = (lane >> 4) * 8;
  f32x4 acc[4][4] = {};
  const int arow = bm * 128;
  const int brow = bn * 128;
  const int k0base = chunk * 512;

  for (int k0 = k0base; k0 < k0base + 512; k0 += 64) {
#pragma unroll
    for (int p = 0; p < 4; ++p) {
      const int row = p * 32 + (t >> 3);
      const int col = (t & 7) * 8;
      gload_lds16(A + (long)(arow + row) * 1024 + k0 + col, &As[row * 64 + col]);
      gload_lds16(B + (long)(brow + row) * 1024 + k0 + col, &Bs[row * 64 + col]);
    }
    __syncthreads();
#pragma unroll
    for (int kk = 0; kk < 64; kk += 32) {
      short8 a[4], b[4];
#pragma unroll
      for (int m = 0; m < 4; ++m)
        a[m] = *(const short8*)&As[(wr + m * 16 + lr) * 64 + kk + lk];
#pragma unroll
      for (int n = 0; n < 4; ++n)
        b[n] = *(const short8*)&Bs[(wc + n * 16 + lr) * 64 + kk + lk];
#pragma unroll
      for (int m = 0; m < 4; ++m)
#pragma unroll
        for (int n = 0; n < 4; ++n)
          acc[m][n] =
              __builtin_amdgcn_mfma_f32_16x16x32_bf16(a[m], b[n], acc[m][n], 0, 0, 0);
    }
    __syncthreads();
  }
#pragma unroll
  for (int m = 0; m < 4; ++m)
#pragma unroll
    for (int n = 0; n < 4; ++n)
#pragma unroll
      for (int r = 0; r < 4; ++r) {
        const int row = arow + wr + m * 16 + (lane >> 4) * 4 + r;
        const int col = brow + wc + n * 16 + lr;
        C[(long)row * 1024 + col] = acc[m][n][r];
      }
}

// ---------------- sum split-K partials, convert to bf16 M' / W'.
__global__ __launch_bounds__(256) void reduce_w(
    const float* __restrict__ part, bf16* __restrict__ Mp, bf16* __restrict__ Wp) {
  const long i = ((long)blockIdx.x * 256 + threadIdx.x) * 8;  // 0 .. 2M
  const long M1 = 1024L * 1024;
  const int mat = (i >= M1) ? 1 : 0;
  const long e = i - (long)mat * M1;
  const float* p0 = part + (long)(mat * 2) * M1 + e;
  const float* p1 = p0 + M1;
  bf16* dst = (mat ? Wp : Mp) + e;
  const float4 a0 = *(const float4*)p0;
  const float4 a1 = *(const float4*)(p0 + 4);
  const float4 b0 = *(const float4*)p1;
  const float4 b1 = *(const float4*)(p1 + 4);
  const float v[8] = {a0.x + b0.x, a0.y + b0.y, a0.z + b0.z, a0.w + b0.w,
                      a1.x + b1.x, a1.y + b1.y, a1.z + b1.z, a1.w + b1.w};
  union { bf16 h; short s; } u;
  short8 o;
#pragma unroll
  for (int j = 0; j < 8; ++j) { u.h = __float2bfloat16(v[j]); o[j] = u.s; }
  *(short8*)dst = o;
}

// ---------------- scores = BT(G_b, xb_b), causal 128x256 tiles, bf16 -> P.
// grid 160: bz = id/20, r = id%20 -> (bm 0..7, bn 0..bm/2). NT=16 (full d-sum).
__global__ __launch_bounds__(512, 2) void gemm_sc(
    const bf16* __restrict__ Gall, const bf16* __restrict__ xball,
    bf16* __restrict__ Pall) {
  __shared__ bf16 smem[49152];
  const int id = blockIdx.x;
  const int bz = id / 20;
  int rr = id - bz * 20, bm = 0;
  while (rr >= bm / 2 + 1) { rr -= bm / 2 + 1; ++bm; }
  const int bn = rr;
  const long SS = 1024L * 1024;
  const bf16* A = Gall + SS * bz;
  const bf16* B = xball + SS * bz;
  const int tid = threadIdx.x;
  const int lane = tid & 63;
  const int wid = tid >> 6;
  const int wr = wid >> 2;
  const int wc = wid & 3;
  const int lr = lane & 15;
  const int c16 = lane >> 4;
  const int bcol = bn * 256;
  const int arow = bm * 128;
  const int NT = 16;
  const bf16* Ag = A + (long)arow * 1024;
  const bf16* Bg = B + (long)bcol * 1024;
  bf16* sA = smem;
  bf16* sB = smem + 16384;

  stage_half(Ag, sA, tid);
  stage_half(Bg, sB, tid);
  stage_half(Bg + 128 * 1024, sB + 8192, tid);
  stage_half(Ag + 64, sA + 8192, tid);
  VMCNT2();
  SBAR();

  f32x4 acc[4][4] = {};
  for (int t = 0; t < NT; ++t) {
    const int rp = t & 1;
    const int sp = rp ^ 1;
    const bf16* As = sA + rp * 8192;
    const bf16* Bs = sB + (rp * 2 + (wc >> 1)) * 8192;
    const int brb = (wc & 1) * 64;
    short8 aq[4][2], b01[2][2], b23[2][2];
#pragma unroll
    for (int m = 0; m < 4; ++m)
#pragma unroll
      for (int ks = 0; ks < 2; ++ks)
        aq[m][ks] = lds_frag(As, wr * 64 + m * 16 + lr, c16 + ks * 4);
#pragma unroll
    for (int n = 0; n < 2; ++n)
#pragma unroll
      for (int ks = 0; ks < 2; ++ks)
        b01[n][ks] = lds_frag(Bs, brb + n * 16 + lr, c16 + ks * 4);
    if (t + 1 < NT) stage_half(Bg + (t + 1) * 64, sB + sp * 2 * 8192, tid);
    SBAR();
    __builtin_amdgcn_s_setprio(1);
#pragma unroll
    for (int m = 0; m < 4; ++m)
#pragma unroll
      for (int n = 0; n < 2; ++n)
#pragma unroll
        for (int ks = 0; ks < 2; ++ks)
          acc[m][n] = __builtin_amdgcn_mfma_f32_16x16x32_bf16(
              aq[m][ks], b01[n][ks], acc[m][n], 0, 0, 0);
    __builtin_amdgcn_s_setprio(0);
    SBAR();
#pragma unroll
    for (int n = 0; n < 2; ++n)
#pragma unroll
      for (int ks = 0; ks < 2; ++ks)
        b23[n][ks] = lds_frag(Bs, brb + (n + 2) * 16 + lr, c16 + ks * 4);
    if (t + 1 < NT)
      stage_half(Bg + 128 * 1024 + (t + 1) * 64, sB + (sp * 2 + 1) * 8192, tid);
    if (t + 2 < NT) {
      stage_half(Ag + (t + 2) * 64, sA + rp * 8192, tid);
      VMCNT2();
    } else if (t + 1 < NT) {
      VMCNT0();
    }
    SBAR();
    __builtin_amdgcn_s_setprio(1);
#pragma unroll
    for (int m = 0; m < 4; ++m)
#pragma unroll
      for (int n = 0; n < 2; ++n)
#pragma unroll
        for (int ks = 0; ks < 2; ++ks)
          acc[m][n + 2] = __builtin_amdgcn_mfma_f32_16x16x32_bf16(
              aq[m][ks], b23[n][ks], acc[m][n + 2], 0, 0, 0);
    __builtin_amdgcn_s_setprio(0);
    SBAR();
  }

  const int r0 = (lane >> 4) * 4;
  bf16* C = Pall + SS * bz;
#pragma unroll
  for (int m = 0; m < 4; ++m)
#pragma unroll
    for (int n = 0; n < 4; ++n)
#pragma unroll
      for (int r = 0; r < 4; ++r)
        C[(long)(arow + wr * 64 + m * 16 + r0 + r) * 1024 + bcol + wc * 64 + n * 16 + lr] =
            __float2bfloat16(acc[m][n][r]);
}

// ---------------- PV: out[b][q][g] = sum_s P[q][s] V'^T[g][s], fp32 -> d_out.
__global__ __launch_bounds__(512, 2) void gemm_pv32(
    const bf16* __restrict__ Pall, const bf16* __restrict__ VTall,
    float* __restrict__ Out) {
  __shared__ bf16 smem[49152];
  const int bm = blockIdx.x, bn = blockIdx.y, bz = blockIdx.z;
  const long SS = 1024L * 1024;
  const bf16* A = Pall + SS * bz;
  const bf16* B = VTall + SS * bz;
  const int tid = threadIdx.x;
  const int lane = tid & 63;
  const int wid = tid >> 6;
  const int wr = wid >> 2;
  const int wc = wid & 3;
  const int lr = lane & 15;
  const int c16 = lane >> 4;
  const int bcol = bn * 256;
  const int arow = bm * 128;
  const int NT = (bm + 1) * 2;  // causal: s < (bm+1)*128
  const bf16* Ag = A + (long)arow * 1024;
  const bf16* Bg = B + (long)bcol * 1024;
  bf16* sA = smem;
  bf16* sB = smem + 16384;

  stage_half(Ag, sA, tid);
  stage_half(Bg, sB, tid);
  stage_half(Bg + 128 * 1024, sB + 8192, tid);
  stage_half(Ag + 64, sA + 8192, tid);
  VMCNT2();
  SBAR();

  f32x4 acc[4][4] = {};
  for (int t = 0; t < NT; ++t) {
    const int rp = t & 1;
    const int sp = rp ^ 1;
    const bf16* As = sA + rp * 8192;
    const bf16* Bs = sB + (rp * 2 + (wc >> 1)) * 8192;
    const int brb = (wc & 1) * 64;
    short8 aq[4][2], b01[2][2], b23[2][2];
#pragma unroll
    for (int m = 0; m < 4; ++m)
#pragma unroll
      for (int ks = 0; ks < 2; ++ks)
        aq[m][ks] = lds_frag(As, wr * 64 + m * 16 + lr, c16 + ks * 4);
#pragma unroll
    for (int n = 0; n < 2; ++n)
#pragma unroll
      for (int ks = 0; ks < 2; ++ks)
        b01[n][ks] = lds_frag(Bs, brb + n * 16 + lr, c16 + ks * 4);
    if (t + 1 < NT) stage_half(Bg + (t + 1) * 64, sB + sp * 2 * 8192, tid);
    SBAR();
    __builtin_amdgcn_s_setprio(1);
#pragma unroll
    for (int m = 0; m < 4; ++m)
#pragma unroll
      for (int n = 0; n < 2; ++n)
#pragma unroll
        for (int ks = 0; ks < 2; ++ks)
          acc[m][n] = __builtin_amdgcn_mfma_f32_16x16x32_bf16(
              aq[m][ks], b01[n][ks], acc[m][n], 0, 0, 0);
    __builtin_amdgcn_s_setprio(0);
    SBAR();
#pragma unroll
    for (int n = 0; n < 2; ++n)
#pragma unroll
      for (int ks = 0; ks < 2; ++ks)
        b23[n][ks] = lds_frag(Bs, brb + (n + 2) * 16 + lr, c16 + ks * 4);
    if (t + 1 < NT)
      stage_half(Bg + 128 * 1024 + (t + 1) * 64, sB + (sp * 2 + 1) * 8192, tid);
    if (t + 2 < NT) {
      stage_half(Ag + (t + 2) * 64, sA + rp * 8192, tid);
      VMCNT2();
    } else if (t + 1 < NT) {
      VMCNT0();
    }
    SBAR();
    __builtin_amdgcn_s_setprio(1);
#pragma unroll
    for (int m = 0; m < 4; ++m)
#pragma unroll
      for (int n = 0; n < 2; ++n)
#pragma unroll
        for (int ks = 0; ks < 2; ++ks)
          acc[m][n + 2] = __builtin_amdgcn_mfma_f32_16x16x32_bf16(
              aq[m][ks], b23[n][ks], acc[m][n + 2], 0, 0, 0);
    __builtin_amdgcn_s_setprio(0);
    SBAR();
  }

  const int r0 = (lane >> 4) * 4;
  float* C = Out + SS * bz;
#pragma unroll
  for (int m = 0; m < 4; ++m)
#pragma unroll
    for (int n = 0; n < 4; ++n)
#pragma unroll
      for (int r = 0; r < 4; ++r)
        C[(long)(arow + wr * 64 + m * 16 + r0 + r) * 1024 + bcol + wc * 64 + n * 16 + lr] =
            acc[m][n][r];
}

// fp32 -> bf16 weights: wq, wk, wv transposed (64x64 LDS tiles); wo plain.
__global__ __launch_bounds__(256) void f2bw(
    const float* __restrict__ wq, const float* __restrict__ wk,
    const float* __restrict__ wv, const float* __restrict__ wo,
    bf16* __restrict__ wqTb, bf16* __restrict__ wkTb,
    bf16* __restrict__ wvTb, bf16* __restrict__ wob) {
  __shared__ float T[64][65];
  const int bid = blockIdx.x;
  const int t = threadIdx.x;
  union { bf16 h; short s; } u;

  if (bid < 768) {  // transpose-convert: wT[d][e] = w[e][d]
    const int mat = bid >> 8;          // 0 wq, 1 wk, 2 wv
    const int tile = bid & 255;
    const int er = tile >> 4, dc = tile & 15;
    const float* src = ((mat == 0) ? wq : (mat == 1) ? wk : wv);
    bf16* dstb = ((mat == 0) ? wqTb : (mat == 1) ? wkTb : wvTb);
    const int r = t >> 2, c = (t & 3) * 16;
    const float* s0 = src + (long)(er * 64 + r) * 1024 + dc * 64 + c;
#pragma unroll
    for (int j = 0; j < 4; ++j) {
      const float4 v = *(const float4*)(s0 + j * 4);
      T[r][c + j * 4 + 0] = v.x;
      T[r][c + j * 4 + 1] = v.y;
      T[r][c + j * 4 + 2] = v.z;
      T[r][c + j * 4 + 3] = v.w;
    }
    __syncthreads();
    const int d = t >> 2, ec = (t & 3) * 16;
    bf16* dst = dstb + (long)(dc * 64 + d) * 1024 + er * 64 + ec;
#pragma unroll
    for (int half = 0; half < 2; ++half) {
      short8 o;
#pragma unroll
      for (int j = 0; j < 8; ++j) {
        u.h = __float2bfloat16(T[ec + half * 8 + j][d]);
        o[j] = u.s;
      }
      *(short8*)(dst + half * 8) = o;
    }
    return;
  }
  // wo plain convert
  const long i = (long)(bid - 768) * 2048 + t * 8;
  const float4 a = *(const float4*)&wo[i];
  const float4 b = *(const float4*)&wo[i + 4];
  const float va[8] = {a.x, a.y, a.z, a.w, b.x, b.y, b.z, b.w};
  short8 o;
#pragma unroll
  for (int j = 0; j < 8; ++j) { u.h = __float2bfloat16(va[j]); o[j] = u.s; }
  *(short8*)&wob[i] = o;
}

// In-place causal softmax, vectorized: 128 thr/row, one bf16x8 (16B) per lane.
__global__ __launch_bounds__(128) void softmax_causal(bf16* __restrict__ P) {
  const int q = blockIdx.x;
  const int b = blockIdx.y;
  bf16* row = P + ((long)b * 1024 + q) * 1024;
  const int t = threadIdx.x;
  const int n = q + 1;  // causal length
  __shared__ float red[4];
  union { bf16 h; short s; } u;

  const short8 raw = *(const short8*)&row[t * 8];
  float v[8];
  float mx = -1e30f;
#pragma unroll
  for (int j = 0; j < 8; ++j) {
    const int k = t * 8 + j;
    u.s = raw[j];
    v[j] = (k < n) ? __bfloat162float(u.h) * 0.03125f : -1e30f;
    mx = fmaxf(mx, v[j]);
  }
#pragma unroll
  for (int o = 32; o > 0; o >>= 1) mx = fmaxf(mx, __shfl_xor(mx, o, 64));
  if ((t & 63) == 0) red[t >> 6] = mx;
  __syncthreads();
  mx = fmaxf(red[0], red[1]);

  float s = 0.f;
  float e[8];
#pragma unroll
  for (int j = 0; j < 8; ++j) {
    const int k = t * 8 + j;
    e[j] = (k < n) ? __expf(v[j] - mx) : 0.f;
    s += e[j];
  }
#pragma unroll
  for (int o = 32; o > 0; o >>= 1) s += __shfl_xor(s, o, 64);
  if ((t & 63) == 0) red[2 + (t >> 6)] = s;
  __syncthreads();
  s = red[2] + red[3];
  const float inv = 1.f / s;
  short8 o;
#pragma unroll
  for (int j = 0; j < 8; ++j) {
    u.h = __float2bfloat16(e[j] * inv);
    o[j] = u.s;
  }
  *(short8*)&row[t * 8] = o;
}

extern "C" void kernel_launch(void* const* d_in, const int* in_sizes, int n_in,
                              void* d_out, int out_size, void* d_ws, size_t ws_size,
                              hipStream_t stream) {
  (void)in_sizes; (void)n_in; (void)out_size; (void)ws_size;
  const float* x  = (const float*)d_in[0];
  const float* wq = (const float*)d_in[1];
  const float* wk = (const float*)d_in[2];
  const float* wv = (const float*)d_in[3];
  const float* wo = (const float*)d_in[4];
  float* out = (float*)d_out;
  bf16* ws = (bf16*)d_ws;

  const long SB = 8192L * 1024;
  const long SW = 1024L * 1024;

  bf16* xb   = ws;                    // [8][s][d]     16.8 MB
  bf16* wqTb = ws + SB;               // wq^T [d][e]
  bf16* wkTb = ws + SB + SW;          // wk^T [d][e]
  bf16* wvTb = ws + SB + 2 * SW;      // wv^T [d][e]
  bf16* wob  = ws + SB + 3 * SW;      // wo   [g][e]
  bf16* Mp   = ws + SB + 4 * SW;      // M'[d'][d] = wq^T wk (via BT(wkT,wqT))
  bf16* Wp   = ws + SB + 5 * SW;      // W'[g][d]  = wo wv   (via BT(wo,wvT))
  bf16* G    = ws + SB + 6 * SW;      // [8192][1024]
  bf16* VT   = G + SB;                // V'^T [8][g][s]
  bf16* P    = VT + SB;               // scores / P in place
  float* part = (float*)P;            // split-K partials (16 MB, dead before P)

  // weights convert/transpose (1280 light blocks)
  f2bw<<<dim3(1280), dim3(256), 0, stream>>>(wq, wk, wv, wo, wqTb, wkTb, wvTb, wob);
  // small GEMMs (blocks 0-255, start first) overlapped with x conversion
  prep2<<<dim3(4352), dim3(256), 0, stream>>>(wkTb, wqTb, wob, wvTb, part, x, xb);
  reduce_w<<<dim3(1024), dim3(256), 0, stream>>>(part, Mp, Wp);
  // G = x M'  and  V'^T = W' x^T : 256 blocks = 1 exact 256^2 round
  gemm_gv<<<dim3(256), dim3(512), 0, stream>>>(xb, Mp, Wp, G, VT);
  // scores = G x^T, causal 128x256 tiles (20 per batch)
  gemm_sc<<<dim3(160), dim3(512), 0, stream>>>(G, xb, P);
  softmax_causal<<<dim3(1024, 8), dim3(128), 0, stream>>>(P);
  // out = P @ V' (causal K-limit), fp32 straight to d_out
  gemm_pv32<<<dim3(8, 4, 8), dim3(512), 0, stream>>>(P, VT, out);
}

// Round 10
// 128.401 us; speedup vs baseline: 1.4252x; 1.0301x over previous
//
#include <hip/hip_runtime.h>
#include <hip/hip_bf16.h>

typedef __hip_bfloat16 bf16;
typedef __attribute__((ext_vector_type(8))) short short8;
typedef __attribute__((ext_vector_type(4))) float f32x4;

#define SBAR() asm volatile("s_barrier" ::: "memory")
#define VMCNT4() asm volatile("s_waitcnt vmcnt(4)" ::: "memory")
#define VMCNT2() asm volatile("s_waitcnt vmcnt(2)" ::: "memory")
#define VMCNT0() asm volatile("s_waitcnt vmcnt(0)" ::: "memory")

__device__ __forceinline__ void gload_lds16(const bf16* g, bf16* l) {
  __builtin_amdgcn_global_load_lds(
      (const __attribute__((address_space(1))) unsigned int*)g,
      (__attribute__((address_space(3))) unsigned int*)l, 16, 0, 0);
}

// Stage one 128x64 half-tile (row-major, ld=1024) into a linear 16KB LDS slot.
// Global source col is XOR-swizzled so swizzled LDS reads are conflict-free.
__device__ __forceinline__ void stage_half(const bf16* gbase, bf16* slot, int tid) {
  const int r = tid >> 3;                    // 0..63
  const int c = ((tid & 7) ^ (r & 7)) << 3;  // swizzled 16B chunk
  gload_lds16(gbase + (long)r * 1024 + c, slot + tid * 8);
  gload_lds16(gbase + (long)(r + 64) * 1024 + c, slot + 4096 + tid * 8);
}

// Swizzled fragment read: logical (row, 16B-chunk c16) of a [128][64] half-slot.
__device__ __forceinline__ short8 lds_frag(const bf16* slot, int row, int c16) {
  return *(const short8*)(slot + row * 64 + ((c16 ^ (row & 7)) << 3));
}

// ======== 256x256-tile 4-phase loop with READ-AHEAD schedule:
// every ds_read completes >=1 phase (2 barriers) before its consuming MFMA.
// aq0/bq0 of tile t+1 are read in ph3 of tile t (published by VMCNT4+SBAR there);
// arrays are overwritten only after their last use (no copies).
#define LOOP256(Ag, Bg, sA, sB, acc)                                              \
  {                                                                               \
    stage_half(Ag, sA, tid);                                                      \
    stage_half(Ag + 128 * 1024, sA + 8192, tid);                                  \
    stage_half(Bg, sB, tid);                                                      \
    stage_half(Bg + 128 * 1024, sB + 8192, tid);                                  \
    stage_half(Ag + 64, sA + 16384, tid);                                         \
    stage_half(Ag + 128 * 1024 + 64, sA + 24576, tid);                            \
    VMCNT4();                                                                     \
    SBAR();                                                                       \
    const int brb = (wc & 1) * 64;                                                \
    short8 aq0[4][2], aq1[4][2], bq0[2][2], bq1[2][2];                            \
    _Pragma("unroll") for (int m = 0; m < 4; ++m)                                 \
        _Pragma("unroll") for (int ks = 0; ks < 2; ++ks)                          \
            aq0[m][ks] = lds_frag(sA + wr * 8192, m * 16 + lr, c16 + ks * 4);     \
    _Pragma("unroll") for (int n = 0; n < 2; ++n)                                 \
        _Pragma("unroll") for (int ks = 0; ks < 2; ++ks)                          \
            bq0[n][ks] = lds_frag(sB + (wc >> 1) * 8192, brb + n * 16 + lr,       \
                                  c16 + ks * 4);                                  \
    const int NT = 16;                                                            \
    for (int t = 0; t < NT; ++t) {                                                \
      const int rp = t & 1;                                                       \
      const int sp = rp ^ 1;                                                      \
      const bf16* Bs = sB + (rp * 2 + (wc >> 1)) * 8192;                          \
      const bf16* AsC = sA + (rp * 2 + wr) * 8192;                                \
      const bf16* AsN = sA + (sp * 2 + wr) * 8192;                                \
      const bf16* BsN = sB + (sp * 2 + (wc >> 1)) * 8192;                         \
      /* ph0: read bq1(t) (for ph1); stage B(t+1)h0; MFMA aq0*bq0 */              \
      _Pragma("unroll") for (int n = 0; n < 2; ++n)                               \
          _Pragma("unroll") for (int ks = 0; ks < 2; ++ks)                        \
              bq1[n][ks] = lds_frag(Bs, brb + (n + 2) * 16 + lr, c16 + ks * 4);   \
      if (t + 1 < NT) stage_half(Bg + (t + 1) * 64, sB + sp * 2 * 8192, tid);     \
      SBAR();                                                                     \
      __builtin_amdgcn_s_setprio(1);                                              \
      _Pragma("unroll") for (int m = 0; m < 4; ++m)                               \
          _Pragma("unroll") for (int n = 0; n < 2; ++n)                           \
              _Pragma("unroll") for (int ks = 0; ks < 2; ++ks)                    \
                  acc[m][n] = __builtin_amdgcn_mfma_f32_16x16x32_bf16(            \
                      aq0[m][ks], bq0[n][ks], acc[m][n], 0, 0, 0);                \
      __builtin_amdgcn_s_setprio(0);                                              \
      SBAR();                                                                     \
      /* ph1: read aq1(t) (for ph2/ph3); stage B(t+1)h1; MFMA aq0*bq1 */          \
      _Pragma("unroll") for (int m = 0; m < 4; ++m)                               \
          _Pragma("unroll") for (int ks = 0; ks < 2; ++ks)                        \
              aq1[m][ks] = lds_frag(AsC, (m + 4) * 16 + lr, c16 + ks * 4);        \
      if (t + 1 < NT)                                                             \
        stage_half(Bg + 128 * 1024 + (t + 1) * 64, sB + (sp * 2 + 1) * 8192, tid);\
      SBAR();                                                                     \
      __builtin_amdgcn_s_setprio(1);                                              \
      _Pragma("unroll") for (int m = 0; m < 4; ++m)                               \
          _Pragma("unroll") for (int n = 0; n < 2; ++n)                           \
              _Pragma("unroll") for (int ks = 0; ks < 2; ++ks)                    \
                  acc[m][n + 2] = __builtin_amdgcn_mfma_f32_16x16x32_bf16(        \
                      aq0[m][ks], bq1[n][ks], acc[m][n + 2], 0, 0, 0);            \
      __builtin_amdgcn_s_setprio(0);                                              \
      SBAR();                                                                     \
      /* ph2: pure MFMA aq1*bq1 */                                                \
      __builtin_amdgcn_s_setprio(1);                                              \
      _Pragma("unroll") for (int m = 0; m < 4; ++m)                               \
          _Pragma("unroll") for (int n = 0; n < 2; ++n)                           \
              _Pragma("unroll") for (int ks = 0; ks < 2; ++ks)                    \
                  acc[m + 4][n + 2] = __builtin_amdgcn_mfma_f32_16x16x32_bf16(    \
                      aq1[m][ks], bq1[n][ks], acc[m + 4][n + 2], 0, 0, 0);        \
      __builtin_amdgcn_s_setprio(0);                                              \
      SBAR();                                                                     \
      /* ph3: stage A(t+2); counted vmcnt; read next aq0; MFMA aq1*bq0;           \
         read next bq0 (bq0 dead after this MFMA) */                              \
      if (t + 2 < NT) {                                                           \
        stage_half(Ag + (t + 2) * 64, sA + rp * 2 * 8192, tid);                   \
        stage_half(Ag + 128 * 1024 + (t + 2) * 64, sA + (rp * 2 + 1) * 8192, tid);\
        VMCNT4();                                                                 \
      } else if (t + 1 < NT) {                                                    \
        VMCNT0();                                                                 \
      }                                                                           \
      SBAR();                                                                     \
      if (t + 1 < NT) {                                                           \
        _Pragma("unroll") for (int m = 0; m < 4; ++m)                             \
            _Pragma("unroll") for (int ks = 0; ks < 2; ++ks)                      \
                aq0[m][ks] = lds_frag(AsN, m * 16 + lr, c16 + ks * 4);            \
      }                                                                           \
      __builtin_amdgcn_s_setprio(1);                                              \
      _Pragma("unroll") for (int m = 0; m < 4; ++m)                               \
          _Pragma("unroll") for (int n = 0; n < 2; ++n)                           \
              _Pragma("unroll") for (int ks = 0; ks < 2; ++ks)                    \
                  acc[m + 4][n] = __builtin_amdgcn_mfma_f32_16x16x32_bf16(        \
                      aq1[m][ks], bq0[n][ks], acc[m + 4][n], 0, 0, 0);            \
      __builtin_amdgcn_s_setprio(0);                                              \
      if (t + 1 < NT) {                                                           \
        _Pragma("unroll") for (int n = 0; n < 2; ++n)                             \
            _Pragma("unroll") for (int ks = 0; ks < 2; ++ks)                      \
                bq0[n][ks] = lds_frag(BsN, brb + n * 16 + lr, c16 + ks * 4);      \
      }                                                                           \
      SBAR();                                                                     \
    }                                                                             \
  }

// ======== 128x256-tile 2-phase loop with the same read-ahead schedule.
// aq(t+1)/b01(t+1) read at ph1-end (after their last use; slots published by
// this phase's VMCNT2+SBAR); b23(t) read at ph0 (used in ph1).
#define LOOP128(Ag, Bg, sA, sB, acc, NTv)                                         \
  {                                                                               \
    stage_half(Ag, sA, tid);                                                      \
    stage_half(Bg, sB, tid);                                                      \
    stage_half(Bg + 128 * 1024, sB + 8192, tid);                                  \
    stage_half(Ag + 64, sA + 8192, tid);                                          \
    VMCNT2();                                                                     \
    SBAR();                                                                       \
    const int brb = (wc & 1) * 64;                                                \
    short8 aq[4][2], b01[2][2], b23[2][2];                                        \
    _Pragma("unroll") for (int m = 0; m < 4; ++m)                                 \
        _Pragma("unroll") for (int ks = 0; ks < 2; ++ks)                          \
            aq[m][ks] = lds_frag(sA, wr * 64 + m * 16 + lr, c16 + ks * 4);        \
    _Pragma("unroll") for (int n = 0; n < 2; ++n)                                 \
        _Pragma("unroll") for (int ks = 0; ks < 2; ++ks)                          \
            b01[n][ks] = lds_frag(sB + (wc >> 1) * 8192, brb + n * 16 + lr,       \
                                  c16 + ks * 4);                                  \
    const int NT = (NTv);                                                         \
    for (int t = 0; t < NT; ++t) {                                                \
      const int rp = t & 1;                                                       \
      const int sp = rp ^ 1;                                                      \
      const bf16* Bs = sB + (rp * 2 + (wc >> 1)) * 8192;                          \
      const bf16* AsN = sA + sp * 8192;                                           \
      const bf16* BsN = sB + (sp * 2 + (wc >> 1)) * 8192;                         \
      /* ph0: read b23(t) (for ph1); stage B(t+1)h0; MFMA aq*b01 */               \
      _Pragma("unroll") for (int n = 0; n < 2; ++n)                               \
          _Pragma("unroll") for (int ks = 0; ks < 2; ++ks)                        \
              b23[n][ks] = lds_frag(Bs, brb + (n + 2) * 16 + lr, c16 + ks * 4);   \
      if (t + 1 < NT) stage_half(Bg + (t + 1) * 64, sB + sp * 2 * 8192, tid);     \
      SBAR();                                                                     \
      __builtin_amdgcn_s_setprio(1);                                              \
      _Pragma("unroll") for (int m = 0; m < 4; ++m)                               \
          _Pragma("unroll") for (int n = 0; n < 2; ++n)                           \
              _Pragma("unroll") for (int ks = 0; ks < 2; ++ks)                    \
                  acc[m][n] = __builtin_amdgcn_mfma_f32_16x16x32_bf16(            \
                      aq[m][ks], b01[n][ks], acc[m][n], 0, 0, 0);                 \
      __builtin_amdgcn_s_setprio(0);                                              \
      SBAR();                                                                     \
      /* ph1: stage B(t+1)h1 + A(t+2); counted vmcnt; MFMA aq*b23;                \
         then read aq(t+1), b01(t+1) (both dead after this phase) */              \
      if (t + 1 < NT)                                                             \
        stage_half(Bg + 128 * 1024 + (t + 1) * 64, sB + (sp * 2 + 1) * 8192, tid);\
      if (t + 2 < NT) {                                                           \
        stage_half(Ag + (t + 2) * 64, sA + rp * 8192, tid);                       \
        VMCNT2();                                                                 \
      } else if (t + 1 < NT) {                                                    \
        VMCNT0();                                                                 \
      }                                                                           \
      SBAR();                                                                     \
      __builtin_amdgcn_s_setprio(1);                                              \
      _Pragma("unroll") for (int m = 0; m < 4; ++m)                               \
          _Pragma("unroll") for (int n = 0; n < 2; ++n)                           \
              _Pragma("unroll") for (int ks = 0; ks < 2; ++ks)                    \
                  acc[m][n + 2] = __builtin_amdgcn_mfma_f32_16x16x32_bf16(        \
                      aq[m][ks], b23[n][ks], acc[m][n + 2], 0, 0, 0);             \
      __builtin_amdgcn_s_setprio(0);                                              \
      if (t + 1 < NT) {                                                           \
        _Pragma("unroll") for (int m = 0; m < 4; ++m)                             \
            _Pragma("unroll") for (int ks = 0; ks < 2; ++ks)                      \
                aq[m][ks] = lds_frag(AsN, wr * 64 + m * 16 + lr, c16 + ks * 4);   \
        _Pragma("unroll") for (int n = 0; n < 2; ++n)                             \
            _Pragma("unroll") for (int ks = 0; ks < 2; ++ks)                      \
                b01[n][ks] = lds_frag(BsN, brb + n * 16 + lr, c16 + ks * 4);      \
      }                                                                           \
      SBAR();                                                                     \
    }                                                                             \
  }

// ---------------- merged G-projection + V'-projection at 256^2 rate.
// id 0..127:  G = BT(xb, M')   [8192 x 1024], bm=id>>2, bn=id&3
// id 128..255: V'^T = BT(W', xb_b) per batch (b=(id-128)>>4, tile (id-128)&15)
__global__ __launch_bounds__(512, 1) void gemm_gv(
    const bf16* __restrict__ xb, const bf16* __restrict__ Mp,
    const bf16* __restrict__ Wp, bf16* __restrict__ G, bf16* __restrict__ VT) {
  __shared__ bf16 smem[65536];
  const int id = blockIdx.x;
  const int tid = threadIdx.x;
  const int lane = tid & 63;
  const int wid = tid >> 6;
  const int wr = wid >> 2;
  const int wc = wid & 3;
  const int lr = lane & 15;
  const int c16 = lane >> 4;
  const long SS = 1024L * 1024;

  const bf16 *Ag, *Bg;
  bf16* C;
  int arow, bcol;
  if (id < 128) {
    const int bm = id >> 2, bn = id & 3;
    arow = bm * 256;
    bcol = bn * 256;
    Ag = xb + (long)arow * 1024;
    Bg = Mp + (long)bcol * 1024;
    C = G;
  } else {
    const int v = id - 128;
    const int b = v >> 4;
    const int gs = (v & 15) >> 2, ss = v & 3;
    arow = gs * 256;
    bcol = ss * 256;
    Ag = Wp + (long)arow * 1024;
    Bg = xb + (long)b * SS + (long)bcol * 1024;
    C = VT + (long)b * SS;
  }
  bf16* sA = smem;
  bf16* sB = smem + 32768;

  f32x4 acc[8][4] = {};
  LOOP256(Ag, Bg, sA, sB, acc);

  const int r0 = (lane >> 4) * 4;
#pragma unroll
  for (int m = 0; m < 8; ++m)
#pragma unroll
    for (int n = 0; n < 4; ++n)
#pragma unroll
      for (int r = 0; r < 4; ++r)
        C[(long)(arow + wr * 128 + m * 16 + r0 + r) * 1024 + bcol + wc * 64 + n * 16 + lr] =
            __float2bfloat16(acc[m][n][r]);
}

// ---------------- prep2: small GEMMs (blocks 0-255, dispatched FIRST so they
// overlap) + x fp32->bf16 conversion (blocks 256-4351, HBM-bound filler).
__global__ __launch_bounds__(256, 2) void prep2(
    const bf16* __restrict__ wkT, const bf16* __restrict__ wqT,
    const bf16* __restrict__ wo, const bf16* __restrict__ wvT,
    float* __restrict__ part, const float* __restrict__ x,
    bf16* __restrict__ xb) {
  __shared__ bf16 smem[128 * 64 * 2];
  const int bid = blockIdx.x;
  const int t = threadIdx.x;

  if (bid >= 256) {  // x conversion
    const long i = (long)(bid - 256) * 2048 + t * 8;
    const float4 a = *(const float4*)&x[i];
    const float4 b = *(const float4*)&x[i + 4];
    const float va[8] = {a.x, a.y, a.z, a.w, b.x, b.y, b.z, b.w};
    union { bf16 h; short s; } u;
    short8 o;
#pragma unroll
    for (int j = 0; j < 8; ++j) { u.h = __float2bfloat16(va[j]); o[j] = u.s; }
    *(short8*)&xb[i] = o;
    return;
  }

  const int id = bid;
  const int mat = id >> 7;
  const int chunk = (id >> 6) & 1;
  const int tile = id & 63;
  const int bm = tile >> 3, bn = tile & 7;
  const bf16* A = (mat == 0) ? wkT : wo;
  const bf16* B = (mat == 0) ? wqT : wvT;
  float* C = part + (long)(mat * 2 + chunk) * (1024L * 1024);

  bf16* As = smem;
  bf16* Bs = smem + 128 * 64;
  const int lane = t & 63;
  const int wid = t >> 6;
  const int wr = (wid >> 1) * 64;
  const int wc = (wid & 1) * 64;
  const int lr = lane & 15;
  const int lk = (lane >> 4) * 8;
  f32x4 acc[4][4] = {};
  const int arow = bm * 128;
  const int brow = bn * 128;
  const int k0base = chunk * 512;

  for (int k0 = k0base; k0 < k0base + 512; k0 += 64) {
#pragma unroll
    for (int p = 0; p < 4; ++p) {
      const int row = p * 32 + (t >> 3);
      const int col = (t & 7) * 8;
      gload_lds16(A + (long)(arow + row) * 1024 + k0 + col, &As[row * 64 + col]);
      gload_lds16(B + (long)(brow + row) * 1024 + k0 + col, &Bs[row * 64 + col]);
    }
    __syncthreads();
#pragma unroll
    for (int kk = 0; kk < 64; kk += 32) {
      short8 a[4], b[4];
#pragma unroll
      for (int m = 0; m < 4; ++m)
        a[m] = *(const short8*)&As[(wr + m * 16 + lr) * 64 + kk + lk];
#pragma unroll
      for (int n = 0; n < 4; ++n)
        b[n] = *(const short8*)&Bs[(wc + n * 16 + lr) * 64 + kk + lk];
#pragma unroll
      for (int m = 0; m < 4; ++m)
#pragma unroll
        for (int n = 0; n < 4; ++n)
          acc[m][n] =
              __builtin_amdgcn_mfma_f32_16x16x32_bf16(a[m], b[n], acc[m][n], 0, 0, 0);
    }
    __syncthreads();
  }
#pragma unroll
  for (int m = 0; m < 4; ++m)
#pragma unroll
    for (int n = 0; n < 4; ++n)
#pragma unroll
      for (int r = 0; r < 4; ++r) {
        const int row = arow + wr + m * 16 + (lane >> 4) * 4 + r;
        const int col = brow + wc + n * 16 + lr;
        C[(long)row * 1024 + col] = acc[m][n][r];
      }
}

// ---------------- sum split-K partials, convert to bf16 M' / W'.
__global__ __launch_bounds__(256) void reduce_w(
    const float* __restrict__ part, bf16* __restrict__ Mp, bf16* __restrict__ Wp) {
  const long i = ((long)blockIdx.x * 256 + threadIdx.x) * 8;  // 0 .. 2M
  const long M1 = 1024L * 1024;
  const int mat = (i >= M1) ? 1 : 0;
  const long e = i - (long)mat * M1;
  const float* p0 = part + (long)(mat * 2) * M1 + e;
  const float* p1 = p0 + M1;
  bf16* dst = (mat ? Wp : Mp) + e;
  const float4 a0 = *(const float4*)p0;
  const float4 a1 = *(const float4*)(p0 + 4);
  const float4 b0 = *(const float4*)p1;
  const float4 b1 = *(const float4*)(p1 + 4);
  const float v[8] = {a0.x + b0.x, a0.y + b0.y, a0.z + b0.z, a0.w + b0.w,
                      a1.x + b1.x, a1.y + b1.y, a1.z + b1.z, a1.w + b1.w};
  union { bf16 h; short s; } u;
  short8 o;
#pragma unroll
  for (int j = 0; j < 8; ++j) { u.h = __float2bfloat16(v[j]); o[j] = u.s; }
  *(short8*)dst = o;
}

// ---------------- scores = BT(G_b, xb_b), causal 128x256 tiles, bf16 -> P.
__global__ __launch_bounds__(512, 1) void gemm_sc(
    const bf16* __restrict__ Gall, const bf16* __restrict__ xball,
    bf16* __restrict__ Pall) {
  __shared__ bf16 smem[49152];
  const int id = blockIdx.x;
  const int bz = id / 20;
  int rr = id - bz * 20, bm = 0;
  while (rr >= bm / 2 + 1) { rr -= bm / 2 + 1; ++bm; }
  const int bn = rr;
  const long SS = 1024L * 1024;
  const bf16* A = Gall + SS * bz;
  const bf16* B = xball + SS * bz;
  const int tid = threadIdx.x;
  const int lane = tid & 63;
  const int wid = tid >> 6;
  const int wr = wid >> 2;
  const int wc = wid & 3;
  const int lr = lane & 15;
  const int c16 = lane >> 4;
  const int bcol = bn * 256;
  const int arow = bm * 128;
  const bf16* Ag = A + (long)arow * 1024;
  const bf16* Bg = B + (long)bcol * 1024;
  bf16* sA = smem;
  bf16* sB = smem + 16384;

  f32x4 acc[4][4] = {};
  LOOP128(Ag, Bg, sA, sB, acc, 16);

  const int r0 = (lane >> 4) * 4;
  bf16* C = Pall + SS * bz;
#pragma unroll
  for (int m = 0; m < 4; ++m)
#pragma unroll
    for (int n = 0; n < 4; ++n)
#pragma unroll
      for (int r = 0; r < 4; ++r)
        C[(long)(arow + wr * 64 + m * 16 + r0 + r) * 1024 + bcol + wc * 64 + n * 16 + lr] =
            __float2bfloat16(acc[m][n][r]);
}

// ---------------- PV: out[b][q][g] = sum_s P[q][s] V'^T[g][s], fp32 -> d_out.
__global__ __launch_bounds__(512, 1) void gemm_pv32(
    const bf16* __restrict__ Pall, const bf16* __restrict__ VTall,
    float* __restrict__ Out) {
  __shared__ bf16 smem[49152];
  const int bm = blockIdx.x, bn = blockIdx.y, bz = blockIdx.z;
  const long SS = 1024L * 1024;
  const bf16* A = Pall + SS * bz;
  const bf16* B = VTall + SS * bz;
  const int tid = threadIdx.x;
  const int lane = tid & 63;
  const int wid = tid >> 6;
  const int wr = wid >> 2;
  const int wc = wid & 3;
  const int lr = lane & 15;
  const int c16 = lane >> 4;
  const int bcol = bn * 256;
  const int arow = bm * 128;
  const bf16* Ag = A + (long)arow * 1024;
  const bf16* Bg = B + (long)bcol * 1024;
  bf16* sA = smem;
  bf16* sB = smem + 16384;

  f32x4 acc[4][4] = {};
  LOOP128(Ag, Bg, sA, sB, acc, (bm + 1) * 2);  // causal: s < (bm+1)*128

  const int r0 = (lane >> 4) * 4;
  float* C = Out + SS * bz;
#pragma unroll
  for (int m = 0; m < 4; ++m)
#pragma unroll
    for (int n = 0; n < 4; ++n)
#pragma unroll
      for (int r = 0; r < 4; ++r)
        C[(long)(arow + wr * 64 + m * 16 + r0 + r) * 1024 + bcol + wc * 64 + n * 16 + lr] =
            acc[m][n][r];
}

// fp32 -> bf16 weights: wq, wk, wv transposed (64x64 LDS tiles); wo plain.
__global__ __launch_bounds__(256) void f2bw(
    const float* __restrict__ wq, const float* __restrict__ wk,
    const float* __restrict__ wv, const float* __restrict__ wo,
    bf16* __restrict__ wqTb, bf16* __restrict__ wkTb,
    bf16* __restrict__ wvTb, bf16* __restrict__ wob) {
  __shared__ float T[64][65];
  const int bid = blockIdx.x;
  const int t = threadIdx.x;
  union { bf16 h; short s; } u;

  if (bid < 768) {  // transpose-convert: wT[d][e] = w[e][d]
    const int mat = bid >> 8;          // 0 wq, 1 wk, 2 wv
    const int tile = bid & 255;
    const int er = tile >> 4, dc = tile & 15;
    const float* src = ((mat == 0) ? wq : (mat == 1) ? wk : wv);
    bf16* dstb = ((mat == 0) ? wqTb : (mat == 1) ? wkTb : wvTb);
    const int r = t >> 2, c = (t & 3) * 16;
    const float* s0 = src + (long)(er * 64 + r) * 1024 + dc * 64 + c;
#pragma unroll
    for (int j = 0; j < 4; ++j) {
      const float4 v = *(const float4*)(s0 + j * 4);
      T[r][c + j * 4 + 0] = v.x;
      T[r][c + j * 4 + 1] = v.y;
      T[r][c + j * 4 + 2] = v.z;
      T[r][c + j * 4 + 3] = v.w;
    }
    __syncthreads();
    const int d = t >> 2, ec = (t & 3) * 16;
    bf16* dst = dstb + (long)(dc * 64 + d) * 1024 + er * 64 + ec;
#pragma unroll
    for (int half = 0; half < 2; ++half) {
      short8 o;
#pragma unroll
      for (int j = 0; j < 8; ++j) {
        u.h = __float2bfloat16(T[ec + half * 8 + j][d]);
        o[j] = u.s;
      }
      *(short8*)(dst + half * 8) = o;
    }
    return;
  }
  // wo plain convert
  const long i = (long)(bid - 768) * 2048 + t * 8;
  const float4 a = *(const float4*)&wo[i];
  const float4 b = *(const float4*)&wo[i + 4];
  const float va[8] = {a.x, a.y, a.z, a.w, b.x, b.y, b.z, b.w};
  short8 o;
#pragma unroll
  for (int j = 0; j < 8; ++j) { u.h = __float2bfloat16(va[j]); o[j] = u.s; }
  *(short8*)&wob[i] = o;
}

// In-place causal softmax, vectorized: 128 thr/row, one bf16x8 (16B) per lane.
__global__ __launch_bounds__(128) void softmax_causal(bf16* __restrict__ P) {
  const int q = blockIdx.x;
  const int b = blockIdx.y;
  bf16* row = P + ((long)b * 1024 + q) * 1024;
  const int t = threadIdx.x;
  const int n = q + 1;  // causal length
  __shared__ float red[4];
  union { bf16 h; short s; } u;

  const short8 raw = *(const short8*)&row[t * 8];
  float v[8];
  float mx = -1e30f;
#pragma unroll
  for (int j = 0; j < 8; ++j) {
    const int k = t * 8 + j;
    u.s = raw[j];
    v[j] = (k < n) ? __bfloat162float(u.h) * 0.03125f : -1e30f;
    mx = fmaxf(mx, v[j]);
  }
#pragma unroll
  for (int o = 32; o > 0; o >>= 1) mx = fmaxf(mx, __shfl_xor(mx, o, 64));
  if ((t & 63) == 0) red[t >> 6] = mx;
  __syncthreads();
  mx = fmaxf(red[0], red[1]);

  float s = 0.f;
  float e[8];
#pragma unroll
  for (int j = 0; j < 8; ++j) {
    const int k = t * 8 + j;
    e[j] = (k < n) ? __expf(v[j] - mx) : 0.f;
    s += e[j];
  }
#pragma unroll
  for (int o = 32; o > 0; o >>= 1) s += __shfl_xor(s, o, 64);
  if ((t & 63) == 0) red[2 + (t >> 6)] = s;
  __syncthreads();
  s = red[2] + red[3];
  const float inv = 1.f / s;
  short8 o;
#pragma unroll
  for (int j = 0; j < 8; ++j) {
    u.h = __float2bfloat16(e[j] * inv);
    o[j] = u.s;
  }
  *(short8*)&row[t * 8] = o;
}

extern "C" void kernel_launch(void* const* d_in, const int* in_sizes, int n_in,
                              void* d_out, int out_size, void* d_ws, size_t ws_size,
                              hipStream_t stream) {
  (void)in_sizes; (void)n_in; (void)out_size; (void)ws_size;
  const float* x  = (const float*)d_in[0];
  const float* wq = (const float*)d_in[1];
  const float* wk = (const float*)d_in[2];
  const float* wv = (const float*)d_in[3];
  const float* wo = (const float*)d_in[4];
  float* out = (float*)d_out;
  bf16* ws = (bf16*)d_ws;

  const long SB = 8192L * 1024;
  const long SW = 1024L * 1024;

  bf16* xb   = ws;                    // [8][s][d]     16.8 MB
  bf16* wqTb = ws + SB;               // wq^T [d][e]
  bf16* wkTb = ws + SB + SW;          // wk^T [d][e]
  bf16* wvTb = ws + SB + 2 * SW;      // wv^T [d][e]
  bf16* wob  = ws + SB + 3 * SW;      // wo   [g][e]
  bf16* Mp   = ws + SB + 4 * SW;      // M'[d'][d] = wq^T wk (via BT(wkT,wqT))
  bf16* Wp   = ws + SB + 5 * SW;      // W'[g][d]  = wo wv   (via BT(wo,wvT))
  bf16* G    = ws + SB + 6 * SW;      // [8192][1024]
  bf16* VT   = G + SB;                // V'^T [8][g][s]
  bf16* P    = VT + SB;               // scores / P in place
  float* part = (float*)P;            // split-K partials (16 MB, dead before P)

  // weights convert/transpose (1280 light blocks)
  f2bw<<<dim3(1280), dim3(256), 0, stream>>>(wq, wk, wv, wo, wqTb, wkTb, wvTb, wob);
  // small GEMMs (blocks 0-255, start first) overlapped with x conversion
  prep2<<<dim3(4352), dim3(256), 0, stream>>>(wkTb, wqTb, wob, wvTb, part, x, xb);
  reduce_w<<<dim3(1024), dim3(256), 0, stream>>>(part, Mp, Wp);
  // G = x M'  and  V'^T = W' x^T : 256 blocks = 1 exact 256^2 round
  gemm_gv<<<dim3(256), dim3(512), 0, stream>>>(xb, Mp, Wp, G, VT);
  // scores = G x^T, causal 128x256 tiles (20 per batch)
  gemm_sc<<<dim3(160), dim3(512), 0, stream>>>(G, xb, P);
  softmax_causal<<<dim3(1024, 8), dim3(128), 0, stream>>>(P);
  // out = P @ V' (causal K-limit), fp32 straight to d_out
  gemm_pv32<<<dim3(8, 4, 8), dim3(512), 0, stream>>>(P, VT, out);
}

// Round 11
// 112.397 us; speedup vs baseline: 1.6281x; 1.1424x over previous
//
#include <hip/hip_runtime.h>
#include <hip/hip_bf16.h>

typedef __hip_bfloat16 bf16;
typedef __attribute__((ext_vector_type(8))) short short8;
typedef __attribute__((ext_vector_type(4))) float f32x4;

#define SBAR() asm volatile("s_barrier" ::: "memory")
#define VMCNT8() asm volatile("s_waitcnt vmcnt(8)" ::: "memory")
#define VMCNT4() asm volatile("s_waitcnt vmcnt(4)" ::: "memory")
#define VMCNT2() asm volatile("s_waitcnt vmcnt(2)" ::: "memory")
#define VMCNT0() asm volatile("s_waitcnt vmcnt(0)" ::: "memory")

__device__ __forceinline__ void gload_lds16(const bf16* g, bf16* l) {
  __builtin_amdgcn_global_load_lds(
      (const __attribute__((address_space(1))) unsigned int*)g,
      (__attribute__((address_space(3))) unsigned int*)l, 16, 0, 0);
}

// Stage one 128x64 half-tile (row-major, ld=1024) into a linear 16KB LDS slot.
// Global source col is XOR-swizzled so swizzled LDS reads are conflict-free.
__device__ __forceinline__ void stage_half(const bf16* gbase, bf16* slot, int tid) {
  const int r = tid >> 3;                    // 0..63
  const int c = ((tid & 7) ^ (r & 7)) << 3;  // swizzled 16B chunk
  gload_lds16(gbase + (long)r * 1024 + c, slot + tid * 8);
  gload_lds16(gbase + (long)(r + 64) * 1024 + c, slot + 4096 + tid * 8);
}

// Same, for 256-thread blocks (4 passes of 32 rows).
__device__ __forceinline__ void stage_tile128_t256(const bf16* gbase, bf16* slot,
                                                   int t) {
#pragma unroll
  for (int p = 0; p < 4; ++p) {
    const int r = p * 32 + (t >> 3);
    const int c = ((t & 7) ^ (r & 7)) << 3;
    gload_lds16(gbase + (long)r * 1024 + c, slot + p * 2048 + t * 8);
  }
}

// Swizzled fragment read: logical (row, 16B-chunk c16) of a [128][64] half-slot.
__device__ __forceinline__ short8 lds_frag(const bf16* slot, int row, int c16) {
  return *(const short8*)(slot + row * 64 + ((c16 ^ (row & 7)) << 3));
}

// ======== 256x256-tile 4-phase loop with READ-AHEAD schedule (round-10 proven).
#define LOOP256(Ag, Bg, sA, sB, acc)                                              \
  {                                                                               \
    stage_half(Ag, sA, tid);                                                      \
    stage_half(Ag + 128 * 1024, sA + 8192, tid);                                  \
    stage_half(Bg, sB, tid);                                                      \
    stage_half(Bg + 128 * 1024, sB + 8192, tid);                                  \
    stage_half(Ag + 64, sA + 16384, tid);                                         \
    stage_half(Ag + 128 * 1024 + 64, sA + 24576, tid);                            \
    VMCNT4();                                                                     \
    SBAR();                                                                       \
    const int brb = (wc & 1) * 64;                                                \
    short8 aq0[4][2], aq1[4][2], bq0[2][2], bq1[2][2];                            \
    _Pragma("unroll") for (int m = 0; m < 4; ++m)                                 \
        _Pragma("unroll") for (int ks = 0; ks < 2; ++ks)                          \
            aq0[m][ks] = lds_frag(sA + wr * 8192, m * 16 + lr, c16 + ks * 4);     \
    _Pragma("unroll") for (int n = 0; n < 2; ++n)                                 \
        _Pragma("unroll") for (int ks = 0; ks < 2; ++ks)                          \
            bq0[n][ks] = lds_frag(sB + (wc >> 1) * 8192, brb + n * 16 + lr,       \
                                  c16 + ks * 4);                                  \
    const int NT = 16;                                                            \
    for (int t = 0; t < NT; ++t) {                                                \
      const int rp = t & 1;                                                       \
      const int sp = rp ^ 1;                                                      \
      const bf16* Bs = sB + (rp * 2 + (wc >> 1)) * 8192;                          \
      const bf16* AsC = sA + (rp * 2 + wr) * 8192;                                \
      const bf16* AsN = sA + (sp * 2 + wr) * 8192;                                \
      const bf16* BsN = sB + (sp * 2 + (wc >> 1)) * 8192;                         \
      _Pragma("unroll") for (int n = 0; n < 2; ++n)                               \
          _Pragma("unroll") for (int ks = 0; ks < 2; ++ks)                        \
              bq1[n][ks] = lds_frag(Bs, brb + (n + 2) * 16 + lr, c16 + ks * 4);   \
      if (t + 1 < NT) stage_half(Bg + (t + 1) * 64, sB + sp * 2 * 8192, tid);     \
      SBAR();                                                                     \
      __builtin_amdgcn_s_setprio(1);                                              \
      _Pragma("unroll") for (int m = 0; m < 4; ++m)                               \
          _Pragma("unroll") for (int n = 0; n < 2; ++n)                           \
              _Pragma("unroll") for (int ks = 0; ks < 2; ++ks)                    \
                  acc[m][n] = __builtin_amdgcn_mfma_f32_16x16x32_bf16(            \
                      aq0[m][ks], bq0[n][ks], acc[m][n], 0, 0, 0);                \
      __builtin_amdgcn_s_setprio(0);                                              \
      SBAR();                                                                     \
      _Pragma("unroll") for (int m = 0; m < 4; ++m)                               \
          _Pragma("unroll") for (int ks = 0; ks < 2; ++ks)                        \
              aq1[m][ks] = lds_frag(AsC, (m + 4) * 16 + lr, c16 + ks * 4);        \
      if (t + 1 < NT)                                                             \
        stage_half(Bg + 128 * 1024 + (t + 1) * 64, sB + (sp * 2 + 1) * 8192, tid);\
      SBAR();                                                                     \
      __builtin_amdgcn_s_setprio(1);                                              \
      _Pragma("unroll") for (int m = 0; m < 4; ++m)                               \
          _Pragma("unroll") for (int n = 0; n < 2; ++n)                           \
              _Pragma("unroll") for (int ks = 0; ks < 2; ++ks)                    \
                  acc[m][n + 2] = __builtin_amdgcn_mfma_f32_16x16x32_bf16(        \
                      aq0[m][ks], bq1[n][ks], acc[m][n + 2], 0, 0, 0);            \
      __builtin_amdgcn_s_setprio(0);                                              \
      SBAR();                                                                     \
      __builtin_amdgcn_s_setprio(1);                                              \
      _Pragma("unroll") for (int m = 0; m < 4; ++m)                               \
          _Pragma("unroll") for (int n = 0; n < 2; ++n)                           \
              _Pragma("unroll") for (int ks = 0; ks < 2; ++ks)                    \
                  acc[m + 4][n + 2] = __builtin_amdgcn_mfma_f32_16x16x32_bf16(    \
                      aq1[m][ks], bq1[n][ks], acc[m + 4][n + 2], 0, 0, 0);        \
      __builtin_amdgcn_s_setprio(0);                                              \
      SBAR();                                                                     \
      if (t + 2 < NT) {                                                           \
        stage_half(Ag + (t + 2) * 64, sA + rp * 2 * 8192, tid);                   \
        stage_half(Ag + 128 * 1024 + (t + 2) * 64, sA + (rp * 2 + 1) * 8192, tid);\
        VMCNT4();                                                                 \
      } else if (t + 1 < NT) {                                                    \
        VMCNT0();                                                                 \
      }                                                                           \
      SBAR();                                                                     \
      if (t + 1 < NT) {                                                           \
        _Pragma("unroll") for (int m = 0; m < 4; ++m)                             \
            _Pragma("unroll") for (int ks = 0; ks < 2; ++ks)                      \
                aq0[m][ks] = lds_frag(AsN, m * 16 + lr, c16 + ks * 4);            \
      }                                                                           \
      __builtin_amdgcn_s_setprio(1);                                              \
      _Pragma("unroll") for (int m = 0; m < 4; ++m)                               \
          _Pragma("unroll") for (int n = 0; n < 2; ++n)                           \
              _Pragma("unroll") for (int ks = 0; ks < 2; ++ks)                    \
                  acc[m + 4][n] = __builtin_amdgcn_mfma_f32_16x16x32_bf16(        \
                      aq1[m][ks], bq0[n][ks], acc[m + 4][n], 0, 0, 0);            \
      __builtin_amdgcn_s_setprio(0);                                              \
      if (t + 1 < NT) {                                                           \
        _Pragma("unroll") for (int n = 0; n < 2; ++n)                             \
            _Pragma("unroll") for (int ks = 0; ks < 2; ++ks)                      \
                bq0[n][ks] = lds_frag(BsN, brb + n * 16 + lr, c16 + ks * 4);      \
      }                                                                           \
      SBAR();                                                                     \
    }                                                                             \
  }

// ======== 128x256-tile 2-phase loop with read-ahead (round-10 proven).
#define LOOP128(Ag, Bg, sA, sB, acc, NTv)                                         \
  {                                                                               \
    stage_half(Ag, sA, tid);                                                      \
    stage_half(Bg, sB, tid);                                                      \
    stage_half(Bg + 128 * 1024, sB + 8192, tid);                                  \
    stage_half(Ag + 64, sA + 8192, tid);                                          \
    VMCNT2();                                                                     \
    SBAR();                                                                       \
    const int brb = (wc & 1) * 64;                                                \
    short8 aq[4][2], b01[2][2], b23[2][2];                                        \
    _Pragma("unroll") for (int m = 0; m < 4; ++m)                                 \
        _Pragma("unroll") for (int ks = 0; ks < 2; ++ks)                          \
            aq[m][ks] = lds_frag(sA, wr * 64 + m * 16 + lr, c16 + ks * 4);        \
    _Pragma("unroll") for (int n = 0; n < 2; ++n)                                 \
        _Pragma("unroll") for (int ks = 0; ks < 2; ++ks)                          \
            b01[n][ks] = lds_frag(sB + (wc >> 1) * 8192, brb + n * 16 + lr,       \
                                  c16 + ks * 4);                                  \
    const int NT = (NTv);                                                         \
    for (int t = 0; t < NT; ++t) {                                                \
      const int rp = t & 1;                                                       \
      const int sp = rp ^ 1;                                                      \
      const bf16* Bs = sB + (rp * 2 + (wc >> 1)) * 8192;                          \
      const bf16* AsN = sA + sp * 8192;                                           \
      const bf16* BsN = sB + (sp * 2 + (wc >> 1)) * 8192;                         \
      _Pragma("unroll") for (int n = 0; n < 2; ++n)                               \
          _Pragma("unroll") for (int ks = 0; ks < 2; ++ks)                        \
              b23[n][ks] = lds_frag(Bs, brb + (n + 2) * 16 + lr, c16 + ks * 4);   \
      if (t + 1 < NT) stage_half(Bg + (t + 1) * 64, sB + sp * 2 * 8192, tid);     \
      SBAR();                                                                     \
      __builtin_amdgcn_s_setprio(1);                                              \
      _Pragma("unroll") for (int m = 0; m < 4; ++m)                               \
          _Pragma("unroll") for (int n = 0; n < 2; ++n)                           \
              _Pragma("unroll") for (int ks = 0; ks < 2; ++ks)                    \
                  acc[m][n] = __builtin_amdgcn_mfma_f32_16x16x32_bf16(            \
                      aq[m][ks], b01[n][ks], acc[m][n], 0, 0, 0);                 \
      __builtin_amdgcn_s_setprio(0);                                              \
      SBAR();                                                                     \
      if (t + 1 < NT)                                                             \
        stage_half(Bg + 128 * 1024 + (t + 1) * 64, sB + (sp * 2 + 1) * 8192, tid);\
      if (t + 2 < NT) {                                                           \
        stage_half(Ag + (t + 2) * 64, sA + rp * 8192, tid);                       \
        VMCNT2();                                                                 \
      } else if (t + 1 < NT) {                                                    \
        VMCNT0();                                                                 \
      }                                                                           \
      SBAR();                                                                     \
      __builtin_amdgcn_s_setprio(1);                                              \
      _Pragma("unroll") for (int m = 0; m < 4; ++m)                               \
          _Pragma("unroll") for (int n = 0; n < 2; ++n)                           \
              _Pragma("unroll") for (int ks = 0; ks < 2; ++ks)                    \
                  acc[m][n + 2] = __builtin_amdgcn_mfma_f32_16x16x32_bf16(        \
                      aq[m][ks], b23[n][ks], acc[m][n + 2], 0, 0, 0);             \
      __builtin_amdgcn_s_setprio(0);                                              \
      if (t + 1 < NT) {                                                           \
        _Pragma("unroll") for (int m = 0; m < 4; ++m)                             \
            _Pragma("unroll") for (int ks = 0; ks < 2; ++ks)                      \
                aq[m][ks] = lds_frag(AsN, wr * 64 + m * 16 + lr, c16 + ks * 4);   \
        _Pragma("unroll") for (int n = 0; n < 2; ++n)                             \
            _Pragma("unroll") for (int ks = 0; ks < 2; ++ks)                      \
                b01[n][ks] = lds_frag(BsN, brb + n * 16 + lr, c16 + ks * 4);      \
      }                                                                           \
      SBAR();                                                                     \
    }                                                                             \
  }

// ---------------- merged G-projection + V'-projection, XCD-affine block map.
// id 0..127 (G): xcd=id&7, w=id>>3: bm=(id&7)+8*(w>>2), bn=w&3
//   -> all 4 bn-siblings (same x A-panel) share an XCD-L2.
// id 128..255 (V'): v=id-128: batch=v&7, gs=(v>>3)&3, ss=v>>5
//   -> each XCD handles one batch (its x panels stay in that L2).
__global__ __launch_bounds__(512, 1) void gemm_gv(
    const bf16* __restrict__ xb, const bf16* __restrict__ Mp,
    const bf16* __restrict__ Wp, bf16* __restrict__ G, bf16* __restrict__ VT) {
  __shared__ bf16 smem[65536];
  const int id = blockIdx.x;
  const int tid = threadIdx.x;
  const int lane = tid & 63;
  const int wid = tid >> 6;
  const int wr = wid >> 2;
  const int wc = wid & 3;
  const int lr = lane & 15;
  const int c16 = lane >> 4;
  const long SS = 1024L * 1024;

  const bf16 *Ag, *Bg;
  bf16* C;
  int arow, bcol;
  if (id < 128) {
    const int w = id >> 3;
    const int bm = (id & 7) + 8 * (w >> 2);
    const int bn = w & 3;
    arow = bm * 256;
    bcol = bn * 256;
    Ag = xb + (long)arow * 1024;
    Bg = Mp + (long)bcol * 1024;
    C = G;
  } else {
    const int v = id - 128;
    const int b = v & 7;
    const int gs = (v >> 3) & 3;
    const int ss = v >> 5;
    arow = gs * 256;
    bcol = ss * 256;
    Ag = Wp + (long)arow * 1024;
    Bg = xb + (long)b * SS + (long)bcol * 1024;
    C = VT + (long)b * SS;
  }
  bf16* sA = smem;
  bf16* sB = smem + 32768;

  f32x4 acc[8][4] = {};
  LOOP256(Ag, Bg, sA, sB, acc);

  const int r0 = (lane >> 4) * 4;
#pragma unroll
  for (int m = 0; m < 8; ++m)
#pragma unroll
    for (int n = 0; n < 4; ++n)
#pragma unroll
      for (int r = 0; r < 4; ++r)
        C[(long)(arow + wr * 128 + m * 16 + r0 + r) * 1024 + bcol + wc * 64 + n * 16 + lr] =
            __float2bfloat16(acc[m][n][r]);
}

// ---------------- prep2: full-K small GEMMs (blocks 0-127, direct bf16 write,
// double-buffered counted-vmcnt) overlapped with x fp32->bf16 (blocks 128-4223).
// small: mat = id>>6 (0: M'=BT(wkT,wqT), 1: W'=BT(wo,wvT)), tile=id&63.
__global__ __launch_bounds__(256, 2) void prep2(
    const bf16* __restrict__ wkT, const bf16* __restrict__ wqT,
    const bf16* __restrict__ wo, const bf16* __restrict__ wvT,
    bf16* __restrict__ Mp, bf16* __restrict__ Wp, const float* __restrict__ x,
    bf16* __restrict__ xb) {
  __shared__ bf16 smem[32768];  // 64 KB: A[2] + B[2] slots of 128x64
  const int bid = blockIdx.x;
  const int t = threadIdx.x;

  if (bid >= 128) {  // x conversion
    const long i = (long)(bid - 128) * 2048 + t * 8;
    const float4 a = *(const float4*)&x[i];
    const float4 b = *(const float4*)&x[i + 4];
    const float va[8] = {a.x, a.y, a.z, a.w, b.x, b.y, b.z, b.w};
    union { bf16 h; short s; } u;
    short8 o;
#pragma unroll
    for (int j = 0; j < 8; ++j) { u.h = __float2bfloat16(va[j]); o[j] = u.s; }
    *(short8*)&xb[i] = o;
    return;
  }

  const int mat = bid >> 6;
  const int tile = bid & 63;
  const int bm = tile >> 3, bn = tile & 7;
  const bf16* A = (mat == 0) ? wkT : wo;
  const bf16* B = (mat == 0) ? wqT : wvT;
  bf16* C = (mat == 0) ? Mp : Wp;

  const int lane = t & 63;
  const int wid = t >> 6;
  const int wr = (wid >> 1) * 64;
  const int wc = (wid & 1) * 64;
  const int lr = lane & 15;
  const int c16 = lane >> 4;
  const int arow = bm * 128;
  const int brow = bn * 128;
  const bf16* Ag = A + (long)arow * 1024;
  const bf16* Bg = B + (long)brow * 1024;
  bf16* sA = smem;          // 2 slots of 8192
  bf16* sB = smem + 16384;  // 2 slots of 8192

  // prologue: tiles 0 and 1
  stage_tile128_t256(Ag, sA, t);
  stage_tile128_t256(Bg, sB, t);
  stage_tile128_t256(Ag + 64, sA + 8192, t);
  stage_tile128_t256(Bg + 64, sB + 8192, t);
  VMCNT8();  // drain tile 0 (8 loads of tile 1 may stay in flight)
  SBAR();

  f32x4 acc[4][4] = {};
  for (int tt = 0; tt < 16; ++tt) {
    const int cur = tt & 1;
    const bf16* As = sA + cur * 8192;
    const bf16* Bs = sB + cur * 8192;
    short8 a[4][2], b[4][2];
#pragma unroll
    for (int m = 0; m < 4; ++m)
#pragma unroll
      for (int ks = 0; ks < 2; ++ks)
        a[m][ks] = lds_frag(As, wr + m * 16 + lr, c16 + ks * 4);
#pragma unroll
    for (int n = 0; n < 4; ++n)
#pragma unroll
      for (int ks = 0; ks < 2; ++ks)
        b[n][ks] = lds_frag(Bs, wc + n * 16 + lr, c16 + ks * 4);
#pragma unroll
    for (int m = 0; m < 4; ++m)
#pragma unroll
      for (int n = 0; n < 4; ++n)
#pragma unroll
        for (int ks = 0; ks < 2; ++ks)
          acc[m][n] = __builtin_amdgcn_mfma_f32_16x16x32_bf16(
              a[m][ks], b[n][ks], acc[m][n], 0, 0, 0);
    SBAR();  // all waves done reading slot cur
    if (tt + 2 < 16) {
      stage_tile128_t256(Ag + (tt + 2) * 64, sA + cur * 8192, t);
      stage_tile128_t256(Bg + (tt + 2) * 64, sB + cur * 8192, t);
      VMCNT8();  // drain stage of tile tt+1
    } else if (tt + 1 < 16) {
      VMCNT0();  // drain stage of tile 15
    }
    SBAR();
  }

#pragma unroll
  for (int m = 0; m < 4; ++m)
#pragma unroll
    for (int n = 0; n < 4; ++n)
#pragma unroll
      for (int r = 0; r < 4; ++r) {
        const int row = arow + wr + m * 16 + (lane >> 4) * 4 + r;
        const int col = brow + wc + n * 16 + lr;
        C[(long)row * 1024 + col] = __float2bfloat16(acc[m][n][r]);
      }
}

// ---------------- scores = BT(G_b, xb_b), causal 128x256 tiles, XCD-affine:
// bz = id&7 (one batch per XCD), r = id>>3 enumerates (bm, bn<=bm/2).
__global__ __launch_bounds__(512, 1) void gemm_sc(
    const bf16* __restrict__ Gall, const bf16* __restrict__ xball,
    bf16* __restrict__ Pall) {
  __shared__ bf16 smem[49152];
  const int id = blockIdx.x;
  const int bz = id & 7;
  int rr = id >> 3, bm = 0;
  while (rr >= bm / 2 + 1) { rr -= bm / 2 + 1; ++bm; }
  const int bn = rr;
  const long SS = 1024L * 1024;
  const bf16* A = Gall + SS * bz;
  const bf16* B = xball + SS * bz;
  const int tid = threadIdx.x;
  const int lane = tid & 63;
  const int wid = tid >> 6;
  const int wr = wid >> 2;
  const int wc = wid & 3;
  const int lr = lane & 15;
  const int c16 = lane >> 4;
  const int bcol = bn * 256;
  const int arow = bm * 128;
  const bf16* Ag = A + (long)arow * 1024;
  const bf16* Bg = B + (long)bcol * 1024;
  bf16* sA = smem;
  bf16* sB = smem + 16384;

  f32x4 acc[4][4] = {};
  LOOP128(Ag, Bg, sA, sB, acc, 16);

  const int r0 = (lane >> 4) * 4;
  bf16* C = Pall + SS * bz;
#pragma unroll
  for (int m = 0; m < 4; ++m)
#pragma unroll
    for (int n = 0; n < 4; ++n)
#pragma unroll
      for (int r = 0; r < 4; ++r)
        C[(long)(arow + wr * 64 + m * 16 + r0 + r) * 1024 + bcol + wc * 64 + n * 16 + lr] =
            __float2bfloat16(acc[m][n][r]);
}

// ---------------- PV: out = P @ V' (causal K-limit), fp32 -> d_out.
// XCD-affine 1-D grid 256: bz = id&7, w = id>>3: bm = w&7, bn = w>>3.
__global__ __launch_bounds__(512, 1) void gemm_pv32(
    const bf16* __restrict__ Pall, const bf16* __restrict__ VTall,
    float* __restrict__ Out) {
  __shared__ bf16 smem[49152];
  const int id = blockIdx.x;
  const int bz = id & 7;
  const int w = id >> 3;
  const int bm = w & 7;
  const int bn = w >> 3;
  const long SS = 1024L * 1024;
  const bf16* A = Pall + SS * bz;
  const bf16* B = VTall + SS * bz;
  const int tid = threadIdx.x;
  const int lane = tid & 63;
  const int wid = tid >> 6;
  const int wr = wid >> 2;
  const int wc = wid & 3;
  const int lr = lane & 15;
  const int c16 = lane >> 4;
  const int bcol = bn * 256;
  const int arow = bm * 128;
  const bf16* Ag = A + (long)arow * 1024;
  const bf16* Bg = B + (long)bcol * 1024;
  bf16* sA = smem;
  bf16* sB = smem + 16384;

  f32x4 acc[4][4] = {};
  LOOP128(Ag, Bg, sA, sB, acc, (bm + 1) * 2);  // causal: s < (bm+1)*128

  const int r0 = (lane >> 4) * 4;
  float* C = Out + SS * bz;
#pragma unroll
  for (int m = 0; m < 4; ++m)
#pragma unroll
    for (int n = 0; n < 4; ++n)
#pragma unroll
      for (int r = 0; r < 4; ++r)
        C[(long)(arow + wr * 64 + m * 16 + r0 + r) * 1024 + bcol + wc * 64 + n * 16 + lr] =
            acc[m][n][r];
}

// fp32 -> bf16 weights: wq, wk, wv transposed (64x64 LDS tiles); wo plain.
__global__ __launch_bounds__(256) void f2bw(
    const float* __restrict__ wq, const float* __restrict__ wk,
    const float* __restrict__ wv, const float* __restrict__ wo,
    bf16* __restrict__ wqTb, bf16* __restrict__ wkTb,
    bf16* __restrict__ wvTb, bf16* __restrict__ wob) {
  __shared__ float T[64][65];
  const int bid = blockIdx.x;
  const int t = threadIdx.x;
  union { bf16 h; short s; } u;

  if (bid < 768) {  // transpose-convert: wT[d][e] = w[e][d]
    const int mat = bid >> 8;          // 0 wq, 1 wk, 2 wv
    const int tile = bid & 255;
    const int er = tile >> 4, dc = tile & 15;
    const float* src = ((mat == 0) ? wq : (mat == 1) ? wk : wv);
    bf16* dstb = ((mat == 0) ? wqTb : (mat == 1) ? wkTb : wvTb);
    const int r = t >> 2, c = (t & 3) * 16;
    const float* s0 = src + (long)(er * 64 + r) * 1024 + dc * 64 + c;
#pragma unroll
    for (int j = 0; j < 4; ++j) {
      const float4 v = *(const float4*)(s0 + j * 4);
      T[r][c + j * 4 + 0] = v.x;
      T[r][c + j * 4 + 1] = v.y;
      T[r][c + j * 4 + 2] = v.z;
      T[r][c + j * 4 + 3] = v.w;
    }
    __syncthreads();
    const int d = t >> 2, ec = (t & 3) * 16;
    bf16* dst = dstb + (long)(dc * 64 + d) * 1024 + er * 64 + ec;
#pragma unroll
    for (int half = 0; half < 2; ++half) {
      short8 o;
#pragma unroll
      for (int j = 0; j < 8; ++j) {
        u.h = __float2bfloat16(T[ec + half * 8 + j][d]);
        o[j] = u.s;
      }
      *(short8*)(dst + half * 8) = o;
    }
    return;
  }
  // wo plain convert
  const long i = (long)(bid - 768) * 2048 + t * 8;
  const float4 a = *(const float4*)&wo[i];
  const float4 b = *(const float4*)&wo[i + 4];
  const float va[8] = {a.x, a.y, a.z, a.w, b.x, b.y, b.z, b.w};
  short8 o;
#pragma unroll
  for (int j = 0; j < 8; ++j) { u.h = __float2bfloat16(va[j]); o[j] = u.s; }
  *(short8*)&wob[i] = o;
}

// In-place causal softmax, vectorized: 128 thr/row, one bf16x8 (16B) per lane.
__global__ __launch_bounds__(128) void softmax_causal(bf16* __restrict__ P) {
  const int q = blockIdx.x;
  const int b = blockIdx.y;
  bf16* row = P + ((long)b * 1024 + q) * 1024;
  const int t = threadIdx.x;
  const int n = q + 1;  // causal length
  __shared__ float red[4];
  union { bf16 h; short s; } u;

  const short8 raw = *(const short8*)&row[t * 8];
  float v[8];
  float mx = -1e30f;
#pragma unroll
  for (int j = 0; j < 8; ++j) {
    const int k = t * 8 + j;
    u.s = raw[j];
    v[j] = (k < n) ? __bfloat162float(u.h) * 0.03125f : -1e30f;
    mx = fmaxf(mx, v[j]);
  }
#pragma unroll
  for (int o = 32; o > 0; o >>= 1) mx = fmaxf(mx, __shfl_xor(mx, o, 64));
  if ((t & 63) == 0) red[t >> 6] = mx;
  __syncthreads();
  mx = fmaxf(red[0], red[1]);

  float s = 0.f;
  float e[8];
#pragma unroll
  for (int j = 0; j < 8; ++j) {
    const int k = t * 8 + j;
    e[j] = (k < n) ? __expf(v[j] - mx) : 0.f;
    s += e[j];
  }
#pragma unroll
  for (int o = 32; o > 0; o >>= 1) s += __shfl_xor(s, o, 64);
  if ((t & 63) == 0) red[2 + (t >> 6)] = s;
  __syncthreads();
  s = red[2] + red[3];
  const float inv = 1.f / s;
  short8 o;
#pragma unroll
  for (int j = 0; j < 8; ++j) {
    u.h = __float2bfloat16(e[j] * inv);
    o[j] = u.s;
  }
  *(short8*)&row[t * 8] = o;
}

extern "C" void kernel_launch(void* const* d_in, const int* in_sizes, int n_in,
                              void* d_out, int out_size, void* d_ws, size_t ws_size,
                              hipStream_t stream) {
  (void)in_sizes; (void)n_in; (void)out_size; (void)ws_size;
  const float* x  = (const float*)d_in[0];
  const float* wq = (const float*)d_in[1];
  const float* wk = (const float*)d_in[2];
  const float* wv = (const float*)d_in[3];
  const float* wo = (const float*)d_in[4];
  float* out = (float*)d_out;
  bf16* ws = (bf16*)d_ws;

  const long SB = 8192L * 1024;
  const long SW = 1024L * 1024;

  bf16* xb   = ws;                    // [8][s][d]     16.8 MB
  bf16* wqTb = ws + SB;               // wq^T [d][e]
  bf16* wkTb = ws + SB + SW;          // wk^T [d][e]
  bf16* wvTb = ws + SB + 2 * SW;      // wv^T [d][e]
  bf16* wob  = ws + SB + 3 * SW;      // wo   [g][e]
  bf16* Mp   = ws + SB + 4 * SW;      // M'[d'][d] = wq^T wk (via BT(wkT,wqT))
  bf16* Wp   = ws + SB + 5 * SW;      // W'[g][d]  = wo wv   (via BT(wo,wvT))
  bf16* G    = ws + SB + 6 * SW;      // [8192][1024]
  bf16* VT   = G + SB;                // V'^T [8][g][s]
  bf16* P    = VT + SB;               // scores / P in place

  // weights convert/transpose (1280 light blocks)
  f2bw<<<dim3(1280), dim3(256), 0, stream>>>(wq, wk, wv, wo, wqTb, wkTb, wvTb, wob);
  // full-K small GEMMs (blocks 0-127, direct bf16) overlapped with x conversion
  prep2<<<dim3(4224), dim3(256), 0, stream>>>(wkTb, wqTb, wob, wvTb, Mp, Wp, x, xb);
  // G = x M'  and  V'^T = W' x^T : 256 blocks = 1 exact 256^2 round, XCD-affine
  gemm_gv<<<dim3(256), dim3(512), 0, stream>>>(xb, Mp, Wp, G, VT);
  // scores = G x^T, causal 128x256 tiles, one batch per XCD
  gemm_sc<<<dim3(160), dim3(512), 0, stream>>>(G, xb, P);
  softmax_causal<<<dim3(1024, 8), dim3(128), 0, stream>>>(P);
  // out = P @ V' (causal K-limit), fp32 straight to d_out, XCD-affine
  gemm_pv32<<<dim3(256), dim3(512), 0, stream>>>(P, VT, out);
}